// Round 3
// baseline (385.079 us; speedup 1.0000x reference)
//
#include <hip/hip_runtime.h>

typedef __bf16 bf16;
typedef __attribute__((ext_vector_type(8))) __bf16 bf16x8;
typedef __attribute__((ext_vector_type(4))) float f32x4;

static __device__ __forceinline__ int swz4(int r) { return (r & 3) ^ ((r >> 2) & 3); }

static __device__ __forceinline__ void async_cp16(void* lds, const void* g) {
  __builtin_amdgcn_global_load_lds((__attribute__((address_space(1))) void*)g,
                                   (__attribute__((address_space(3))) void*)lds,
                                   16, 0, 0);
}

static __device__ __forceinline__ f32x4 mfma16(bf16x8 a, bf16x8 b, f32x4 c) {
  return __builtin_amdgcn_mfma_f32_16x16x32_bf16(a, b, c, 0, 0, 0);
}

static __device__ __forceinline__ unsigned short bfbits(float f) {
  bf16 b = (bf16)f;
  return __builtin_bit_cast(unsigned short, b);
}

// ---------------- small kernels ----------------

extern "C" __global__ void cvt_kernel(const float* __restrict__ src,
                                      unsigned short* __restrict__ hi,
                                      unsigned short* __restrict__ lo, int n4) {
  int i = blockIdx.x * 256 + threadIdx.x;
  if (i >= n4) return;
  float4 v = ((const float4*)src)[i];
  bf16 b0 = (bf16)v.x, b1 = (bf16)v.y, b2 = (bf16)v.z, b3 = (bf16)v.w;
  ushort4 oh;
  oh.x = __builtin_bit_cast(unsigned short, b0);
  oh.y = __builtin_bit_cast(unsigned short, b1);
  oh.z = __builtin_bit_cast(unsigned short, b2);
  oh.w = __builtin_bit_cast(unsigned short, b3);
  ((ushort4*)hi)[i] = oh;
  if (lo) {
    ushort4 ol;
    ol.x = bfbits(v.x - (float)b0);
    ol.y = bfbits(v.y - (float)b1);
    ol.z = bfbits(v.z - (float)b2);
    ol.w = bfbits(v.w - (float)b3);
    ((ushort4*)lo)[i] = ol;
  }
}

extern "C" __global__ void rope_table_kernel(float2* __restrict__ rope) {
  int idx = blockIdx.x * 256 + threadIdx.x; // 32768
  int s = idx >> 5, i = idx & 31;
  float inv_freq = powf(10000.0f, -(2.0f * (float)i) / 64.0f);
  float ang = (float)s * inv_freq;
  float2 cs;
  cs.x = cosf(ang);
  cs.y = sinf(ang);
  rope[idx] = cs;
}

extern "C" __global__ __launch_bounds__(256) void rmsnorm_kernel(
    const float* __restrict__ x, const float* __restrict__ g,
    unsigned short* __restrict__ yhi, unsigned short* __restrict__ ylo) {
  int row = blockIdx.x;
  int t = threadIdx.x;
  const float4 xv = *(const float4*)(x + (size_t)row * 1024 + t * 4);
  float ss = xv.x * xv.x + xv.y * xv.y + xv.z * xv.z + xv.w * xv.w;
#pragma unroll
  for (int d = 1; d < 64; d <<= 1) ss += __shfl_xor(ss, d, 64);
  __shared__ float red[4];
  if ((t & 63) == 0) red[t >> 6] = ss;
  __syncthreads();
  float tot = red[0] + red[1] + red[2] + red[3];
  float inv = 1.0f / sqrtf(tot * (1.0f / 1024.0f) + 1e-5f);
  const float4 gv = *(const float4*)(g + t * 4);
  float y0 = xv.x * gv.x * inv, y1 = xv.y * gv.y * inv;
  float y2 = xv.z * gv.z * inv, y3 = xv.w * gv.w * inv;
  bf16 b0 = (bf16)y0, b1 = (bf16)y1, b2 = (bf16)y2, b3 = (bf16)y3;
  ushort4 oh;
  oh.x = __builtin_bit_cast(unsigned short, b0);
  oh.y = __builtin_bit_cast(unsigned short, b1);
  oh.z = __builtin_bit_cast(unsigned short, b2);
  oh.w = __builtin_bit_cast(unsigned short, b3);
  ((ushort4*)yhi)[(size_t)row * 256 + t] = oh;
  if (ylo) {
    ushort4 ol;
    ol.x = bfbits(y0 - (float)b0);
    ol.y = bfbits(y1 - (float)b1);
    ol.z = bfbits(y2 - (float)b2);
    ol.w = bfbits(y3 - (float)b3);
    ((ushort4*)ylo)[(size_t)row * 256 + t] = ol;
  }
}

// ---------------- GEMM: C[M,N] = A[M,K] * B[N,K]^T, 128x128 tile, BK=32 ----------------
// EPI 0: vT store (bf16, transposed per-head v)
// EPI 1: + resF -> f32 outF
// EPI 4: outF[idx] += acc (f32 in/out)
template <int EPI>
__global__ __launch_bounds__(256, 2) void gemm_nt(
    const bf16* __restrict__ A, const bf16* __restrict__ B, int M, int N, int K,
    float* __restrict__ outF, bf16* __restrict__ outB,
    const float* __restrict__ resF) {
  __shared__ alignas(16) bf16 As[128 * 32];
  __shared__ alignas(16) bf16 Bs[128 * 32];
  const int tid = threadIdx.x;
  const int lane = tid & 63, wave = tid >> 6;
  const int lo = lane & 15, hi = lane >> 4;
  const int wm = wave >> 1, wn = wave & 1;
  const size_t tm = (size_t)blockIdx.y * 128, tn = (size_t)blockIdx.x * 128;
  f32x4 acc[4][4] = {};
  for (int k0 = 0; k0 < K; k0 += 32) {
    __syncthreads();
#pragma unroll
    for (int i2 = 0; i2 < 2; i2++) {
      int p = tid + 256 * i2;
      int row = p >> 2, kcp = p & 3;
      int kcl = kcp ^ swz4(row);
      async_cp16((char*)As + (size_t)p * 16, A + (tm + row) * (size_t)K + k0 + kcl * 8);
      async_cp16((char*)Bs + (size_t)p * 16, B + (tn + row) * (size_t)K + k0 + kcl * 8);
    }
    __syncthreads();
    bf16x8 fa[4], fb[4];
#pragma unroll
    for (int i = 0; i < 4; i++) {
      int ra = wm * 64 + i * 16 + lo;
      fa[i] = *(const bf16x8*)((const char*)As + ra * 64 + ((hi ^ swz4(ra)) << 4));
      int rb = wn * 64 + i * 16 + lo;
      fb[i] = *(const bf16x8*)((const char*)Bs + rb * 64 + ((hi ^ swz4(rb)) << 4));
    }
    __builtin_amdgcn_s_setprio(1);
#pragma unroll
    for (int i = 0; i < 4; i++)
#pragma unroll
      for (int j = 0; j < 4; j++) acc[i][j] = mfma16(fa[i], fb[j], acc[i][j]);
    __builtin_amdgcn_s_setprio(0);
  }
#pragma unroll
  for (int i = 0; i < 4; i++)
#pragma unroll
    for (int j = 0; j < 4; j++)
#pragma unroll
      for (int r = 0; r < 4; r++) {
        size_t m = tm + wm * 64 + i * 16 + hi * 4 + r;
        size_t n = tn + wn * 64 + j * 16 + lo;
        float v = acc[i][j][r];
        if constexpr (EPI == 0) {
          size_t idx = (((m >> 10) * 16 + (n >> 6)) * 64 + (n & 63)) * 1024 + (m & 1023);
          outB[idx] = (bf16)v;
        } else if constexpr (EPI == 1) {
          size_t idx = m * (size_t)N + n;
          outF[idx] = v + resF[idx];
        } else {
          size_t idx = m * (size_t)N + n;
          outF[idx] = outF[idx] + v;
        }
      }
}

// ---------------- 8-phase 256x256xBK64 GEMM (T2+T3+T4+T5), K=1024, N=4096 ----------------
// C[M,N] = A[M,1024] * B[N,1024]^T ; 512 threads = 8 waves (2M x 4N); LDS 128KB dbuf.
// Tile t kh0 staged in iter t-2 (ph3-4); kh1 in iter t-1 (ph1-2). Gate: vmcnt(4) per tile.
// EPI 0: O = silu(acc) bf16 ; EPI 1: O = O * acc (in-place RMW, bf16)
template <int EPI>
__global__ __launch_bounds__(512, 2) void gemm8(
    const bf16* __restrict__ A, const bf16* __restrict__ B, bf16* __restrict__ O) {
  __shared__ alignas(16) bf16 LA[2][2][256][32];
  __shared__ alignas(16) bf16 LB[2][2][256][32];
  const int tid = threadIdx.x;
  const int lane = tid & 63, wave = tid >> 6;
  const int lo = lane & 15, hi = lane >> 4;
  const int wm = wave >> 2, wn = wave & 3;  // 2 x 4 wave grid, per-wave C = 128x64
  const int K = 1024;
  // XCD-aware bijective swizzle (256 blocks, 256 % 8 == 0)
  int wg = ((blockIdx.x & 7) << 5) + (blockIdx.x >> 3);
  const size_t tm = (size_t)(wg >> 4) * 256, tn = (size_t)(wg & 15) * 256;

  f32x4 acc[8][4] = {};

  // stage one kh-half (256 rows x 32 cols) of one matrix: 2 x global_load_lds_dwordx4
  auto stage = [&](const bf16* __restrict__ G, size_t row0, int kt, int kh, bf16* dst) {
#pragma unroll
    for (int i = 0; i < 2; i++) {
      int s = i * 512 + tid;
      int r = s >> 2, c = s & 3;
      async_cp16((char*)dst + (size_t)s * 16,
                 G + (row0 + r) * (size_t)K + kt * 64 + kh * 32 + ((c ^ (r & 3)) << 3));
    }
  };

  // prologue: t0 kh0, t0 kh1, t1 kh0  (12 loads in flight; gate first 8)
  stage(A, tm, 0, 0, &LA[0][0][0][0]);
  stage(B, tn, 0, 0, &LB[0][0][0][0]);
  stage(A, tm, 0, 1, &LA[0][1][0][0]);
  stage(B, tn, 0, 1, &LB[0][1][0][0]);
  stage(A, tm, 1, 0, &LA[1][0][0][0]);
  stage(B, tn, 1, 0, &LB[1][0][0][0]);
  asm volatile("s_waitcnt vmcnt(4)");
  __builtin_amdgcn_s_barrier();

  bf16x8 fb[4];
  for (int t = 0; t < 16; t++) {
    const int p = t & 1;
#pragma unroll
    for (int q = 0; q < 4; q++) {
      const int kh = q >> 1, mh = q & 1;
      bf16x8 fa[4];
#pragma unroll
      for (int i = 0; i < 4; i++) {
        int r = wm * 128 + (mh * 4 + i) * 16 + lo;
        fa[i] = *(const bf16x8*)&LA[p][kh][r][(hi ^ (r & 3)) << 3];
      }
      if (mh == 0) {
#pragma unroll
        for (int j = 0; j < 4; j++) {
          int r = wn * 64 + j * 16 + lo;
          fb[j] = *(const bf16x8*)&LB[p][kh][r][(hi ^ (r & 3)) << 3];
        }
      }
      // prefetch schedule: ph1: A(t+1,kh1) ph2: B(t+1,kh1) -> buf p^1 (kh1 region free)
      //                    ph3: A(t+2,kh0) ph4: B(t+2,kh0) -> buf p   (kh0 dead after ph2)
      if (q == 0) {
        if (t + 1 < 16) stage(A, tm, t + 1, 1, &LA[p ^ 1][1][0][0]);
      } else if (q == 1) {
        if (t + 1 < 16) stage(B, tn, t + 1, 1, &LB[p ^ 1][1][0][0]);
      } else if (q == 2) {
        if (t + 2 < 16) stage(A, tm, t + 2, 0, &LA[p][0][0][0]);
      } else {
        if (t + 2 < 16) stage(B, tn, t + 2, 0, &LB[p][0][0][0]);
      }
      __builtin_amdgcn_s_barrier();
      asm volatile("s_waitcnt lgkmcnt(0)");
      __builtin_amdgcn_sched_barrier(0);
      __builtin_amdgcn_s_setprio(1);
#pragma unroll
      for (int i = 0; i < 4; i++)
#pragma unroll
        for (int j = 0; j < 4; j++)
          acc[mh * 4 + i][j] = mfma16(fa[i], fb[j], acc[mh * 4 + i][j]);
      __builtin_amdgcn_s_setprio(0);
      if (q == 3) {
        // tile gate for iter t+1: outstanding = [t+1 kh1 (4)][t+2 kh0 (4)]
        if (t + 2 < 16) {
          asm volatile("s_waitcnt vmcnt(4)");
        } else if (t + 1 < 16) {
          asm volatile("s_waitcnt vmcnt(0)");
        }
      }
      __builtin_amdgcn_s_barrier();
    }
  }

#pragma unroll
  for (int i = 0; i < 8; i++)
#pragma unroll
    for (int j = 0; j < 4; j++)
#pragma unroll
      for (int r = 0; r < 4; r++) {
        size_t m = tm + wm * 128 + i * 16 + hi * 4 + r;
        size_t n = tn + wn * 64 + j * 16 + lo;
        float v = acc[i][j][r];
        size_t idx = m * 4096 + n;
        if constexpr (EPI == 0) {
          O[idx] = (bf16)(v / (1.0f + __expf(-v)));
        } else {
          O[idx] = (bf16)((float)O[idx] * v);
        }
      }
}

// ---------------- split-precision q/k projection GEMM with fused RoPE ----------------
// z=0: Q (BhQ/BlQ -> OhQ/OlQ), z=1: K
extern "C" __global__ __launch_bounds__(256, 2) void gemm_qk_kernel(
    const bf16* __restrict__ Ah, const bf16* __restrict__ Al,
    const bf16* __restrict__ BhQ, const bf16* __restrict__ BlQ,
    const bf16* __restrict__ BhK, const bf16* __restrict__ BlK,
    const float2* __restrict__ rope,
    bf16* __restrict__ OhQ, bf16* __restrict__ OlQ,
    bf16* __restrict__ OhK, bf16* __restrict__ OlK) {
  const bf16* Bh = blockIdx.z ? BhK : BhQ;
  const bf16* Bl = blockIdx.z ? BlK : BlQ;
  bf16* Oh = blockIdx.z ? OhK : OhQ;
  bf16* Ol = blockIdx.z ? OlK : OlQ;
  __shared__ alignas(16) bf16 Ahs[128 * 32], Als[128 * 32], Bhs[128 * 32], Bls[128 * 32];
  const int tid = threadIdx.x;
  const int lane = tid & 63, wave = tid >> 6;
  const int lo = lane & 15, hi = lane >> 4;
  const int wm = wave >> 1, wn = wave & 1;
  const size_t tm = (size_t)blockIdx.y * 128, tn = (size_t)blockIdx.x * 128;
  const int K = 1024;
  f32x4 acc[4][4] = {};
  for (int k0 = 0; k0 < K; k0 += 32) {
    __syncthreads();
#pragma unroll
    for (int i2 = 0; i2 < 2; i2++) {
      int p = tid + 256 * i2;
      int row = p >> 2;
      int kcl = (p & 3) ^ swz4(row);
      size_t ga = (tm + row) * (size_t)K + k0 + kcl * 8;
      size_t gb = (tn + row) * (size_t)K + k0 + kcl * 8;
      async_cp16((char*)Ahs + (size_t)p * 16, Ah + ga);
      async_cp16((char*)Als + (size_t)p * 16, Al + ga);
      async_cp16((char*)Bhs + (size_t)p * 16, Bh + gb);
      async_cp16((char*)Bls + (size_t)p * 16, Bl + gb);
    }
    __syncthreads();
    bf16x8 fah[4], fal[4], fbh[4], fbl[4];
#pragma unroll
    for (int i = 0; i < 4; i++) {
      int ra = wm * 64 + i * 16 + lo;
      int oa = ra * 64 + ((hi ^ swz4(ra)) << 4);
      fah[i] = *(const bf16x8*)((const char*)Ahs + oa);
      fal[i] = *(const bf16x8*)((const char*)Als + oa);
      int rb = wn * 64 + i * 16 + lo;
      int ob = rb * 64 + ((hi ^ swz4(rb)) << 4);
      fbh[i] = *(const bf16x8*)((const char*)Bhs + ob);
      fbl[i] = *(const bf16x8*)((const char*)Bls + ob);
    }
    __builtin_amdgcn_s_setprio(1);
#pragma unroll
    for (int i = 0; i < 4; i++)
#pragma unroll
      for (int j = 0; j < 4; j++) {
        f32x4 a = acc[i][j];
        a = mfma16(fah[i], fbh[j], a);
        a = mfma16(fah[i], fbl[j], a);
        a = mfma16(fal[i], fbh[j], a);
        acc[i][j] = a;
      }
    __builtin_amdgcn_s_setprio(0);
  }
#pragma unroll
  for (int i = 0; i < 4; i++)
#pragma unroll
    for (int j = 0; j < 4; j++)
#pragma unroll
      for (int r = 0; r < 4; r++) {
        float v = acc[i][j][r];
        float vp = __shfl_xor(v, 1, 64);
        size_t m = tm + wm * 64 + i * 16 + hi * 4 + r;
        size_t n = tn + wn * 64 + j * 16 + lo;
        int s = (int)(m & 1023);
        int pi = (int)((n & 63) >> 1);
        float2 cs = rope[s * 32 + pi];
        float res = (n & 1) ? (vp * cs.y + v * cs.x) : (v * cs.x - vp * cs.y);
        size_t idx = (((m >> 10) * 16 + (n >> 6)) * 1024 + (m & 1023)) * 64 + (n & 63);
        bf16 hb = (bf16)res;
        Oh[idx] = hb;
        Ol[idx] = (bf16)(res - (float)hb);
      }
}

// ---------------- flash attention (causal), LDS-staged K/V, 64-row Q block, 4 waves ----------------
extern "C" __global__ __launch_bounds__(256, 4) void flash_kernel(
    const bf16* __restrict__ qhi, const bf16* __restrict__ qlo,
    const bf16* __restrict__ khi, const bf16* __restrict__ klo,
    const bf16* __restrict__ vT, bf16* __restrict__ ctx) {
  const int bid = blockIdx.x;
  const int qb = bid >> 6;
  const int bh = bid & 63;
  const int tid = threadIdx.x;
  const int wave = tid >> 6, lane = tid & 63;
  const int lo = lane & 15, hi = lane >> 4;

  __shared__ alignas(16) bf16 Ksh[2][64][32];
  __shared__ alignas(16) bf16 Ksl[2][64][32];
  __shared__ alignas(16) bf16 Vs[2][64][32];
  __shared__ alignas(16) bf16 P[4][16][72];

  size_t qoff = ((size_t)bh * 1024 + qb * 64 + wave * 16 + lo) * 64;
  bf16x8 qh[2], ql[2];
#pragma unroll
  for (int ks = 0; ks < 2; ks++) {
    qh[ks] = *(const bf16x8*)(qhi + qoff + ks * 32 + hi * 8);
    ql[ks] = *(const bf16x8*)(qlo + qoff + ks * 32 + hi * 8);
  }

  const int srow = tid >> 2;
  const int scl = (tid & 3) ^ swz4(srow);
  const size_t kgb = (size_t)bh * 1024 * 64;
  const size_t vgb = ((size_t)bh * 64 + srow) * 1024;

  float mrun[4] = {-1e30f, -1e30f, -1e30f, -1e30f};
  float lrun[4] = {0.f, 0.f, 0.f, 0.f};
  f32x4 o[4] = {};
  const float scale = 0.125f;

  for (int kt = 0; kt <= qb; kt++) {
    __syncthreads();
#pragma unroll
    for (int i = 0; i < 2; i++) {
      int p = tid + 256 * i;
      size_t gk = kgb + (size_t)(kt * 64 + srow) * 64 + i * 32 + scl * 8;
      async_cp16((char*)Ksh + (size_t)p * 16, khi + gk);
      async_cp16((char*)Ksl + (size_t)p * 16, klo + gk);
      async_cp16((char*)Vs + (size_t)p * 16, vT + vgb + kt * 64 + i * 32 + scl * 8);
    }
    __syncthreads();

    f32x4 sv[4];
    __builtin_amdgcn_s_setprio(1);
#pragma unroll
    for (int nb = 0; nb < 4; nb++) {
      f32x4 a = {0.f, 0.f, 0.f, 0.f};
#pragma unroll
      for (int ks = 0; ks < 2; ks++) {
        int row = nb * 16 + lo;
        int off16 = (ks * 64 + row) * 4 + (hi ^ swz4(row));
        bf16x8 kh = *(const bf16x8*)((const char*)Ksh + off16 * 16);
        bf16x8 kl = *(const bf16x8*)((const char*)Ksl + off16 * 16);
        a = mfma16(qh[ks], kh, a);
        a = mfma16(qh[ks], kl, a);
        a = mfma16(ql[ks], kh, a);
      }
      sv[nb] = a;
    }
    __builtin_amdgcn_s_setprio(0);

    const bool mt = (kt == qb);
#pragma unroll
    for (int nb = 0; nb < 4; nb++)
#pragma unroll
      for (int r = 0; r < 4; r++) {
        float s = sv[nb][r] * scale;
        if (mt) {
          int kp = nb * 16 + lo;
          int qr = wave * 16 + hi * 4 + r;
          if (kp > qr) s = -1e30f;
        }
        sv[nb][r] = s;
      }
    float mnew[4], rs[4];
#pragma unroll
    for (int r = 0; r < 4; r++) {
      float mx = fmaxf(fmaxf(sv[0][r], sv[1][r]), fmaxf(sv[2][r], sv[3][r]));
#pragma unroll
      for (int d = 1; d < 16; d <<= 1) mx = fmaxf(mx, __shfl_xor(mx, d, 64));
      mnew[r] = fmaxf(mrun[r], mx);
      float sc = __expf(mrun[r] - mnew[r]);
      lrun[r] *= sc;
#pragma unroll
      for (int db = 0; db < 4; db++) o[db][r] *= sc;
      mrun[r] = mnew[r];
      rs[r] = 0.f;
    }
#pragma unroll
    for (int nb = 0; nb < 4; nb++)
#pragma unroll
      for (int r = 0; r < 4; r++) {
        float p = __expf(sv[nb][r] - mnew[r]);
        bf16 pb = (bf16)p;
        rs[r] += (float)pb;
        P[wave][hi * 4 + r][nb * 16 + lo] = pb;
      }
#pragma unroll
    for (int r = 0; r < 4; r++) {
      float t = rs[r];
#pragma unroll
      for (int d = 1; d < 16; d <<= 1) t += __shfl_xor(t, d, 64);
      lrun[r] += t;
    }
    bf16x8 pa[2];
#pragma unroll
    for (int ks = 0; ks < 2; ks++) pa[ks] = *(const bf16x8*)&P[wave][lo][ks * 32 + hi * 8];
    __builtin_amdgcn_s_setprio(1);
#pragma unroll
    for (int db = 0; db < 4; db++)
#pragma unroll
      for (int ks = 0; ks < 2; ks++) {
        int row = db * 16 + lo;
        int off16 = (ks * 64 + row) * 4 + (hi ^ swz4(row));
        bf16x8 vf = *(const bf16x8*)((const char*)Vs + off16 * 16);
        o[db] = mfma16(pa[ks], vf, o[db]);
      }
    __builtin_amdgcn_s_setprio(0);
  }
  int b = bh >> 4, h = bh & 15;
#pragma unroll
  for (int db = 0; db < 4; db++)
#pragma unroll
    for (int r = 0; r < 4; r++) {
      float val = o[db][r] / lrun[r];
      size_t row = (size_t)b * 1024 + qb * 64 + wave * 16 + hi * 4 + r;
      ctx[row * 1024 + h * 64 + db * 16 + lo] = (bf16)val;
    }
}

// ---------------- host launcher ----------------

extern "C" void kernel_launch(void* const* d_in, const int* in_sizes, int n_in,
                              void* d_out, int out_size, void* d_ws, size_t ws_size,
                              hipStream_t stream) {
  (void)in_sizes; (void)n_in; (void)out_size; (void)ws_size;
  const float* x  = (const float*)d_in[0];
  const float* wq = (const float*)d_in[1];
  const float* wk = (const float*)d_in[2];
  const float* wv = (const float*)d_in[3];
  const float* wo = (const float*)d_in[4];
  const float* w1 = (const float*)d_in[5];
  const float* w2 = (const float*)d_in[6];
  const float* w3 = (const float*)d_in[7];
  const float* g1 = (const float*)d_in[8];
  const float* g2 = (const float*)d_in[9];
  float* out = (float*)d_out;

  char* ws = (char*)d_ws;
  size_t off = 0;
  auto alloc = [&](size_t bytes) {
    char* p = ws + off;
    off += (bytes + 255) & ~(size_t)255;
    return p;
  };
  const size_t MB2 = 1024u * 1024u * 2u;      // 1M bf16
  const size_t MB8 = 4096u * 1024u * 2u;      // 4M bf16
  void* WQH = alloc(MB2);  void* WQL = alloc(MB2);
  void* WKH = alloc(MB2);  void* WKL = alloc(MB2);
  void* WVH = alloc(MB2);  void* WOH = alloc(MB2);
  void* W1H = alloc(MB8);  void* W3H = alloc(MB8);  void* W2H = alloc(MB8);
  void* ROPE = alloc(32768u * 8u);
  void* Y1H = alloc(MB8);  void* Y1L = alloc(MB8);
  void* QH = alloc(MB8);   void* QL = alloc(MB8);
  void* KH = alloc(MB8);   void* KL = alloc(MB8);
  void* VT = alloc(MB8);
  void* CTX = alloc(MB8);
  void* Y2H = alloc(MB8);
  void* GLU = QH;  // 32MB alias over QH,QL,KH,KL (dead after flash)

  dim3 blk(256);
  auto cvt = [&](const float* src, void* hi_, void* lo_, int n) {
    int n4 = n / 4;
    cvt_kernel<<<dim3((n4 + 255) / 256), blk, 0, stream>>>(
        src, (unsigned short*)hi_, (unsigned short*)lo_, n4);
  };
  cvt(wq, WQH, WQL, 1024 * 1024);
  cvt(wk, WKH, WKL, 1024 * 1024);
  cvt(wv, WVH, nullptr, 1024 * 1024);
  cvt(wo, WOH, nullptr, 1024 * 1024);
  cvt(w1, W1H, nullptr, 4096 * 1024);
  cvt(w3, W3H, nullptr, 4096 * 1024);
  cvt(w2, W2H, nullptr, 4096 * 1024);

  rope_table_kernel<<<dim3(128), blk, 0, stream>>>((float2*)ROPE);

  rmsnorm_kernel<<<dim3(4096), blk, 0, stream>>>(x, g1, (unsigned short*)Y1H,
                                                 (unsigned short*)Y1L);

  gemm_qk_kernel<<<dim3(8, 32, 2), blk, 0, stream>>>(
      (const bf16*)Y1H, (const bf16*)Y1L,
      (const bf16*)WQH, (const bf16*)WQL, (const bf16*)WKH, (const bf16*)WKL,
      (const float2*)ROPE,
      (bf16*)QH, (bf16*)QL, (bf16*)KH, (bf16*)KL);

  gemm_nt<0><<<dim3(8, 32), blk, 0, stream>>>(
      (const bf16*)Y1H, (const bf16*)WVH, 4096, 1024, 1024,
      nullptr, (bf16*)VT, nullptr);

  flash_kernel<<<dim3(1024), blk, 0, stream>>>(
      (const bf16*)QH, (const bf16*)QL, (const bf16*)KH, (const bf16*)KL,
      (const bf16*)VT, (bf16*)CTX);

  gemm_nt<1><<<dim3(8, 32), blk, 0, stream>>>(
      (const bf16*)CTX, (const bf16*)WOH, 4096, 1024, 1024,
      out, nullptr, x);

  rmsnorm_kernel<<<dim3(4096), blk, 0, stream>>>(out, g2, (unsigned short*)Y2H, nullptr);

  // SwiGLU up: SIL = silu(y2 @ w1^T); GLU = SIL * (y2 @ w3^T)  (in-place on GLU)
  gemm8<0><<<dim3(256), dim3(512), 0, stream>>>(
      (const bf16*)Y2H, (const bf16*)W1H, (bf16*)GLU);
  gemm8<1><<<dim3(256), dim3(512), 0, stream>>>(
      (const bf16*)Y2H, (const bf16*)W3H, (bf16*)GLU);

  gemm_nt<4><<<dim3(8, 32), blk, 0, stream>>>(
      (const bf16*)GLU, (const bf16*)W2H, 4096, 1024, 4096,
      out, nullptr, nullptr);
}

// Round 4
// 346.573 us; speedup vs baseline: 1.1111x; 1.1111x over previous
//
#include <hip/hip_runtime.h>

typedef __bf16 bf16;
typedef __attribute__((ext_vector_type(8))) __bf16 bf16x8;
typedef __attribute__((ext_vector_type(4))) float f32x4;

static __device__ __forceinline__ int swz4(int r) { return (r & 3) ^ ((r >> 2) & 3); }

static __device__ __forceinline__ void async_cp16(void* lds, const void* g) {
  __builtin_amdgcn_global_load_lds((__attribute__((address_space(1))) void*)g,
                                   (__attribute__((address_space(3))) void*)lds,
                                   16, 0, 0);
}

static __device__ __forceinline__ f32x4 mfma16(bf16x8 a, bf16x8 b, f32x4 c) {
  return __builtin_amdgcn_mfma_f32_16x16x32_bf16(a, b, c, 0, 0, 0);
}

static __device__ __forceinline__ unsigned short bfbits(float f) {
  bf16 b = (bf16)f;
  return __builtin_bit_cast(unsigned short, b);
}

// ---------------- fused prep: 7 weight conversions + rope table, one launch ----------------
extern "C" __global__ void prep_kernel(
    const float* __restrict__ wq, const float* __restrict__ wk,
    const float* __restrict__ wv, const float* __restrict__ wo,
    const float* __restrict__ w1, const float* __restrict__ w3,
    const float* __restrict__ w2,
    unsigned short* __restrict__ WQH, unsigned short* __restrict__ WQL,
    unsigned short* __restrict__ WKH, unsigned short* __restrict__ WKL,
    unsigned short* __restrict__ WVH, unsigned short* __restrict__ WOH,
    unsigned short* __restrict__ W1H, unsigned short* __restrict__ W3H,
    unsigned short* __restrict__ W2H, float2* __restrict__ rope) {
  const int seg = blockIdx.y;
  const int i = blockIdx.x * 256 + threadIdx.x;
  if (seg == 7) {  // rope table
    if (i >= 32768) return;
    int s = i >> 5, fi = i & 31;
    float inv_freq = powf(10000.0f, -(2.0f * (float)fi) / 64.0f);
    float ang = (float)s * inv_freq;
    float2 cs;
    cs.x = cosf(ang);
    cs.y = sinf(ang);
    rope[i] = cs;
    return;
  }
  const float* src;
  unsigned short* hi_;
  unsigned short* lo_ = nullptr;
  int n4;
  switch (seg) {
    case 0: src = wq; hi_ = WQH; lo_ = WQL; n4 = 262144; break;
    case 1: src = wk; hi_ = WKH; lo_ = WKL; n4 = 262144; break;
    case 2: src = wv; hi_ = WVH; n4 = 262144; break;
    case 3: src = wo; hi_ = WOH; n4 = 262144; break;
    case 4: src = w1; hi_ = W1H; n4 = 1048576; break;
    case 5: src = w3; hi_ = W3H; n4 = 1048576; break;
    default: src = w2; hi_ = W2H; n4 = 1048576; break;
  }
  if (i >= n4) return;
  float4 v = ((const float4*)src)[i];
  bf16 b0 = (bf16)v.x, b1 = (bf16)v.y, b2 = (bf16)v.z, b3 = (bf16)v.w;
  ushort4 oh;
  oh.x = __builtin_bit_cast(unsigned short, b0);
  oh.y = __builtin_bit_cast(unsigned short, b1);
  oh.z = __builtin_bit_cast(unsigned short, b2);
  oh.w = __builtin_bit_cast(unsigned short, b3);
  ((ushort4*)hi_)[i] = oh;
  if (lo_) {
    ushort4 ol;
    ol.x = bfbits(v.x - (float)b0);
    ol.y = bfbits(v.y - (float)b1);
    ol.z = bfbits(v.z - (float)b2);
    ol.w = bfbits(v.w - (float)b3);
    ((ushort4*)lo_)[i] = ol;
  }
}

extern "C" __global__ __launch_bounds__(256) void rmsnorm_kernel(
    const float* __restrict__ x, const float* __restrict__ g,
    unsigned short* __restrict__ yhi, unsigned short* __restrict__ ylo) {
  int row = blockIdx.x;
  int t = threadIdx.x;
  const float4 xv = *(const float4*)(x + (size_t)row * 1024 + t * 4);
  float ss = xv.x * xv.x + xv.y * xv.y + xv.z * xv.z + xv.w * xv.w;
#pragma unroll
  for (int d = 1; d < 64; d <<= 1) ss += __shfl_xor(ss, d, 64);
  __shared__ float red[4];
  if ((t & 63) == 0) red[t >> 6] = ss;
  __syncthreads();
  float tot = red[0] + red[1] + red[2] + red[3];
  float inv = 1.0f / sqrtf(tot * (1.0f / 1024.0f) + 1e-5f);
  const float4 gv = *(const float4*)(g + t * 4);
  float y0 = xv.x * gv.x * inv, y1 = xv.y * gv.y * inv;
  float y2 = xv.z * gv.z * inv, y3 = xv.w * gv.w * inv;
  bf16 b0 = (bf16)y0, b1 = (bf16)y1, b2 = (bf16)y2, b3 = (bf16)y3;
  ushort4 oh;
  oh.x = __builtin_bit_cast(unsigned short, b0);
  oh.y = __builtin_bit_cast(unsigned short, b1);
  oh.z = __builtin_bit_cast(unsigned short, b2);
  oh.w = __builtin_bit_cast(unsigned short, b3);
  ((ushort4*)yhi)[(size_t)row * 256 + t] = oh;
  if (ylo) {
    ushort4 ol;
    ol.x = bfbits(y0 - (float)b0);
    ol.y = bfbits(y1 - (float)b1);
    ol.z = bfbits(y2 - (float)b2);
    ol.w = bfbits(y3 - (float)b3);
    ((ushort4*)ylo)[(size_t)row * 256 + t] = ol;
  }
}

// ---------------- GEMM: C[M,N] = A[M,K(ldk)] * B[N,K(ldk)]^T, 128x128 tile, BK=32 ----------------
// blockIdx.z = K-slice (A,B advanced by z*K). EPI 0: vT store; EPI 1: +resF -> f32; EPI 5: atomicAdd f32
template <int EPI>
__global__ __launch_bounds__(256, 2) void gemm_nt(
    const bf16* __restrict__ A, const bf16* __restrict__ B, int M, int N, int K, int ldk,
    float* __restrict__ outF, bf16* __restrict__ outB,
    const float* __restrict__ resF) {
  A += (size_t)blockIdx.z * K;
  B += (size_t)blockIdx.z * K;
  __shared__ alignas(16) bf16 As[128 * 32];
  __shared__ alignas(16) bf16 Bs[128 * 32];
  const int tid = threadIdx.x;
  const int lane = tid & 63, wave = tid >> 6;
  const int lo = lane & 15, hi = lane >> 4;
  const int wm = wave >> 1, wn = wave & 1;
  const size_t tm = (size_t)blockIdx.y * 128, tn = (size_t)blockIdx.x * 128;
  f32x4 acc[4][4] = {};
  for (int k0 = 0; k0 < K; k0 += 32) {
    __syncthreads();
#pragma unroll
    for (int i2 = 0; i2 < 2; i2++) {
      int p = tid + 256 * i2;
      int row = p >> 2, kcp = p & 3;
      int kcl = kcp ^ swz4(row);
      async_cp16((char*)As + (size_t)p * 16, A + (tm + row) * (size_t)ldk + k0 + kcl * 8);
      async_cp16((char*)Bs + (size_t)p * 16, B + (tn + row) * (size_t)ldk + k0 + kcl * 8);
    }
    __syncthreads();
    bf16x8 fa[4], fb[4];
#pragma unroll
    for (int i = 0; i < 4; i++) {
      int ra = wm * 64 + i * 16 + lo;
      fa[i] = *(const bf16x8*)((const char*)As + ra * 64 + ((hi ^ swz4(ra)) << 4));
      int rb = wn * 64 + i * 16 + lo;
      fb[i] = *(const bf16x8*)((const char*)Bs + rb * 64 + ((hi ^ swz4(rb)) << 4));
    }
    __builtin_amdgcn_s_setprio(1);
#pragma unroll
    for (int i = 0; i < 4; i++)
#pragma unroll
      for (int j = 0; j < 4; j++) acc[i][j] = mfma16(fa[i], fb[j], acc[i][j]);
    __builtin_amdgcn_s_setprio(0);
  }
#pragma unroll
  for (int i = 0; i < 4; i++)
#pragma unroll
    for (int j = 0; j < 4; j++)
#pragma unroll
      for (int r = 0; r < 4; r++) {
        size_t m = tm + wm * 64 + i * 16 + hi * 4 + r;
        size_t n = tn + wn * 64 + j * 16 + lo;
        float v = acc[i][j][r];
        if constexpr (EPI == 0) {
          size_t idx = (((m >> 10) * 16 + (n >> 6)) * 64 + (n & 63)) * 1024 + (m & 1023);
          outB[idx] = (bf16)v;
        } else if constexpr (EPI == 1) {
          size_t idx = m * (size_t)N + n;
          outF[idx] = v + resF[idx];
        } else {
          atomicAdd(&outF[m * (size_t)N + n], v);
        }
      }
}

// ---------------- fused FFN-up: G = silu(A*B1^T) * (A*B3^T) ----------------
// 256M x 128N tile, BK=64, 8 waves (4M x 2N), 8-phase counted-vmcnt schedule, LDS 128KB.
extern "C" __global__ __launch_bounds__(512, 2) void gemm_up_kernel(
    const bf16* __restrict__ A, const bf16* __restrict__ B1,
    const bf16* __restrict__ B3, bf16* __restrict__ G) {
  __shared__ alignas(16) bf16 LA[2][2][256][32];   // [dbuf][khalf][row][col]
  __shared__ alignas(16) bf16 LB1[2][2][128][32];
  __shared__ alignas(16) bf16 LB3[2][2][128][32];
  const int tid = threadIdx.x;
  const int lane = tid & 63, wave = tid >> 6;
  const int lo = lane & 15, hi = lane >> 4;
  const int wm = wave >> 1, wn = wave & 1;  // 4M x 2N waves, each 64x64 per gemm
  const size_t tm = (size_t)blockIdx.y * 256, tn = (size_t)blockIdx.x * 128;

  f32x4 acc1[4][4] = {}, acc3[4][4] = {};

  auto stageA = [&](int kt, int kh, int buf) {
#pragma unroll
    for (int i2 = 0; i2 < 2; i2++) {
      int s = i2 * 512 + tid;
      int r = s >> 2, c = s & 3;
      async_cp16((char*)&LA[buf][kh][0][0] + (size_t)s * 16,
                 A + (tm + r) * (size_t)1024 + kt * 64 + kh * 32 + ((c ^ (r & 3)) << 3));
    }
  };
  auto stageB = [&](const bf16* __restrict__ Bsrc, bf16* dstBase, int kt, int kh) {
    int r = tid >> 2, c = tid & 3;
    async_cp16((char*)dstBase + (size_t)tid * 16,
               Bsrc + (tn + r) * (size_t)1024 + kt * 64 + kh * 32 + ((c ^ (r & 3)) << 3));
  };

  // prologue: t0 kh0 (4 loads), t0 kh1 (4), t1 kh0 (4); wait first 8
  stageA(0, 0, 0);
  stageB(B1, &LB1[0][0][0][0], 0, 0);
  stageB(B3, &LB3[0][0][0][0], 0, 0);
  stageA(0, 1, 0);
  stageB(B1, &LB1[0][1][0][0], 0, 1);
  stageB(B3, &LB3[0][1][0][0], 0, 1);
  stageA(1, 0, 1);
  stageB(B1, &LB1[1][0][0][0], 1, 0);
  stageB(B3, &LB3[1][0][0][0], 1, 0);
  asm volatile("s_waitcnt vmcnt(4)");
  __builtin_amdgcn_s_barrier();

  for (int t = 0; t < 16; t++) {
    const int p = t & 1;
    bf16x8 fa[4], fb[4];
    // ---- phase 0: kh0 x B1 ; prefetch A(t+1, kh1)
#pragma unroll
    for (int i = 0; i < 4; i++) {
      int ra = wm * 64 + i * 16 + lo;
      fa[i] = *(const bf16x8*)&LA[p][0][ra][(hi ^ (ra & 3)) << 3];
      int rb = wn * 64 + i * 16 + lo;
      fb[i] = *(const bf16x8*)&LB1[p][0][rb][(hi ^ (rb & 3)) << 3];
    }
    if (t + 1 < 16) stageA(t + 1, 1, p ^ 1);
    __builtin_amdgcn_s_barrier();
    asm volatile("s_waitcnt lgkmcnt(0)");
    __builtin_amdgcn_sched_barrier(0);
    __builtin_amdgcn_s_setprio(1);
#pragma unroll
    for (int i = 0; i < 4; i++)
#pragma unroll
      for (int j = 0; j < 4; j++) acc1[i][j] = mfma16(fa[i], fb[j], acc1[i][j]);
    __builtin_amdgcn_s_setprio(0);
    __builtin_amdgcn_s_barrier();
    // ---- phase 1: kh0 x B3 ; prefetch B1,B3(t+1, kh1)
#pragma unroll
    for (int i = 0; i < 4; i++) {
      int rb = wn * 64 + i * 16 + lo;
      fb[i] = *(const bf16x8*)&LB3[p][0][rb][(hi ^ (rb & 3)) << 3];
    }
    if (t + 1 < 16) {
      stageB(B1, &LB1[p ^ 1][1][0][0], t + 1, 1);
      stageB(B3, &LB3[p ^ 1][1][0][0], t + 1, 1);
    }
    __builtin_amdgcn_s_barrier();
    asm volatile("s_waitcnt lgkmcnt(0)");
    __builtin_amdgcn_sched_barrier(0);
    __builtin_amdgcn_s_setprio(1);
#pragma unroll
    for (int i = 0; i < 4; i++)
#pragma unroll
      for (int j = 0; j < 4; j++) acc3[i][j] = mfma16(fa[i], fb[j], acc3[i][j]);
    __builtin_amdgcn_s_setprio(0);
    __builtin_amdgcn_s_barrier();
    // ---- phase 2: kh1 x B1 ; prefetch A(t+2, kh0)
#pragma unroll
    for (int i = 0; i < 4; i++) {
      int ra = wm * 64 + i * 16 + lo;
      fa[i] = *(const bf16x8*)&LA[p][1][ra][(hi ^ (ra & 3)) << 3];
      int rb = wn * 64 + i * 16 + lo;
      fb[i] = *(const bf16x8*)&LB1[p][1][rb][(hi ^ (rb & 3)) << 3];
    }
    if (t + 2 < 16) stageA(t + 2, 0, p);
    __builtin_amdgcn_s_barrier();
    asm volatile("s_waitcnt lgkmcnt(0)");
    __builtin_amdgcn_sched_barrier(0);
    __builtin_amdgcn_s_setprio(1);
#pragma unroll
    for (int i = 0; i < 4; i++)
#pragma unroll
      for (int j = 0; j < 4; j++) acc1[i][j] = mfma16(fa[i], fb[j], acc1[i][j]);
    __builtin_amdgcn_s_setprio(0);
    __builtin_amdgcn_s_barrier();
    // ---- phase 3: kh1 x B3 ; prefetch B1,B3(t+2, kh0) ; tile gate
#pragma unroll
    for (int i = 0; i < 4; i++) {
      int rb = wn * 64 + i * 16 + lo;
      fb[i] = *(const bf16x8*)&LB3[p][1][rb][(hi ^ (rb & 3)) << 3];
    }
    if (t + 2 < 16) {
      stageB(B1, &LB1[p][0][0][0], t + 2, 0);
      stageB(B3, &LB3[p][0][0][0], t + 2, 0);
    }
    __builtin_amdgcn_s_barrier();
    asm volatile("s_waitcnt lgkmcnt(0)");
    __builtin_amdgcn_sched_barrier(0);
    __builtin_amdgcn_s_setprio(1);
#pragma unroll
    for (int i = 0; i < 4; i++)
#pragma unroll
      for (int j = 0; j < 4; j++) acc3[i][j] = mfma16(fa[i], fb[j], acc3[i][j]);
    __builtin_amdgcn_s_setprio(0);
    if (t + 2 < 16) {
      asm volatile("s_waitcnt vmcnt(4)");
    } else if (t + 1 < 16) {
      asm volatile("s_waitcnt vmcnt(0)");
    }
    __builtin_amdgcn_s_barrier();
  }

#pragma unroll
  for (int i = 0; i < 4; i++)
#pragma unroll
    for (int j = 0; j < 4; j++)
#pragma unroll
      for (int r = 0; r < 4; r++) {
        size_t m = tm + wm * 64 + i * 16 + hi * 4 + r;
        size_t n = tn + wn * 64 + j * 16 + lo;
        float v1 = acc1[i][j][r], v3 = acc3[i][j][r];
        G[m * 4096 + n] = (bf16)(v1 / (1.0f + __expf(-v1)) * v3);
      }
}

// ---------------- split-precision q/k projection GEMM with fused RoPE ----------------
extern "C" __global__ __launch_bounds__(256, 2) void gemm_qk_kernel(
    const bf16* __restrict__ Ah, const bf16* __restrict__ Al,
    const bf16* __restrict__ BhQ, const bf16* __restrict__ BlQ,
    const bf16* __restrict__ BhK, const bf16* __restrict__ BlK,
    const float2* __restrict__ rope,
    bf16* __restrict__ OhQ, bf16* __restrict__ OlQ,
    bf16* __restrict__ OhK, bf16* __restrict__ OlK) {
  const bf16* Bh = blockIdx.z ? BhK : BhQ;
  const bf16* Bl = blockIdx.z ? BlK : BlQ;
  bf16* Oh = blockIdx.z ? OhK : OhQ;
  bf16* Ol = blockIdx.z ? OlK : OlQ;
  __shared__ alignas(16) bf16 Ahs[128 * 32], Als[128 * 32], Bhs[128 * 32], Bls[128 * 32];
  const int tid = threadIdx.x;
  const int lane = tid & 63, wave = tid >> 6;
  const int lo = lane & 15, hi = lane >> 4;
  const int wm = wave >> 1, wn = wave & 1;
  const size_t tm = (size_t)blockIdx.y * 128, tn = (size_t)blockIdx.x * 128;
  const int K = 1024;
  f32x4 acc[4][4] = {};
  for (int k0 = 0; k0 < K; k0 += 32) {
    __syncthreads();
#pragma unroll
    for (int i2 = 0; i2 < 2; i2++) {
      int p = tid + 256 * i2;
      int row = p >> 2;
      int kcl = (p & 3) ^ swz4(row);
      size_t ga = (tm + row) * (size_t)K + k0 + kcl * 8;
      size_t gb = (tn + row) * (size_t)K + k0 + kcl * 8;
      async_cp16((char*)Ahs + (size_t)p * 16, Ah + ga);
      async_cp16((char*)Als + (size_t)p * 16, Al + ga);
      async_cp16((char*)Bhs + (size_t)p * 16, Bh + gb);
      async_cp16((char*)Bls + (size_t)p * 16, Bl + gb);
    }
    __syncthreads();
    bf16x8 fah[4], fal[4], fbh[4], fbl[4];
#pragma unroll
    for (int i = 0; i < 4; i++) {
      int ra = wm * 64 + i * 16 + lo;
      int oa = ra * 64 + ((hi ^ swz4(ra)) << 4);
      fah[i] = *(const bf16x8*)((const char*)Ahs + oa);
      fal[i] = *(const bf16x8*)((const char*)Als + oa);
      int rb = wn * 64 + i * 16 + lo;
      int ob = rb * 64 + ((hi ^ swz4(rb)) << 4);
      fbh[i] = *(const bf16x8*)((const char*)Bhs + ob);
      fbl[i] = *(const bf16x8*)((const char*)Bls + ob);
    }
    __builtin_amdgcn_s_setprio(1);
#pragma unroll
    for (int i = 0; i < 4; i++)
#pragma unroll
      for (int j = 0; j < 4; j++) {
        f32x4 a = acc[i][j];
        a = mfma16(fah[i], fbh[j], a);
        a = mfma16(fah[i], fbl[j], a);
        a = mfma16(fal[i], fbh[j], a);
        acc[i][j] = a;
      }
    __builtin_amdgcn_s_setprio(0);
  }
#pragma unroll
  for (int i = 0; i < 4; i++)
#pragma unroll
    for (int j = 0; j < 4; j++)
#pragma unroll
      for (int r = 0; r < 4; r++) {
        float v = acc[i][j][r];
        float vp = __shfl_xor(v, 1, 64);
        size_t m = tm + wm * 64 + i * 16 + hi * 4 + r;
        size_t n = tn + wn * 64 + j * 16 + lo;
        int s = (int)(m & 1023);
        int pi = (int)((n & 63) >> 1);
        float2 cs = rope[s * 32 + pi];
        float res = (n & 1) ? (vp * cs.y + v * cs.x) : (v * cs.x - vp * cs.y);
        size_t idx = (((m >> 10) * 16 + (n >> 6)) * 1024 + (m & 1023)) * 64 + (n & 63);
        bf16 hb = (bf16)res;
        Oh[idx] = hb;
        Ol[idx] = (bf16)(res - (float)hb);
      }
}

// ---------------- flash attention (causal), LDS-staged K/V, 64-row Q block, 4 waves ----------------
extern "C" __global__ __launch_bounds__(256, 4) void flash_kernel(
    const bf16* __restrict__ qhi, const bf16* __restrict__ qlo,
    const bf16* __restrict__ khi, const bf16* __restrict__ klo,
    const bf16* __restrict__ vT, bf16* __restrict__ ctx) {
  const int bid = blockIdx.x;
  const int qb = bid >> 6;
  const int bh = bid & 63;
  const int tid = threadIdx.x;
  const int wave = tid >> 6, lane = tid & 63;
  const int lo = lane & 15, hi = lane >> 4;

  __shared__ alignas(16) bf16 Ksh[2][64][32];
  __shared__ alignas(16) bf16 Ksl[2][64][32];
  __shared__ alignas(16) bf16 Vs[2][64][32];
  __shared__ alignas(16) bf16 P[4][16][72];

  size_t qoff = ((size_t)bh * 1024 + qb * 64 + wave * 16 + lo) * 64;
  bf16x8 qh[2], ql[2];
#pragma unroll
  for (int ks = 0; ks < 2; ks++) {
    qh[ks] = *(const bf16x8*)(qhi + qoff + ks * 32 + hi * 8);
    ql[ks] = *(const bf16x8*)(qlo + qoff + ks * 32 + hi * 8);
  }

  const int srow = tid >> 2;
  const int scl = (tid & 3) ^ swz4(srow);
  const size_t kgb = (size_t)bh * 1024 * 64;
  const size_t vgb = ((size_t)bh * 64 + srow) * 1024;

  float mrun[4] = {-1e30f, -1e30f, -1e30f, -1e30f};
  float lrun[4] = {0.f, 0.f, 0.f, 0.f};
  f32x4 o[4] = {};
  const float scale = 0.125f;

  for (int kt = 0; kt <= qb; kt++) {
    __syncthreads();
#pragma unroll
    for (int i = 0; i < 2; i++) {
      int p = tid + 256 * i;
      size_t gk = kgb + (size_t)(kt * 64 + srow) * 64 + i * 32 + scl * 8;
      async_cp16((char*)Ksh + (size_t)p * 16, khi + gk);
      async_cp16((char*)Ksl + (size_t)p * 16, klo + gk);
      async_cp16((char*)Vs + (size_t)p * 16, vT + vgb + kt * 64 + i * 32 + scl * 8);
    }
    __syncthreads();

    f32x4 sv[4];
    __builtin_amdgcn_s_setprio(1);
#pragma unroll
    for (int nb = 0; nb < 4; nb++) {
      f32x4 a = {0.f, 0.f, 0.f, 0.f};
#pragma unroll
      for (int ks = 0; ks < 2; ks++) {
        int row = nb * 16 + lo;
        int off16 = (ks * 64 + row) * 4 + (hi ^ swz4(row));
        bf16x8 kh = *(const bf16x8*)((const char*)Ksh + off16 * 16);
        bf16x8 kl = *(const bf16x8*)((const char*)Ksl + off16 * 16);
        a = mfma16(qh[ks], kh, a);
        a = mfma16(qh[ks], kl, a);
        a = mfma16(ql[ks], kh, a);
      }
      sv[nb] = a;
    }
    __builtin_amdgcn_s_setprio(0);

    const bool mt = (kt == qb);
#pragma unroll
    for (int nb = 0; nb < 4; nb++)
#pragma unroll
      for (int r = 0; r < 4; r++) {
        float s = sv[nb][r] * scale;
        if (mt) {
          int kp = nb * 16 + lo;
          int qr = wave * 16 + hi * 4 + r;
          if (kp > qr) s = -1e30f;
        }
        sv[nb][r] = s;
      }
    float mnew[4], rs[4];
#pragma unroll
    for (int r = 0; r < 4; r++) {
      float mx = fmaxf(fmaxf(sv[0][r], sv[1][r]), fmaxf(sv[2][r], sv[3][r]));
#pragma unroll
      for (int d = 1; d < 16; d <<= 1) mx = fmaxf(mx, __shfl_xor(mx, d, 64));
      mnew[r] = fmaxf(mrun[r], mx);
      float sc = __expf(mrun[r] - mnew[r]);
      lrun[r] *= sc;
#pragma unroll
      for (int db = 0; db < 4; db++) o[db][r] *= sc;
      mrun[r] = mnew[r];
      rs[r] = 0.f;
    }
#pragma unroll
    for (int nb = 0; nb < 4; nb++)
#pragma unroll
      for (int r = 0; r < 4; r++) {
        float p = __expf(sv[nb][r] - mnew[r]);
        bf16 pb = (bf16)p;
        rs[r] += (float)pb;
        P[wave][hi * 4 + r][nb * 16 + lo] = pb;
      }
#pragma unroll
    for (int r = 0; r < 4; r++) {
      float t = rs[r];
#pragma unroll
      for (int d = 1; d < 16; d <<= 1) t += __shfl_xor(t, d, 64);
      lrun[r] += t;
    }
    bf16x8 pa[2];
#pragma unroll
    for (int ks = 0; ks < 2; ks++) pa[ks] = *(const bf16x8*)&P[wave][lo][ks * 32 + hi * 8];
    __builtin_amdgcn_s_setprio(1);
#pragma unroll
    for (int db = 0; db < 4; db++)
#pragma unroll
      for (int ks = 0; ks < 2; ks++) {
        int row = db * 16 + lo;
        int off16 = (ks * 64 + row) * 4 + (hi ^ swz4(row));
        bf16x8 vf = *(const bf16x8*)((const char*)Vs + off16 * 16);
        o[db] = mfma16(pa[ks], vf, o[db]);
      }
    __builtin_amdgcn_s_setprio(0);
  }
  int b = bh >> 4, h = bh & 15;
#pragma unroll
  for (int db = 0; db < 4; db++)
#pragma unroll
    for (int r = 0; r < 4; r++) {
      float val = o[db][r] / lrun[r];
      size_t row = (size_t)b * 1024 + qb * 64 + wave * 16 + hi * 4 + r;
      ctx[row * 1024 + h * 64 + db * 16 + lo] = (bf16)val;
    }
}

// ---------------- host launcher ----------------

extern "C" void kernel_launch(void* const* d_in, const int* in_sizes, int n_in,
                              void* d_out, int out_size, void* d_ws, size_t ws_size,
                              hipStream_t stream) {
  (void)in_sizes; (void)n_in; (void)out_size; (void)ws_size;
  const float* x  = (const float*)d_in[0];
  const float* wq = (const float*)d_in[1];
  const float* wk = (const float*)d_in[2];
  const float* wv = (const float*)d_in[3];
  const float* wo = (const float*)d_in[4];
  const float* w1 = (const float*)d_in[5];
  const float* w2 = (const float*)d_in[6];
  const float* w3 = (const float*)d_in[7];
  const float* g1 = (const float*)d_in[8];
  const float* g2 = (const float*)d_in[9];
  float* out = (float*)d_out;

  char* ws = (char*)d_ws;
  size_t off = 0;
  auto alloc = [&](size_t bytes) {
    char* p = ws + off;
    off += (bytes + 255) & ~(size_t)255;
    return p;
  };
  const size_t MB2 = 1024u * 1024u * 2u;      // 1M bf16
  const size_t MB8 = 4096u * 1024u * 2u;      // 4M bf16
  void* WQH = alloc(MB2);  void* WQL = alloc(MB2);
  void* WKH = alloc(MB2);  void* WKL = alloc(MB2);
  void* WVH = alloc(MB2);  void* WOH = alloc(MB2);
  void* W1H = alloc(MB8);  void* W3H = alloc(MB8);  void* W2H = alloc(MB8);
  void* ROPE = alloc(32768u * 8u);
  void* Y1H = alloc(MB8);  void* Y1L = alloc(MB8);
  void* QH = alloc(MB8);   void* QL = alloc(MB8);
  void* KH = alloc(MB8);   void* KL = alloc(MB8);
  void* VT = alloc(MB8);
  void* CTX = alloc(MB8);
  void* Y2H = alloc(MB8);
  void* GLU = QH;  // 32MB alias over QH,QL,KH,KL (dead after flash)

  prep_kernel<<<dim3(4096, 8), dim3(256), 0, stream>>>(
      wq, wk, wv, wo, w1, w3, w2,
      (unsigned short*)WQH, (unsigned short*)WQL, (unsigned short*)WKH,
      (unsigned short*)WKL, (unsigned short*)WVH, (unsigned short*)WOH,
      (unsigned short*)W1H, (unsigned short*)W3H, (unsigned short*)W2H,
      (float2*)ROPE);

  rmsnorm_kernel<<<dim3(4096), dim3(256), 0, stream>>>(
      x, g1, (unsigned short*)Y1H, (unsigned short*)Y1L);

  gemm_qk_kernel<<<dim3(8, 32, 2), dim3(256), 0, stream>>>(
      (const bf16*)Y1H, (const bf16*)Y1L,
      (const bf16*)WQH, (const bf16*)WQL, (const bf16*)WKH, (const bf16*)WKL,
      (const float2*)ROPE,
      (bf16*)QH, (bf16*)QL, (bf16*)KH, (bf16*)KL);

  gemm_nt<0><<<dim3(8, 32), dim3(256), 0, stream>>>(
      (const bf16*)Y1H, (const bf16*)WVH, 4096, 1024, 1024, 1024,
      nullptr, (bf16*)VT, nullptr);

  flash_kernel<<<dim3(1024), dim3(256), 0, stream>>>(
      (const bf16*)QH, (const bf16*)QL, (const bf16*)KH, (const bf16*)KL,
      (const bf16*)VT, (bf16*)CTX);

  gemm_nt<1><<<dim3(8, 32), dim3(256), 0, stream>>>(
      (const bf16*)CTX, (const bf16*)WOH, 4096, 1024, 1024, 1024,
      out, nullptr, x);

  rmsnorm_kernel<<<dim3(4096), dim3(256), 0, stream>>>(
      out, g2, (unsigned short*)Y2H, nullptr);

  // fused SwiGLU up-projection (single kernel, both w1 and w3)
  gemm_up_kernel<<<dim3(32, 16), dim3(512), 0, stream>>>(
      (const bf16*)Y2H, (const bf16*)W1H, (const bf16*)W3H, (bf16*)GLU);

  // down-projection: split-K=4, atomic f32 accumulate into out
  gemm_nt<5><<<dim3(8, 32, 4), dim3(256), 0, stream>>>(
      (const bf16*)GLU, (const bf16*)W2H, 4096, 1024, 1024, 4096,
      out, nullptr, nullptr);
}

// Round 5
// 330.630 us; speedup vs baseline: 1.1647x; 1.0482x over previous
//
#include <hip/hip_runtime.h>

typedef __bf16 bf16;
typedef __attribute__((ext_vector_type(8))) __bf16 bf16x8;
typedef __attribute__((ext_vector_type(4))) float f32x4;

// LDS chunk swizzle for [R][32]-bf16 tiles (64B rows): rows r,r+2 share a 16-bank
// half; reads touch 16 consecutive rows at chunk hi^swz4(r). (r>>1)&3 spreads the
// 8 same-parity rows 2x over the 4 chunk slots -> 2-way (free). (r&3) was 4-way.
static __device__ __forceinline__ int swz4(int r) { return (r >> 1) & 3; }

static __device__ __forceinline__ void async_cp16(void* lds, const void* g) {
  __builtin_amdgcn_global_load_lds((__attribute__((address_space(1))) void*)g,
                                   (__attribute__((address_space(3))) void*)lds,
                                   16, 0, 0);
}

static __device__ __forceinline__ f32x4 mfma16(bf16x8 a, bf16x8 b, f32x4 c) {
  return __builtin_amdgcn_mfma_f32_16x16x32_bf16(a, b, c, 0, 0, 0);
}

static __device__ __forceinline__ unsigned short bfbits(float f) {
  bf16 b = (bf16)f;
  return __builtin_bit_cast(unsigned short, b);
}

// ---------------- fused prep: 7 weight conversions + rope table, one launch ----------------
extern "C" __global__ void prep_kernel(
    const float* __restrict__ wq, const float* __restrict__ wk,
    const float* __restrict__ wv, const float* __restrict__ wo,
    const float* __restrict__ w1, const float* __restrict__ w3,
    const float* __restrict__ w2,
    unsigned short* __restrict__ WQH, unsigned short* __restrict__ WQL,
    unsigned short* __restrict__ WKH, unsigned short* __restrict__ WKL,
    unsigned short* __restrict__ WVH, unsigned short* __restrict__ WOH,
    unsigned short* __restrict__ W1H, unsigned short* __restrict__ W3H,
    unsigned short* __restrict__ W2H, float2* __restrict__ rope) {
  const int seg = blockIdx.y;
  const int i = blockIdx.x * 256 + threadIdx.x;
  if (seg == 7) {  // rope table
    if (i >= 32768) return;
    int s = i >> 5, fi = i & 31;
    float inv_freq = powf(10000.0f, -(2.0f * (float)fi) / 64.0f);
    float ang = (float)s * inv_freq;
    float2 cs;
    cs.x = cosf(ang);
    cs.y = sinf(ang);
    rope[i] = cs;
    return;
  }
  const float* src;
  unsigned short* hi_;
  unsigned short* lo_ = nullptr;
  int n4;
  switch (seg) {
    case 0: src = wq; hi_ = WQH; lo_ = WQL; n4 = 262144; break;
    case 1: src = wk; hi_ = WKH; lo_ = WKL; n4 = 262144; break;
    case 2: src = wv; hi_ = WVH; n4 = 262144; break;
    case 3: src = wo; hi_ = WOH; n4 = 262144; break;
    case 4: src = w1; hi_ = W1H; n4 = 1048576; break;
    case 5: src = w3; hi_ = W3H; n4 = 1048576; break;
    default: src = w2; hi_ = W2H; n4 = 1048576; break;
  }
  if (i >= n4) return;
  float4 v = ((const float4*)src)[i];
  bf16 b0 = (bf16)v.x, b1 = (bf16)v.y, b2 = (bf16)v.z, b3 = (bf16)v.w;
  ushort4 oh;
  oh.x = __builtin_bit_cast(unsigned short, b0);
  oh.y = __builtin_bit_cast(unsigned short, b1);
  oh.z = __builtin_bit_cast(unsigned short, b2);
  oh.w = __builtin_bit_cast(unsigned short, b3);
  ((ushort4*)hi_)[i] = oh;
  if (lo_) {
    ushort4 ol;
    ol.x = bfbits(v.x - (float)b0);
    ol.y = bfbits(v.y - (float)b1);
    ol.z = bfbits(v.z - (float)b2);
    ol.w = bfbits(v.w - (float)b3);
    ((ushort4*)lo_)[i] = ol;
  }
}

extern "C" __global__ __launch_bounds__(256) void rmsnorm_kernel(
    const float* __restrict__ x, const float* __restrict__ g,
    unsigned short* __restrict__ yhi, unsigned short* __restrict__ ylo) {
  int row = blockIdx.x;
  int t = threadIdx.x;
  const float4 xv = *(const float4*)(x + (size_t)row * 1024 + t * 4);
  float ss = xv.x * xv.x + xv.y * xv.y + xv.z * xv.z + xv.w * xv.w;
#pragma unroll
  for (int d = 1; d < 64; d <<= 1) ss += __shfl_xor(ss, d, 64);
  __shared__ float red[4];
  if ((t & 63) == 0) red[t >> 6] = ss;
  __syncthreads();
  float tot = red[0] + red[1] + red[2] + red[3];
  float inv = 1.0f / sqrtf(tot * (1.0f / 1024.0f) + 1e-5f);
  const float4 gv = *(const float4*)(g + t * 4);
  float y0 = xv.x * gv.x * inv, y1 = xv.y * gv.y * inv;
  float y2 = xv.z * gv.z * inv, y3 = xv.w * gv.w * inv;
  bf16 b0 = (bf16)y0, b1 = (bf16)y1, b2 = (bf16)y2, b3 = (bf16)y3;
  ushort4 oh;
  oh.x = __builtin_bit_cast(unsigned short, b0);
  oh.y = __builtin_bit_cast(unsigned short, b1);
  oh.z = __builtin_bit_cast(unsigned short, b2);
  oh.w = __builtin_bit_cast(unsigned short, b3);
  ((ushort4*)yhi)[(size_t)row * 256 + t] = oh;
  if (ylo) {
    ushort4 ol;
    ol.x = bfbits(y0 - (float)b0);
    ol.y = bfbits(y1 - (float)b1);
    ol.z = bfbits(y2 - (float)b2);
    ol.w = bfbits(y3 - (float)b3);
    ((ushort4*)ylo)[(size_t)row * 256 + t] = ol;
  }
}

// ---------------- GEMM: C[M,N] = A[M,K(ldk)] * B[N,K(ldk)]^T, 128x128 tile, BK=32 ----------------
// Flat grid, XCD-chunked decode: xcd = bid&7 owns M-slab (4 y-tiles) for all x,z.
// z = K-slice (A,B advanced by z*K). EPI 0: vT store; EPI 1: +resF -> f32; EPI 5: atomicAdd f32
template <int EPI>
__global__ __launch_bounds__(256, 2) void gemm_nt(
    const bf16* __restrict__ A, const bf16* __restrict__ B, int N, int K, int ldk,
    float* __restrict__ outF, bf16* __restrict__ outB,
    const float* __restrict__ resF) {
  const int bid = blockIdx.x;
  const int xcd = bid & 7, sq = bid >> 3;
  const int z = sq >> 5;          // 0 for 256-block launches; 0..3 for split-K
  const int rem = sq & 31;
  const size_t tm = (size_t)(xcd * 4 + (rem >> 3)) * 128;
  const size_t tn = (size_t)(rem & 7) * 128;
  A += (size_t)z * K;
  B += (size_t)z * K;
  __shared__ alignas(16) bf16 As[128 * 32];
  __shared__ alignas(16) bf16 Bs[128 * 32];
  const int tid = threadIdx.x;
  const int lane = tid & 63, wave = tid >> 6;
  const int lo = lane & 15, hi = lane >> 4;
  const int wm = wave >> 1, wn = wave & 1;
  f32x4 acc[4][4] = {};
  for (int k0 = 0; k0 < K; k0 += 32) {
    __syncthreads();
#pragma unroll
    for (int i2 = 0; i2 < 2; i2++) {
      int p = tid + 256 * i2;
      int row = p >> 2, kcp = p & 3;
      int kcl = kcp ^ swz4(row);
      async_cp16((char*)As + (size_t)p * 16, A + (tm + row) * (size_t)ldk + k0 + kcl * 8);
      async_cp16((char*)Bs + (size_t)p * 16, B + (tn + row) * (size_t)ldk + k0 + kcl * 8);
    }
    __syncthreads();
    bf16x8 fa[4], fb[4];
#pragma unroll
    for (int i = 0; i < 4; i++) {
      int ra = wm * 64 + i * 16 + lo;
      fa[i] = *(const bf16x8*)((const char*)As + ra * 64 + ((hi ^ swz4(ra)) << 4));
      int rb = wn * 64 + i * 16 + lo;
      fb[i] = *(const bf16x8*)((const char*)Bs + rb * 64 + ((hi ^ swz4(rb)) << 4));
    }
    __builtin_amdgcn_s_setprio(1);
#pragma unroll
    for (int i = 0; i < 4; i++)
#pragma unroll
      for (int j = 0; j < 4; j++) acc[i][j] = mfma16(fa[i], fb[j], acc[i][j]);
    __builtin_amdgcn_s_setprio(0);
  }
#pragma unroll
  for (int i = 0; i < 4; i++)
#pragma unroll
    for (int j = 0; j < 4; j++)
#pragma unroll
      for (int r = 0; r < 4; r++) {
        size_t m = tm + wm * 64 + i * 16 + hi * 4 + r;
        size_t n = tn + wn * 64 + j * 16 + lo;
        float v = acc[i][j][r];
        if constexpr (EPI == 0) {
          size_t idx = (((m >> 10) * 16 + (n >> 6)) * 64 + (n & 63)) * 1024 + (m & 1023);
          outB[idx] = (bf16)v;
        } else if constexpr (EPI == 1) {
          size_t idx = m * (size_t)N + n;
          outF[idx] = v + resF[idx];
        } else {
          atomicAdd(&outF[m * (size_t)N + n], v);
        }
      }
}

// ---------------- fused FFN-up: G = silu(A*B1^T) * (A*B3^T) ----------------
// 256M x 128N tile, BK=64, 8 waves (4M x 2N), 8-phase counted-vmcnt schedule, LDS 128KB.
// XCD-chunked: xcd owns N-slab of 4 x-tiles (B1+B3 slab 2.1MB pinned in its L2).
extern "C" __global__ __launch_bounds__(512, 2) void gemm_up_kernel(
    const bf16* __restrict__ A, const bf16* __restrict__ B1,
    const bf16* __restrict__ B3, bf16* __restrict__ G) {
  __shared__ alignas(16) bf16 LA[2][2][256][32];   // [dbuf][khalf][row][col]
  __shared__ alignas(16) bf16 LB1[2][2][128][32];
  __shared__ alignas(16) bf16 LB3[2][2][128][32];
  const int tid = threadIdx.x;
  const int lane = tid & 63, wave = tid >> 6;
  const int lo = lane & 15, hi = lane >> 4;
  const int wm = wave >> 1, wn = wave & 1;  // 4M x 2N waves, each 64x64 per gemm
  const int bid = blockIdx.x;
  const int xcd = bid & 7, sq = bid >> 3;    // 512 blocks: sq 0..63
  const size_t tn = (size_t)(xcd * 4 + (sq & 3)) * 128;
  const size_t tm = (size_t)(sq >> 2) * 256;

  f32x4 acc1[4][4] = {}, acc3[4][4] = {};

  auto stageA = [&](int kt, int kh, int buf) {
#pragma unroll
    for (int i2 = 0; i2 < 2; i2++) {
      int s = i2 * 512 + tid;
      int r = s >> 2, c = s & 3;
      async_cp16((char*)&LA[buf][kh][0][0] + (size_t)s * 16,
                 A + (tm + r) * (size_t)1024 + kt * 64 + kh * 32 + ((c ^ swz4(r)) << 3));
    }
  };
  auto stageB = [&](const bf16* __restrict__ Bsrc, bf16* dstBase, int kt, int kh) {
    int r = tid >> 2, c = tid & 3;
    async_cp16((char*)dstBase + (size_t)tid * 16,
               Bsrc + (tn + r) * (size_t)1024 + kt * 64 + kh * 32 + ((c ^ swz4(r)) << 3));
  };

  // prologue: t0 kh0 (4 loads), t0 kh1 (4), t1 kh0 (4); wait first 8
  stageA(0, 0, 0);
  stageB(B1, &LB1[0][0][0][0], 0, 0);
  stageB(B3, &LB3[0][0][0][0], 0, 0);
  stageA(0, 1, 0);
  stageB(B1, &LB1[0][1][0][0], 0, 1);
  stageB(B3, &LB3[0][1][0][0], 0, 1);
  stageA(1, 0, 1);
  stageB(B1, &LB1[1][0][0][0], 1, 0);
  stageB(B3, &LB3[1][0][0][0], 1, 0);
  asm volatile("s_waitcnt vmcnt(4)");
  __builtin_amdgcn_s_barrier();

  for (int t = 0; t < 16; t++) {
    const int p = t & 1;
    bf16x8 fa[4], fb[4];
    // ---- phase 0: kh0 x B1 ; prefetch A(t+1, kh1)
#pragma unroll
    for (int i = 0; i < 4; i++) {
      int ra = wm * 64 + i * 16 + lo;
      fa[i] = *(const bf16x8*)&LA[p][0][ra][(hi ^ swz4(ra)) << 3];
      int rb = wn * 64 + i * 16 + lo;
      fb[i] = *(const bf16x8*)&LB1[p][0][rb][(hi ^ swz4(rb)) << 3];
    }
    if (t + 1 < 16) stageA(t + 1, 1, p ^ 1);
    __builtin_amdgcn_s_barrier();
    asm volatile("s_waitcnt lgkmcnt(0)");
    __builtin_amdgcn_sched_barrier(0);
    __builtin_amdgcn_s_setprio(1);
#pragma unroll
    for (int i = 0; i < 4; i++)
#pragma unroll
      for (int j = 0; j < 4; j++) acc1[i][j] = mfma16(fa[i], fb[j], acc1[i][j]);
    __builtin_amdgcn_s_setprio(0);
    __builtin_amdgcn_s_barrier();
    // ---- phase 1: kh0 x B3 ; prefetch B1,B3(t+1, kh1)
#pragma unroll
    for (int i = 0; i < 4; i++) {
      int rb = wn * 64 + i * 16 + lo;
      fb[i] = *(const bf16x8*)&LB3[p][0][rb][(hi ^ swz4(rb)) << 3];
    }
    if (t + 1 < 16) {
      stageB(B1, &LB1[p ^ 1][1][0][0], t + 1, 1);
      stageB(B3, &LB3[p ^ 1][1][0][0], t + 1, 1);
    }
    __builtin_amdgcn_s_barrier();
    asm volatile("s_waitcnt lgkmcnt(0)");
    __builtin_amdgcn_sched_barrier(0);
    __builtin_amdgcn_s_setprio(1);
#pragma unroll
    for (int i = 0; i < 4; i++)
#pragma unroll
      for (int j = 0; j < 4; j++) acc3[i][j] = mfma16(fa[i], fb[j], acc3[i][j]);
    __builtin_amdgcn_s_setprio(0);
    __builtin_amdgcn_s_barrier();
    // ---- phase 2: kh1 x B1 ; prefetch A(t+2, kh0)
#pragma unroll
    for (int i = 0; i < 4; i++) {
      int ra = wm * 64 + i * 16 + lo;
      fa[i] = *(const bf16x8*)&LA[p][1][ra][(hi ^ swz4(ra)) << 3];
      int rb = wn * 64 + i * 16 + lo;
      fb[i] = *(const bf16x8*)&LB1[p][1][rb][(hi ^ swz4(rb)) << 3];
    }
    if (t + 2 < 16) stageA(t + 2, 0, p);
    __builtin_amdgcn_s_barrier();
    asm volatile("s_waitcnt lgkmcnt(0)");
    __builtin_amdgcn_sched_barrier(0);
    __builtin_amdgcn_s_setprio(1);
#pragma unroll
    for (int i = 0; i < 4; i++)
#pragma unroll
      for (int j = 0; j < 4; j++) acc1[i][j] = mfma16(fa[i], fb[j], acc1[i][j]);
    __builtin_amdgcn_s_setprio(0);
    __builtin_amdgcn_s_barrier();
    // ---- phase 3: kh1 x B3 ; prefetch B1,B3(t+2, kh0) ; tile gate
#pragma unroll
    for (int i = 0; i < 4; i++) {
      int rb = wn * 64 + i * 16 + lo;
      fb[i] = *(const bf16x8*)&LB3[p][1][rb][(hi ^ swz4(rb)) << 3];
    }
    if (t + 2 < 16) {
      stageB(B1, &LB1[p][0][0][0], t + 2, 0);
      stageB(B3, &LB3[p][0][0][0], t + 2, 0);
    }
    __builtin_amdgcn_s_barrier();
    asm volatile("s_waitcnt lgkmcnt(0)");
    __builtin_amdgcn_sched_barrier(0);
    __builtin_amdgcn_s_setprio(1);
#pragma unroll
    for (int i = 0; i < 4; i++)
#pragma unroll
      for (int j = 0; j < 4; j++) acc3[i][j] = mfma16(fa[i], fb[j], acc3[i][j]);
    __builtin_amdgcn_s_setprio(0);
    if (t + 2 < 16) {
      asm volatile("s_waitcnt vmcnt(4)");
    } else if (t + 1 < 16) {
      asm volatile("s_waitcnt vmcnt(0)");
    }
    __builtin_amdgcn_s_barrier();
  }

#pragma unroll
  for (int i = 0; i < 4; i++)
#pragma unroll
    for (int j = 0; j < 4; j++)
#pragma unroll
      for (int r = 0; r < 4; r++) {
        size_t m = tm + wm * 64 + i * 16 + hi * 4 + r;
        size_t n = tn + wn * 64 + j * 16 + lo;
        float v1 = acc1[i][j][r], v3 = acc3[i][j][r];
        G[m * 4096 + n] = (bf16)(v1 / (1.0f + __expf(-v1)) * v3);
      }
}

// ---------------- split-precision q/k projection GEMM with fused RoPE ----------------
// Flat grid 512; z = sq>>5 selects Q (0) / K (1); XCD-chunked M-slab like gemm_nt.
extern "C" __global__ __launch_bounds__(256, 2) void gemm_qk_kernel(
    const bf16* __restrict__ Ah, const bf16* __restrict__ Al,
    const bf16* __restrict__ BhQ, const bf16* __restrict__ BlQ,
    const bf16* __restrict__ BhK, const bf16* __restrict__ BlK,
    const float2* __restrict__ rope,
    bf16* __restrict__ OhQ, bf16* __restrict__ OlQ,
    bf16* __restrict__ OhK, bf16* __restrict__ OlK) {
  const int bid = blockIdx.x;
  const int xcd = bid & 7, sq = bid >> 3;
  const int zqk = sq >> 5;
  const int rem = sq & 31;
  const size_t tm = (size_t)(xcd * 4 + (rem >> 3)) * 128;
  const size_t tn = (size_t)(rem & 7) * 128;
  const bf16* Bh = zqk ? BhK : BhQ;
  const bf16* Bl = zqk ? BlK : BlQ;
  bf16* Oh = zqk ? OhK : OhQ;
  bf16* Ol = zqk ? OlK : OlQ;
  __shared__ alignas(16) bf16 Ahs[128 * 32], Als[128 * 32], Bhs[128 * 32], Bls[128 * 32];
  const int tid = threadIdx.x;
  const int lane = tid & 63, wave = tid >> 6;
  const int lo = lane & 15, hi = lane >> 4;
  const int wm = wave >> 1, wn = wave & 1;
  const int K = 1024;
  f32x4 acc[4][4] = {};
  for (int k0 = 0; k0 < K; k0 += 32) {
    __syncthreads();
#pragma unroll
    for (int i2 = 0; i2 < 2; i2++) {
      int p = tid + 256 * i2;
      int row = p >> 2;
      int kcl = (p & 3) ^ swz4(row);
      size_t ga = (tm + row) * (size_t)K + k0 + kcl * 8;
      size_t gb = (tn + row) * (size_t)K + k0 + kcl * 8;
      async_cp16((char*)Ahs + (size_t)p * 16, Ah + ga);
      async_cp16((char*)Als + (size_t)p * 16, Al + ga);
      async_cp16((char*)Bhs + (size_t)p * 16, Bh + gb);
      async_cp16((char*)Bls + (size_t)p * 16, Bl + gb);
    }
    __syncthreads();
    bf16x8 fah[4], fal[4], fbh[4], fbl[4];
#pragma unroll
    for (int i = 0; i < 4; i++) {
      int ra = wm * 64 + i * 16 + lo;
      int oa = ra * 64 + ((hi ^ swz4(ra)) << 4);
      fah[i] = *(const bf16x8*)((const char*)Ahs + oa);
      fal[i] = *(const bf16x8*)((const char*)Als + oa);
      int rb = wn * 64 + i * 16 + lo;
      int ob = rb * 64 + ((hi ^ swz4(rb)) << 4);
      fbh[i] = *(const bf16x8*)((const char*)Bhs + ob);
      fbl[i] = *(const bf16x8*)((const char*)Bls + ob);
    }
    __builtin_amdgcn_s_setprio(1);
#pragma unroll
    for (int i = 0; i < 4; i++)
#pragma unroll
      for (int j = 0; j < 4; j++) {
        f32x4 a = acc[i][j];
        a = mfma16(fah[i], fbh[j], a);
        a = mfma16(fah[i], fbl[j], a);
        a = mfma16(fal[i], fbh[j], a);
        acc[i][j] = a;
      }
    __builtin_amdgcn_s_setprio(0);
  }
#pragma unroll
  for (int i = 0; i < 4; i++)
#pragma unroll
    for (int j = 0; j < 4; j++)
#pragma unroll
      for (int r = 0; r < 4; r++) {
        float v = acc[i][j][r];
        float vp = __shfl_xor(v, 1, 64);
        size_t m = tm + wm * 64 + i * 16 + hi * 4 + r;
        size_t n = tn + wn * 64 + j * 16 + lo;
        int s = (int)(m & 1023);
        int pi = (int)((n & 63) >> 1);
        float2 cs = rope[s * 32 + pi];
        float res = (n & 1) ? (vp * cs.y + v * cs.x) : (v * cs.x - vp * cs.y);
        size_t idx = (((m >> 10) * 16 + (n >> 6)) * 1024 + (m & 1023)) * 64 + (n & 63);
        bf16 hb = (bf16)res;
        Oh[idx] = hb;
        Ol[idx] = (bf16)(res - (float)hb);
      }
}

// ---------------- flash attention (causal), LDS-staged K/V, 64-row Q block, 4 waves ----------------
extern "C" __global__ __launch_bounds__(256, 4) void flash_kernel(
    const bf16* __restrict__ qhi, const bf16* __restrict__ qlo,
    const bf16* __restrict__ khi, const bf16* __restrict__ klo,
    const bf16* __restrict__ vT, bf16* __restrict__ ctx) {
  const int bid = blockIdx.x;
  const int qb = bid >> 6;
  const int bh = bid & 63;
  const int tid = threadIdx.x;
  const int wave = tid >> 6, lane = tid & 63;
  const int lo = lane & 15, hi = lane >> 4;

  __shared__ alignas(16) bf16 Ksh[2][64][32];
  __shared__ alignas(16) bf16 Ksl[2][64][32];
  __shared__ alignas(16) bf16 Vs[2][64][32];
  __shared__ alignas(16) bf16 P[4][16][72];

  size_t qoff = ((size_t)bh * 1024 + qb * 64 + wave * 16 + lo) * 64;
  bf16x8 qh[2], ql[2];
#pragma unroll
  for (int ks = 0; ks < 2; ks++) {
    qh[ks] = *(const bf16x8*)(qhi + qoff + ks * 32 + hi * 8);
    ql[ks] = *(const bf16x8*)(qlo + qoff + ks * 32 + hi * 8);
  }

  const int srow = tid >> 2;
  const int scl = (tid & 3) ^ swz4(srow);
  const size_t kgb = (size_t)bh * 1024 * 64;
  const size_t vgb = ((size_t)bh * 64 + srow) * 1024;

  float mrun[4] = {-1e30f, -1e30f, -1e30f, -1e30f};
  float lrun[4] = {0.f, 0.f, 0.f, 0.f};
  f32x4 o[4] = {};
  const float scale = 0.125f;

  for (int kt = 0; kt <= qb; kt++) {
    __syncthreads();
#pragma unroll
    for (int i = 0; i < 2; i++) {
      int p = tid + 256 * i;
      size_t gk = kgb + (size_t)(kt * 64 + srow) * 64 + i * 32 + scl * 8;
      async_cp16((char*)Ksh + (size_t)p * 16, khi + gk);
      async_cp16((char*)Ksl + (size_t)p * 16, klo + gk);
      async_cp16((char*)Vs + (size_t)p * 16, vT + vgb + kt * 64 + i * 32 + scl * 8);
    }
    __syncthreads();

    f32x4 sv[4];
    __builtin_amdgcn_s_setprio(1);
#pragma unroll
    for (int nb = 0; nb < 4; nb++) {
      f32x4 a = {0.f, 0.f, 0.f, 0.f};
#pragma unroll
      for (int ks = 0; ks < 2; ks++) {
        int row = nb * 16 + lo;
        int off16 = (ks * 64 + row) * 4 + (hi ^ swz4(row));
        bf16x8 kh = *(const bf16x8*)((const char*)Ksh + off16 * 16);
        bf16x8 kl = *(const bf16x8*)((const char*)Ksl + off16 * 16);
        a = mfma16(qh[ks], kh, a);
        a = mfma16(qh[ks], kl, a);
        a = mfma16(ql[ks], kh, a);
      }
      sv[nb] = a;
    }
    __builtin_amdgcn_s_setprio(0);

    const bool mt = (kt == qb);
#pragma unroll
    for (int nb = 0; nb < 4; nb++)
#pragma unroll
      for (int r = 0; r < 4; r++) {
        float s = sv[nb][r] * scale;
        if (mt) {
          int kp = nb * 16 + lo;
          int qr = wave * 16 + hi * 4 + r;
          if (kp > qr) s = -1e30f;
        }
        sv[nb][r] = s;
      }
    float mnew[4], rs[4];
#pragma unroll
    for (int r = 0; r < 4; r++) {
      float mx = fmaxf(fmaxf(sv[0][r], sv[1][r]), fmaxf(sv[2][r], sv[3][r]));
#pragma unroll
      for (int d = 1; d < 16; d <<= 1) mx = fmaxf(mx, __shfl_xor(mx, d, 64));
      mnew[r] = fmaxf(mrun[r], mx);
      float sc = __expf(mrun[r] - mnew[r]);
      lrun[r] *= sc;
#pragma unroll
      for (int db = 0; db < 4; db++) o[db][r] *= sc;
      mrun[r] = mnew[r];
      rs[r] = 0.f;
    }
#pragma unroll
    for (int nb = 0; nb < 4; nb++)
#pragma unroll
      for (int r = 0; r < 4; r++) {
        float p = __expf(sv[nb][r] - mnew[r]);
        bf16 pb = (bf16)p;
        rs[r] += (float)pb;
        P[wave][hi * 4 + r][nb * 16 + lo] = pb;
      }
#pragma unroll
    for (int r = 0; r < 4; r++) {
      float t = rs[r];
#pragma unroll
      for (int d = 1; d < 16; d <<= 1) t += __shfl_xor(t, d, 64);
      lrun[r] += t;
    }
    bf16x8 pa[2];
#pragma unroll
    for (int ks = 0; ks < 2; ks++) pa[ks] = *(const bf16x8*)&P[wave][lo][ks * 32 + hi * 8];
    __builtin_amdgcn_s_setprio(1);
#pragma unroll
    for (int db = 0; db < 4; db++)
#pragma unroll
      for (int ks = 0; ks < 2; ks++) {
        int row = db * 16 + lo;
        int off16 = (ks * 64 + row) * 4 + (hi ^ swz4(row));
        bf16x8 vf = *(const bf16x8*)((const char*)Vs + off16 * 16);
        o[db] = mfma16(pa[ks], vf, o[db]);
      }
    __builtin_amdgcn_s_setprio(0);
  }
  int b = bh >> 4, h = bh & 15;
#pragma unroll
  for (int db = 0; db < 4; db++)
#pragma unroll
    for (int r = 0; r < 4; r++) {
      float val = o[db][r] / lrun[r];
      size_t row = (size_t)b * 1024 + qb * 64 + wave * 16 + hi * 4 + r;
      ctx[row * 1024 + h * 64 + db * 16 + lo] = (bf16)val;
    }
}

// ---------------- host launcher ----------------

extern "C" void kernel_launch(void* const* d_in, const int* in_sizes, int n_in,
                              void* d_out, int out_size, void* d_ws, size_t ws_size,
                              hipStream_t stream) {
  (void)in_sizes; (void)n_in; (void)out_size; (void)ws_size;
  const float* x  = (const float*)d_in[0];
  const float* wq = (const float*)d_in[1];
  const float* wk = (const float*)d_in[2];
  const float* wv = (const float*)d_in[3];
  const float* wo = (const float*)d_in[4];
  const float* w1 = (const float*)d_in[5];
  const float* w2 = (const float*)d_in[6];
  const float* w3 = (const float*)d_in[7];
  const float* g1 = (const float*)d_in[8];
  const float* g2 = (const float*)d_in[9];
  float* out = (float*)d_out;

  char* ws = (char*)d_ws;
  size_t off = 0;
  auto alloc = [&](size_t bytes) {
    char* p = ws + off;
    off += (bytes + 255) & ~(size_t)255;
    return p;
  };
  const size_t MB2 = 1024u * 1024u * 2u;      // 1M bf16
  const size_t MB8 = 4096u * 1024u * 2u;      // 4M bf16
  void* WQH = alloc(MB2);  void* WQL = alloc(MB2);
  void* WKH = alloc(MB2);  void* WKL = alloc(MB2);
  void* WVH = alloc(MB2);  void* WOH = alloc(MB2);
  void* W1H = alloc(MB8);  void* W3H = alloc(MB8);  void* W2H = alloc(MB8);
  void* ROPE = alloc(32768u * 8u);
  void* Y1H = alloc(MB8);  void* Y1L = alloc(MB8);
  void* QH = alloc(MB8);   void* QL = alloc(MB8);
  void* KH = alloc(MB8);   void* KL = alloc(MB8);
  void* VT = alloc(MB8);
  void* CTX = alloc(MB8);
  void* Y2H = alloc(MB8);
  void* GLU = QH;  // 32MB alias over QH,QL,KH,KL (dead after flash)

  prep_kernel<<<dim3(4096, 8), dim3(256), 0, stream>>>(
      wq, wk, wv, wo, w1, w3, w2,
      (unsigned short*)WQH, (unsigned short*)WQL, (unsigned short*)WKH,
      (unsigned short*)WKL, (unsigned short*)WVH, (unsigned short*)WOH,
      (unsigned short*)W1H, (unsigned short*)W3H, (unsigned short*)W2H,
      (float2*)ROPE);

  rmsnorm_kernel<<<dim3(4096), dim3(256), 0, stream>>>(
      x, g1, (unsigned short*)Y1H, (unsigned short*)Y1L);

  gemm_qk_kernel<<<dim3(512), dim3(256), 0, stream>>>(
      (const bf16*)Y1H, (const bf16*)Y1L,
      (const bf16*)WQH, (const bf16*)WQL, (const bf16*)WKH, (const bf16*)WKL,
      (const float2*)ROPE,
      (bf16*)QH, (bf16*)QL, (bf16*)KH, (bf16*)KL);

  gemm_nt<0><<<dim3(256), dim3(256), 0, stream>>>(
      (const bf16*)Y1H, (const bf16*)WVH, 1024, 1024, 1024,
      nullptr, (bf16*)VT, nullptr);

  flash_kernel<<<dim3(1024), dim3(256), 0, stream>>>(
      (const bf16*)QH, (const bf16*)QL, (const bf16*)KH, (const bf16*)KL,
      (const bf16*)VT, (bf16*)CTX);

  gemm_nt<1><<<dim3(256), dim3(256), 0, stream>>>(
      (const bf16*)CTX, (const bf16*)WOH, 1024, 1024, 1024,
      out, nullptr, x);

  rmsnorm_kernel<<<dim3(4096), dim3(256), 0, stream>>>(
      out, g2, (unsigned short*)Y2H, nullptr);

  // fused SwiGLU up-projection (single kernel, both w1 and w3)
  gemm_up_kernel<<<dim3(512), dim3(512), 0, stream>>>(
      (const bf16*)Y2H, (const bf16*)W1H, (const bf16*)W3H, (bf16*)GLU);

  // down-projection: split-K=4 (z = sq>>5), atomic f32 accumulate into out
  gemm_nt<5><<<dim3(1024), dim3(256), 0, stream>>>(
      (const bf16*)GLU, (const bf16*)W2H, 1024, 1024, 4096,
      out, nullptr, nullptr);
}

// Round 6
// 330.549 us; speedup vs baseline: 1.1650x; 1.0002x over previous
//
#include <hip/hip_runtime.h>

typedef __bf16 bf16;
typedef __attribute__((ext_vector_type(8))) __bf16 bf16x8;
typedef __attribute__((ext_vector_type(4))) float f32x4;

// LDS chunk swizzle for [R][32]-bf16 tiles (64B rows): reads touch 16 consecutive
// rows at chunk hi^swz4(r); (r>>1)&3 spreads same-parity rows over 4 chunk slots.
static __device__ __forceinline__ int swz4(int r) { return (r >> 1) & 3; }

static __device__ __forceinline__ void async_cp16(void* lds, const void* g) {
  __builtin_amdgcn_global_load_lds((__attribute__((address_space(1))) void*)g,
                                   (__attribute__((address_space(3))) void*)lds,
                                   16, 0, 0);
}

static __device__ __forceinline__ f32x4 mfma16(bf16x8 a, bf16x8 b, f32x4 c) {
  return __builtin_amdgcn_mfma_f32_16x16x32_bf16(a, b, c, 0, 0, 0);
}

static __device__ __forceinline__ unsigned short bfbits(float f) {
  bf16 b = (bf16)f;
  return __builtin_bit_cast(unsigned short, b);
}

// ---------------- fused prep: 7 weight conversions + rope table, one launch ----------------
extern "C" __global__ void prep_kernel(
    const float* __restrict__ wq, const float* __restrict__ wk,
    const float* __restrict__ wv, const float* __restrict__ wo,
    const float* __restrict__ w1, const float* __restrict__ w3,
    const float* __restrict__ w2,
    unsigned short* __restrict__ WQH, unsigned short* __restrict__ WQL,
    unsigned short* __restrict__ WKH, unsigned short* __restrict__ WKL,
    unsigned short* __restrict__ WVH, unsigned short* __restrict__ WOH,
    unsigned short* __restrict__ W1H, unsigned short* __restrict__ W3H,
    unsigned short* __restrict__ W2H, float2* __restrict__ rope) {
  const int seg = blockIdx.y;
  const int i = blockIdx.x * 256 + threadIdx.x;
  if (seg == 7) {  // rope table
    if (i >= 32768) return;
    int s = i >> 5, fi = i & 31;
    float inv_freq = powf(10000.0f, -(2.0f * (float)fi) / 64.0f);
    float ang = (float)s * inv_freq;
    float2 cs;
    cs.x = cosf(ang);
    cs.y = sinf(ang);
    rope[i] = cs;
    return;
  }
  const float* src;
  unsigned short* hi_;
  unsigned short* lo_ = nullptr;
  int n4;
  switch (seg) {
    case 0: src = wq; hi_ = WQH; lo_ = WQL; n4 = 262144; break;
    case 1: src = wk; hi_ = WKH; lo_ = WKL; n4 = 262144; break;
    case 2: src = wv; hi_ = WVH; n4 = 262144; break;
    case 3: src = wo; hi_ = WOH; n4 = 262144; break;
    case 4: src = w1; hi_ = W1H; n4 = 1048576; break;
    case 5: src = w3; hi_ = W3H; n4 = 1048576; break;
    default: src = w2; hi_ = W2H; n4 = 1048576; break;
  }
  if (i >= n4) return;
  float4 v = ((const float4*)src)[i];
  bf16 b0 = (bf16)v.x, b1 = (bf16)v.y, b2 = (bf16)v.z, b3 = (bf16)v.w;
  ushort4 oh;
  oh.x = __builtin_bit_cast(unsigned short, b0);
  oh.y = __builtin_bit_cast(unsigned short, b1);
  oh.z = __builtin_bit_cast(unsigned short, b2);
  oh.w = __builtin_bit_cast(unsigned short, b3);
  ((ushort4*)hi_)[i] = oh;
  if (lo_) {
    ushort4 ol;
    ol.x = bfbits(v.x - (float)b0);
    ol.y = bfbits(v.y - (float)b1);
    ol.z = bfbits(v.z - (float)b2);
    ol.w = bfbits(v.w - (float)b3);
    ((ushort4*)lo_)[i] = ol;
  }
}

extern "C" __global__ __launch_bounds__(256) void rmsnorm_kernel(
    const float* __restrict__ x, const float* __restrict__ g,
    unsigned short* __restrict__ yhi, unsigned short* __restrict__ ylo) {
  int row = blockIdx.x;
  int t = threadIdx.x;
  const float4 xv = *(const float4*)(x + (size_t)row * 1024 + t * 4);
  float ss = xv.x * xv.x + xv.y * xv.y + xv.z * xv.z + xv.w * xv.w;
#pragma unroll
  for (int d = 1; d < 64; d <<= 1) ss += __shfl_xor(ss, d, 64);
  __shared__ float red[4];
  if ((t & 63) == 0) red[t >> 6] = ss;
  __syncthreads();
  float tot = red[0] + red[1] + red[2] + red[3];
  float inv = 1.0f / sqrtf(tot * (1.0f / 1024.0f) + 1e-5f);
  const float4 gv = *(const float4*)(g + t * 4);
  float y0 = xv.x * gv.x * inv, y1 = xv.y * gv.y * inv;
  float y2 = xv.z * gv.z * inv, y3 = xv.w * gv.w * inv;
  bf16 b0 = (bf16)y0, b1 = (bf16)y1, b2 = (bf16)y2, b3 = (bf16)y3;
  ushort4 oh;
  oh.x = __builtin_bit_cast(unsigned short, b0);
  oh.y = __builtin_bit_cast(unsigned short, b1);
  oh.z = __builtin_bit_cast(unsigned short, b2);
  oh.w = __builtin_bit_cast(unsigned short, b3);
  ((ushort4*)yhi)[(size_t)row * 256 + t] = oh;
  if (ylo) {
    ushort4 ol;
    ol.x = bfbits(y0 - (float)b0);
    ol.y = bfbits(y1 - (float)b1);
    ol.z = bfbits(y2 - (float)b2);
    ol.w = bfbits(y3 - (float)b3);
    ((ushort4*)ylo)[(size_t)row * 256 + t] = ol;
  }
}

// ---------------- GEMM: C[M,N] = A[M,K(ldk)] * B[N,K(ldk)]^T, 128x128 tile, BK=32 ----------------
// Flat grid, XCD-chunked decode: xcd = bid&7 owns M-slab (4 y-tiles) for all x,z.
// z = K-slice (A,B advanced by z*K). EPI 0: vT store; EPI 1: +resF -> f32; EPI 5: atomicAdd f32
template <int EPI>
__global__ __launch_bounds__(256, 2) void gemm_nt(
    const bf16* __restrict__ A, const bf16* __restrict__ B, int N, int K, int ldk,
    float* __restrict__ outF, bf16* __restrict__ outB,
    const float* __restrict__ resF) {
  const int bid = blockIdx.x;
  const int xcd = bid & 7, sq = bid >> 3;
  const int z = sq >> 5;          // 0 for 256-block launches; 0..3 for split-K
  const int rem = sq & 31;
  const size_t tm = (size_t)(xcd * 4 + (rem >> 3)) * 128;
  const size_t tn = (size_t)(rem & 7) * 128;
  A += (size_t)z * K;
  B += (size_t)z * K;
  __shared__ alignas(16) bf16 As[128 * 32];
  __shared__ alignas(16) bf16 Bs[128 * 32];
  const int tid = threadIdx.x;
  const int lane = tid & 63, wave = tid >> 6;
  const int lo = lane & 15, hi = lane >> 4;
  const int wm = wave >> 1, wn = wave & 1;
  f32x4 acc[4][4] = {};
  for (int k0 = 0; k0 < K; k0 += 32) {
    __syncthreads();
#pragma unroll
    for (int i2 = 0; i2 < 2; i2++) {
      int p = tid + 256 * i2;
      int row = p >> 2, kcp = p & 3;
      int kcl = kcp ^ swz4(row);
      async_cp16((char*)As + (size_t)p * 16, A + (tm + row) * (size_t)ldk + k0 + kcl * 8);
      async_cp16((char*)Bs + (size_t)p * 16, B + (tn + row) * (size_t)ldk + k0 + kcl * 8);
    }
    __syncthreads();
    bf16x8 fa[4], fb[4];
#pragma unroll
    for (int i = 0; i < 4; i++) {
      int ra = wm * 64 + i * 16 + lo;
      fa[i] = *(const bf16x8*)((const char*)As + ra * 64 + ((hi ^ swz4(ra)) << 4));
      int rb = wn * 64 + i * 16 + lo;
      fb[i] = *(const bf16x8*)((const char*)Bs + rb * 64 + ((hi ^ swz4(rb)) << 4));
    }
    __builtin_amdgcn_s_setprio(1);
#pragma unroll
    for (int i = 0; i < 4; i++)
#pragma unroll
      for (int j = 0; j < 4; j++) acc[i][j] = mfma16(fa[i], fb[j], acc[i][j]);
    __builtin_amdgcn_s_setprio(0);
  }
#pragma unroll
  for (int i = 0; i < 4; i++)
#pragma unroll
    for (int j = 0; j < 4; j++)
#pragma unroll
      for (int r = 0; r < 4; r++) {
        size_t m = tm + wm * 64 + i * 16 + hi * 4 + r;
        size_t n = tn + wn * 64 + j * 16 + lo;
        float v = acc[i][j][r];
        if constexpr (EPI == 0) {
          size_t idx = (((m >> 10) * 16 + (n >> 6)) * 64 + (n & 63)) * 1024 + (m & 1023);
          outB[idx] = (bf16)v;
        } else if constexpr (EPI == 1) {
          size_t idx = m * (size_t)N + n;
          outF[idx] = v + resF[idx];
        } else {
          atomicAdd(&outF[m * (size_t)N + n], v);
        }
      }
}

// ---------------- fused FFN-up: G = silu(A*B1^T) * (A*B3^T) ----------------
// 256M x 128N tile, BK=64, 8 waves (4M x 2N), 4 phases/tile, ONE barrier per phase
// (after MFMA), compiler-counted lgkmcnt (no manual drain / sched pins), counted
// vmcnt(4) tile gate, compile-time buffer parity, incrementing stage pointers.
extern "C" __global__ __launch_bounds__(512, 2) void gemm_up_kernel(
    const bf16* __restrict__ A, const bf16* __restrict__ B1,
    const bf16* __restrict__ B3, bf16* __restrict__ G) {
  __shared__ alignas(16) bf16 LA[2][2][256][32];   // [dbuf][khalf][row][col]
  __shared__ alignas(16) bf16 LB1[2][2][128][32];
  __shared__ alignas(16) bf16 LB3[2][2][128][32];
  const int tid = threadIdx.x;
  const int lane = tid & 63, wave = tid >> 6;
  const int lo = lane & 15, hi = lane >> 4;
  const int wm = wave >> 1, wn = wave & 1;  // 4M x 2N waves, each 64x64 per gemm
  const int bid = blockIdx.x;
  const int xcd = bid & 7, sq = bid >> 3;    // 512 blocks: sq 0..63
  const size_t tn = (size_t)(xcd * 4 + (sq & 3)) * 128;
  const size_t tm = (size_t)(sq >> 2) * 256;

  f32x4 acc1[4][4] = {}, acc3[4][4] = {};

  // ds_read byte offsets within a [rows][32] plane (loop-invariant)
  int offA[4], offB[4];
#pragma unroll
  for (int i = 0; i < 4; i++) {
    int ra = wm * 64 + i * 16 + lo;
    offA[i] = ra * 64 + ((hi ^ swz4(ra)) << 4);
    int rb = wn * 64 + i * 16 + lo;
    offB[i] = rb * 64 + ((hi ^ swz4(rb)) << 4);
  }

  // staging pointers: every stage call advances +32 elems (uniform over the
  // whole schedule: kh-halves are staged in strictly increasing k order)
  const int r0 = tid >> 2, c0 = tid & 3;
  const bf16* pA0 = A + (tm + r0) * (size_t)1024 + ((c0 ^ swz4(r0)) << 3);
  const bf16* pB1 = B1 + (tn + r0) * (size_t)1024 + ((c0 ^ swz4(r0)) << 3);
  const bf16* pB3 = B3 + (tn + r0) * (size_t)1024 + ((c0 ^ swz4(r0)) << 3);

  auto stA = [&](char* plane) {
    async_cp16(plane + tid * 16, pA0);
    async_cp16(plane + (512 + tid) * 16, pA0 + 128 * 1024);
    pA0 += 32;
  };
  auto stB = [&](char* plane1, char* plane3) {
    async_cp16(plane1 + tid * 16, pB1);
    pB1 += 32;
    async_cp16(plane3 + tid * 16, pB3);
    pB3 += 32;
  };

  // prologue: stage (t0,kh0), (t0,kh1), (t1,kh0); drain the first two groups
  stA((char*)&LA[0][0][0][0]); stB((char*)&LB1[0][0][0][0], (char*)&LB3[0][0][0][0]);
  stA((char*)&LA[0][1][0][0]); stB((char*)&LB1[0][1][0][0], (char*)&LB3[0][1][0][0]);
  stA((char*)&LA[1][0][0][0]); stB((char*)&LB1[1][0][0][0], (char*)&LB3[1][0][0][0]);
  asm volatile("s_waitcnt vmcnt(4)");
  __builtin_amdgcn_s_barrier();

#define UP_RD(ARR, P, KH, OFF) \
  (*(const bf16x8*)((const char*)&ARR[P][KH][0][0] + (OFF)))

#define UP_MFMA(ACC)                                        \
  __builtin_amdgcn_s_setprio(1);                            \
  _Pragma("unroll") for (int i = 0; i < 4; i++)             \
    _Pragma("unroll") for (int j = 0; j < 4; j++)           \
      ACC[i][j] = mfma16(fa[i], fb[j], ACC[i][j]);          \
  __builtin_amdgcn_s_setprio(0);

#define UP_TILE(T, P)                                                          \
  {                                                                            \
    bf16x8 fa[4], fb[4];                                                       \
    /* phase 0: kh0 x B1 ; stage A(T+1,kh1) */                                 \
    _Pragma("unroll") for (int i = 0; i < 4; i++) {                            \
      fa[i] = UP_RD(LA, P, 0, offA[i]);                                        \
      fb[i] = UP_RD(LB1, P, 0, offB[i]);                                       \
    }                                                                          \
    if ((T) + 1 < 16) stA((char*)&LA[(P) ^ 1][1][0][0]);                       \
    UP_MFMA(acc1)                                                              \
    __builtin_amdgcn_s_barrier();                                              \
    /* phase 1: kh0 x B3 ; stage B(T+1,kh1) */                                 \
    _Pragma("unroll") for (int j = 0; j < 4; j++)                              \
      fb[j] = UP_RD(LB3, P, 0, offB[j]);                                       \
    if ((T) + 1 < 16)                                                          \
      stB((char*)&LB1[(P) ^ 1][1][0][0], (char*)&LB3[(P) ^ 1][1][0][0]);       \
    UP_MFMA(acc3)                                                              \
    __builtin_amdgcn_s_barrier();                                              \
    /* phase 2: kh1 x B1 ; stage A(T+2,kh0) */                                 \
    _Pragma("unroll") for (int i = 0; i < 4; i++) {                            \
      fa[i] = UP_RD(LA, P, 1, offA[i]);                                        \
      fb[i] = UP_RD(LB1, P, 1, offB[i]);                                       \
    }                                                                          \
    if ((T) + 2 < 16) stA((char*)&LA[P][0][0][0]);                             \
    UP_MFMA(acc1)                                                              \
    __builtin_amdgcn_s_barrier();                                              \
    /* phase 3: kh1 x B3 ; stage B(T+2,kh0) ; tile gate */                     \
    _Pragma("unroll") for (int j = 0; j < 4; j++)                              \
      fb[j] = UP_RD(LB3, P, 1, offB[j]);                                       \
    if ((T) + 2 < 16)                                                          \
      stB((char*)&LB1[P][0][0][0], (char*)&LB3[P][0][0][0]);                   \
    UP_MFMA(acc3)                                                              \
    if ((T) + 2 < 16) {                                                        \
      asm volatile("s_waitcnt vmcnt(4)");                                      \
    } else if ((T) + 1 < 16) {                                                 \
      asm volatile("s_waitcnt vmcnt(0)");                                      \
    }                                                                          \
    __builtin_amdgcn_s_barrier();                                              \
  }

  for (int tt = 0; tt < 16; tt += 2) {
    UP_TILE(tt, 0)
    UP_TILE(tt + 1, 1)
  }

#pragma unroll
  for (int i = 0; i < 4; i++)
#pragma unroll
    for (int j = 0; j < 4; j++)
#pragma unroll
      for (int r = 0; r < 4; r++) {
        size_t m = tm + wm * 64 + i * 16 + hi * 4 + r;
        size_t n = tn + wn * 64 + j * 16 + lo;
        float v1 = acc1[i][j][r], v3 = acc3[i][j][r];
        G[m * 4096 + n] = (bf16)(v1 / (1.0f + __expf(-v1)) * v3);
      }
}

// ---------------- split-precision q/k projection GEMM with fused RoPE ----------------
// Flat grid 512; z = sq>>5 selects Q (0) / K (1); XCD-chunked M-slab like gemm_nt.
extern "C" __global__ __launch_bounds__(256, 2) void gemm_qk_kernel(
    const bf16* __restrict__ Ah, const bf16* __restrict__ Al,
    const bf16* __restrict__ BhQ, const bf16* __restrict__ BlQ,
    const bf16* __restrict__ BhK, const bf16* __restrict__ BlK,
    const float2* __restrict__ rope,
    bf16* __restrict__ OhQ, bf16* __restrict__ OlQ,
    bf16* __restrict__ OhK, bf16* __restrict__ OlK) {
  const int bid = blockIdx.x;
  const int xcd = bid & 7, sq = bid >> 3;
  const int zqk = sq >> 5;
  const int rem = sq & 31;
  const size_t tm = (size_t)(xcd * 4 + (rem >> 3)) * 128;
  const size_t tn = (size_t)(rem & 7) * 128;
  const bf16* Bh = zqk ? BhK : BhQ;
  const bf16* Bl = zqk ? BlK : BlQ;
  bf16* Oh = zqk ? OhK : OhQ;
  bf16* Ol = zqk ? OlK : OlQ;
  __shared__ alignas(16) bf16 Ahs[128 * 32], Als[128 * 32], Bhs[128 * 32], Bls[128 * 32];
  const int tid = threadIdx.x;
  const int lane = tid & 63, wave = tid >> 6;
  const int lo = lane & 15, hi = lane >> 4;
  const int wm = wave >> 1, wn = wave & 1;
  const int K = 1024;
  f32x4 acc[4][4] = {};
  for (int k0 = 0; k0 < K; k0 += 32) {
    __syncthreads();
#pragma unroll
    for (int i2 = 0; i2 < 2; i2++) {
      int p = tid + 256 * i2;
      int row = p >> 2;
      int kcl = (p & 3) ^ swz4(row);
      size_t ga = (tm + row) * (size_t)K + k0 + kcl * 8;
      size_t gb = (tn + row) * (size_t)K + k0 + kcl * 8;
      async_cp16((char*)Ahs + (size_t)p * 16, Ah + ga);
      async_cp16((char*)Als + (size_t)p * 16, Al + ga);
      async_cp16((char*)Bhs + (size_t)p * 16, Bh + gb);
      async_cp16((char*)Bls + (size_t)p * 16, Bl + gb);
    }
    __syncthreads();
    bf16x8 fah[4], fal[4], fbh[4], fbl[4];
#pragma unroll
    for (int i = 0; i < 4; i++) {
      int ra = wm * 64 + i * 16 + lo;
      int oa = ra * 64 + ((hi ^ swz4(ra)) << 4);
      fah[i] = *(const bf16x8*)((const char*)Ahs + oa);
      fal[i] = *(const bf16x8*)((const char*)Als + oa);
      int rb = wn * 64 + i * 16 + lo;
      int ob = rb * 64 + ((hi ^ swz4(rb)) << 4);
      fbh[i] = *(const bf16x8*)((const char*)Bhs + ob);
      fbl[i] = *(const bf16x8*)((const char*)Bls + ob);
    }
    __builtin_amdgcn_s_setprio(1);
#pragma unroll
    for (int i = 0; i < 4; i++)
#pragma unroll
      for (int j = 0; j < 4; j++) {
        f32x4 a = acc[i][j];
        a = mfma16(fah[i], fbh[j], a);
        a = mfma16(fah[i], fbl[j], a);
        a = mfma16(fal[i], fbh[j], a);
        acc[i][j] = a;
      }
    __builtin_amdgcn_s_setprio(0);
  }
#pragma unroll
  for (int i = 0; i < 4; i++)
#pragma unroll
    for (int j = 0; j < 4; j++)
#pragma unroll
      for (int r = 0; r < 4; r++) {
        float v = acc[i][j][r];
        float vp = __shfl_xor(v, 1, 64);
        size_t m = tm + wm * 64 + i * 16 + hi * 4 + r;
        size_t n = tn + wn * 64 + j * 16 + lo;
        int s = (int)(m & 1023);
        int pi = (int)((n & 63) >> 1);
        float2 cs = rope[s * 32 + pi];
        float res = (n & 1) ? (vp * cs.y + v * cs.x) : (v * cs.x - vp * cs.y);
        size_t idx = (((m >> 10) * 16 + (n >> 6)) * 1024 + (m & 1023)) * 64 + (n & 63);
        bf16 hb = (bf16)res;
        Oh[idx] = hb;
        Ol[idx] = (bf16)(res - (float)hb);
      }
}

// ---------------- flash attention (causal), LDS-staged K/V, 64-row Q block, 4 waves ----------------
extern "C" __global__ __launch_bounds__(256, 4) void flash_kernel(
    const bf16* __restrict__ qhi, const bf16* __restrict__ qlo,
    const bf16* __restrict__ khi, const bf16* __restrict__ klo,
    const bf16* __restrict__ vT, bf16* __restrict__ ctx) {
  const int bid = blockIdx.x;
  const int qb = bid >> 6;
  const int bh = bid & 63;
  const int tid = threadIdx.x;
  const int wave = tid >> 6, lane = tid & 63;
  const int lo = lane & 15, hi = lane >> 4;

  __shared__ alignas(16) bf16 Ksh[2][64][32];
  __shared__ alignas(16) bf16 Ksl[2][64][32];
  __shared__ alignas(16) bf16 Vs[2][64][32];
  __shared__ alignas(16) bf16 P[4][16][72];

  size_t qoff = ((size_t)bh * 1024 + qb * 64 + wave * 16 + lo) * 64;
  bf16x8 qh[2], ql[2];
#pragma unroll
  for (int ks = 0; ks < 2; ks++) {
    qh[ks] = *(const bf16x8*)(qhi + qoff + ks * 32 + hi * 8);
    ql[ks] = *(const bf16x8*)(qlo + qoff + ks * 32 + hi * 8);
  }

  const int srow = tid >> 2;
  const int scl = (tid & 3) ^ swz4(srow);
  const size_t kgb = (size_t)bh * 1024 * 64;
  const size_t vgb = ((size_t)bh * 64 + srow) * 1024;

  float mrun[4] = {-1e30f, -1e30f, -1e30f, -1e30f};
  float lrun[4] = {0.f, 0.f, 0.f, 0.f};
  f32x4 o[4] = {};
  const float scale = 0.125f;

  for (int kt = 0; kt <= qb; kt++) {
    __syncthreads();
#pragma unroll
    for (int i = 0; i < 2; i++) {
      int p = tid + 256 * i;
      size_t gk = kgb + (size_t)(kt * 64 + srow) * 64 + i * 32 + scl * 8;
      async_cp16((char*)Ksh + (size_t)p * 16, khi + gk);
      async_cp16((char*)Ksl + (size_t)p * 16, klo + gk);
      async_cp16((char*)Vs + (size_t)p * 16, vT + vgb + kt * 64 + i * 32 + scl * 8);
    }
    __syncthreads();

    f32x4 sv[4];
    __builtin_amdgcn_s_setprio(1);
#pragma unroll
    for (int nb = 0; nb < 4; nb++) {
      f32x4 a = {0.f, 0.f, 0.f, 0.f};
#pragma unroll
      for (int ks = 0; ks < 2; ks++) {
        int row = nb * 16 + lo;
        int off16 = (ks * 64 + row) * 4 + (hi ^ swz4(row));
        bf16x8 kh = *(const bf16x8*)((const char*)Ksh + off16 * 16);
        bf16x8 kl = *(const bf16x8*)((const char*)Ksl + off16 * 16);
        a = mfma16(qh[ks], kh, a);
        a = mfma16(qh[ks], kl, a);
        a = mfma16(ql[ks], kh, a);
      }
      sv[nb] = a;
    }
    __builtin_amdgcn_s_setprio(0);

    const bool mt = (kt == qb);
#pragma unroll
    for (int nb = 0; nb < 4; nb++)
#pragma unroll
      for (int r = 0; r < 4; r++) {
        float s = sv[nb][r] * scale;
        if (mt) {
          int kp = nb * 16 + lo;
          int qr = wave * 16 + hi * 4 + r;
          if (kp > qr) s = -1e30f;
        }
        sv[nb][r] = s;
      }
    float mnew[4], rs[4];
#pragma unroll
    for (int r = 0; r < 4; r++) {
      float mx = fmaxf(fmaxf(sv[0][r], sv[1][r]), fmaxf(sv[2][r], sv[3][r]));
#pragma unroll
      for (int d = 1; d < 16; d <<= 1) mx = fmaxf(mx, __shfl_xor(mx, d, 64));
      mnew[r] = fmaxf(mrun[r], mx);
      float sc = __expf(mrun[r] - mnew[r]);
      lrun[r] *= sc;
#pragma unroll
      for (int db = 0; db < 4; db++) o[db][r] *= sc;
      mrun[r] = mnew[r];
      rs[r] = 0.f;
    }
#pragma unroll
    for (int nb = 0; nb < 4; nb++)
#pragma unroll
      for (int r = 0; r < 4; r++) {
        float p = __expf(sv[nb][r] - mnew[r]);
        bf16 pb = (bf16)p;
        rs[r] += (float)pb;
        P[wave][hi * 4 + r][nb * 16 + lo] = pb;
      }
#pragma unroll
    for (int r = 0; r < 4; r++) {
      float t = rs[r];
#pragma unroll
      for (int d = 1; d < 16; d <<= 1) t += __shfl_xor(t, d, 64);
      lrun[r] += t;
    }
    bf16x8 pa[2];
#pragma unroll
    for (int ks = 0; ks < 2; ks++) pa[ks] = *(const bf16x8*)&P[wave][lo][ks * 32 + hi * 8];
    __builtin_amdgcn_s_setprio(1);
#pragma unroll
    for (int db = 0; db < 4; db++)
#pragma unroll
      for (int ks = 0; ks < 2; ks++) {
        int row = db * 16 + lo;
        int off16 = (ks * 64 + row) * 4 + (hi ^ swz4(row));
        bf16x8 vf = *(const bf16x8*)((const char*)Vs + off16 * 16);
        o[db] = mfma16(pa[ks], vf, o[db]);
      }
    __builtin_amdgcn_s_setprio(0);
  }
  int b = bh >> 4, h = bh & 15;
#pragma unroll
  for (int db = 0; db < 4; db++)
#pragma unroll
    for (int r = 0; r < 4; r++) {
      float val = o[db][r] / lrun[r];
      size_t row = (size_t)b * 1024 + qb * 64 + wave * 16 + hi * 4 + r;
      ctx[row * 1024 + h * 64 + db * 16 + lo] = (bf16)val;
    }
}

// ---------------- host launcher ----------------

extern "C" void kernel_launch(void* const* d_in, const int* in_sizes, int n_in,
                              void* d_out, int out_size, void* d_ws, size_t ws_size,
                              hipStream_t stream) {
  (void)in_sizes; (void)n_in; (void)out_size; (void)ws_size;
  const float* x  = (const float*)d_in[0];
  const float* wq = (const float*)d_in[1];
  const float* wk = (const float*)d_in[2];
  const float* wv = (const float*)d_in[3];
  const float* wo = (const float*)d_in[4];
  const float* w1 = (const float*)d_in[5];
  const float* w2 = (const float*)d_in[6];
  const float* w3 = (const float*)d_in[7];
  const float* g1 = (const float*)d_in[8];
  const float* g2 = (const float*)d_in[9];
  float* out = (float*)d_out;

  char* ws = (char*)d_ws;
  size_t off = 0;
  auto alloc = [&](size_t bytes) {
    char* p = ws + off;
    off += (bytes + 255) & ~(size_t)255;
    return p;
  };
  const size_t MB2 = 1024u * 1024u * 2u;      // 1M bf16
  const size_t MB8 = 4096u * 1024u * 2u;      // 4M bf16
  void* WQH = alloc(MB2);  void* WQL = alloc(MB2);
  void* WKH = alloc(MB2);  void* WKL = alloc(MB2);
  void* WVH = alloc(MB2);  void* WOH = alloc(MB2);
  void* W1H = alloc(MB8);  void* W3H = alloc(MB8);  void* W2H = alloc(MB8);
  void* ROPE = alloc(32768u * 8u);
  void* Y1H = alloc(MB8);  void* Y1L = alloc(MB8);
  void* QH = alloc(MB8);   void* QL = alloc(MB8);
  void* KH = alloc(MB8);   void* KL = alloc(MB8);
  void* VT = alloc(MB8);
  void* CTX = alloc(MB8);
  void* Y2H = alloc(MB8);
  void* GLU = QH;  // 32MB alias over QH,QL,KH,KL (dead after flash)

  prep_kernel<<<dim3(4096, 8), dim3(256), 0, stream>>>(
      wq, wk, wv, wo, w1, w3, w2,
      (unsigned short*)WQH, (unsigned short*)WQL, (unsigned short*)WKH,
      (unsigned short*)WKL, (unsigned short*)WVH, (unsigned short*)WOH,
      (unsigned short*)W1H, (unsigned short*)W3H, (unsigned short*)W2H,
      (float2*)ROPE);

  rmsnorm_kernel<<<dim3(4096), dim3(256), 0, stream>>>(
      x, g1, (unsigned short*)Y1H, (unsigned short*)Y1L);

  gemm_qk_kernel<<<dim3(512), dim3(256), 0, stream>>>(
      (const bf16*)Y1H, (const bf16*)Y1L,
      (const bf16*)WQH, (const bf16*)WQL, (const bf16*)WKH, (const bf16*)WKL,
      (const float2*)ROPE,
      (bf16*)QH, (bf16*)QL, (bf16*)KH, (bf16*)KL);

  gemm_nt<0><<<dim3(256), dim3(256), 0, stream>>>(
      (const bf16*)Y1H, (const bf16*)WVH, 1024, 1024, 1024,
      nullptr, (bf16*)VT, nullptr);

  flash_kernel<<<dim3(1024), dim3(256), 0, stream>>>(
      (const bf16*)QH, (const bf16*)QL, (const bf16*)KH, (const bf16*)KL,
      (const bf16*)VT, (bf16*)CTX);

  gemm_nt<1><<<dim3(256), dim3(256), 0, stream>>>(
      (const bf16*)CTX, (const bf16*)WOH, 1024, 1024, 1024,
      out, nullptr, x);

  rmsnorm_kernel<<<dim3(4096), dim3(256), 0, stream>>>(
      out, g2, (unsigned short*)Y2H, nullptr);

  // fused SwiGLU up-projection (single kernel, both w1 and w3)
  gemm_up_kernel<<<dim3(512), dim3(512), 0, stream>>>(
      (const bf16*)Y2H, (const bf16*)W1H, (const bf16*)W3H, (bf16*)GLU);

  // down-projection: split-K=4 (z = sq>>5), atomic f32 accumulate into out
  gemm_nt<5><<<dim3(1024), dim3(256), 0, stream>>>(
      (const bf16*)GLU, (const bf16*)W2H, 1024, 1024, 4096,
      out, nullptr, nullptr);
}

// Round 7
// 310.082 us; speedup vs baseline: 1.2419x; 1.0660x over previous
//
#include <hip/hip_runtime.h>

typedef __bf16 bf16;
typedef __attribute__((ext_vector_type(8))) __bf16 bf16x8;
typedef __attribute__((ext_vector_type(4))) float f32x4;

// swizzle for [R][32]-bf16 (64B-row) tiles (up/flash kernels)
static __device__ __forceinline__ int swz4(int r) { return (r >> 1) & 3; }

static __device__ __forceinline__ void async_cp16(void* lds, const void* g) {
  __builtin_amdgcn_global_load_lds((__attribute__((address_space(1))) void*)g,
                                   (__attribute__((address_space(3))) void*)lds,
                                   16, 0, 0);
}

static __device__ __forceinline__ f32x4 mfma16(bf16x8 a, bf16x8 b, f32x4 c) {
  return __builtin_amdgcn_mfma_f32_16x16x32_bf16(a, b, c, 0, 0, 0);
}

static __device__ __forceinline__ unsigned short bfbits(float f) {
  bf16 b = (bf16)f;
  return __builtin_bit_cast(unsigned short, b);
}

// ---------------- fused prep: 7 weight conversions + rope table, one launch ----------------
extern "C" __global__ void prep_kernel(
    const float* __restrict__ wq, const float* __restrict__ wk,
    const float* __restrict__ wv, const float* __restrict__ wo,
    const float* __restrict__ w1, const float* __restrict__ w3,
    const float* __restrict__ w2,
    unsigned short* __restrict__ WQH, unsigned short* __restrict__ WQL,
    unsigned short* __restrict__ WKH, unsigned short* __restrict__ WKL,
    unsigned short* __restrict__ WVH, unsigned short* __restrict__ WOH,
    unsigned short* __restrict__ W1H, unsigned short* __restrict__ W3H,
    unsigned short* __restrict__ W2H, float2* __restrict__ rope) {
  const int seg = blockIdx.y;
  const int i = blockIdx.x * 256 + threadIdx.x;
  if (seg == 7) {
    if (i >= 32768) return;
    int s = i >> 5, fi = i & 31;
    float inv_freq = powf(10000.0f, -(2.0f * (float)fi) / 64.0f);
    float ang = (float)s * inv_freq;
    float2 cs;
    cs.x = cosf(ang);
    cs.y = sinf(ang);
    rope[i] = cs;
    return;
  }
  const float* src;
  unsigned short* hi_;
  unsigned short* lo_ = nullptr;
  int n4;
  switch (seg) {
    case 0: src = wq; hi_ = WQH; lo_ = WQL; n4 = 262144; break;
    case 1: src = wk; hi_ = WKH; lo_ = WKL; n4 = 262144; break;
    case 2: src = wv; hi_ = WVH; n4 = 262144; break;
    case 3: src = wo; hi_ = WOH; n4 = 262144; break;
    case 4: src = w1; hi_ = W1H; n4 = 1048576; break;
    case 5: src = w3; hi_ = W3H; n4 = 1048576; break;
    default: src = w2; hi_ = W2H; n4 = 1048576; break;
  }
  if (i >= n4) return;
  float4 v = ((const float4*)src)[i];
  bf16 b0 = (bf16)v.x, b1 = (bf16)v.y, b2 = (bf16)v.z, b3 = (bf16)v.w;
  ushort4 oh;
  oh.x = __builtin_bit_cast(unsigned short, b0);
  oh.y = __builtin_bit_cast(unsigned short, b1);
  oh.z = __builtin_bit_cast(unsigned short, b2);
  oh.w = __builtin_bit_cast(unsigned short, b3);
  ((ushort4*)hi_)[i] = oh;
  if (lo_) {
    ushort4 ol;
    ol.x = bfbits(v.x - (float)b0);
    ol.y = bfbits(v.y - (float)b1);
    ol.z = bfbits(v.z - (float)b2);
    ol.w = bfbits(v.w - (float)b3);
    ((ushort4*)lo_)[i] = ol;
  }
}

extern "C" __global__ __launch_bounds__(256) void rmsnorm_kernel(
    const float* __restrict__ x, const float* __restrict__ g,
    unsigned short* __restrict__ yhi, unsigned short* __restrict__ ylo) {
  int row = blockIdx.x;
  int t = threadIdx.x;
  const float4 xv = *(const float4*)(x + (size_t)row * 1024 + t * 4);
  float ss = xv.x * xv.x + xv.y * xv.y + xv.z * xv.z + xv.w * xv.w;
#pragma unroll
  for (int d = 1; d < 64; d <<= 1) ss += __shfl_xor(ss, d, 64);
  __shared__ float red[4];
  if ((t & 63) == 0) red[t >> 6] = ss;
  __syncthreads();
  float tot = red[0] + red[1] + red[2] + red[3];
  float inv = 1.0f / sqrtf(tot * (1.0f / 1024.0f) + 1e-5f);
  const float4 gv = *(const float4*)(g + t * 4);
  float y0 = xv.x * gv.x * inv, y1 = xv.y * gv.y * inv;
  float y2 = xv.z * gv.z * inv, y3 = xv.w * gv.w * inv;
  bf16 b0 = (bf16)y0, b1 = (bf16)y1, b2 = (bf16)y2, b3 = (bf16)y3;
  ushort4 oh;
  oh.x = __builtin_bit_cast(unsigned short, b0);
  oh.y = __builtin_bit_cast(unsigned short, b1);
  oh.z = __builtin_bit_cast(unsigned short, b2);
  oh.w = __builtin_bit_cast(unsigned short, b3);
  ((ushort4*)yhi)[(size_t)row * 256 + t] = oh;
  if (ylo) {
    ushort4 ol;
    ol.x = bfbits(y0 - (float)b0);
    ol.y = bfbits(y1 - (float)b1);
    ol.z = bfbits(y2 - (float)b2);
    ol.w = bfbits(y3 - (float)b3);
    ((ushort4*)ylo)[(size_t)row * 256 + t] = ol;
  }
}

// ---------------- GEMM: C[M,N] = A[M,K(ldk)] * B[N,K(ldk)]^T, 128x128 tile, BK=64 ----------------
// [128][64] LDS tiles, 128B rows, swizzle c^= r&7 (2-way free). 16 K-iters at K=1024.
// Flat grid, XCD-chunked: xcd = bid&7 owns M-slab. z = sq>>5 = K-slice for split-K.
// EPI 0: vT store; EPI 1: +resF -> f32; EPI 5: atomicAdd f32
template <int EPI>
__global__ __launch_bounds__(256, 2) void gemm_nt(
    const bf16* __restrict__ A, const bf16* __restrict__ B, int N, int K, int ldk,
    float* __restrict__ outF, bf16* __restrict__ outB,
    const float* __restrict__ resF) {
  const int bid = blockIdx.x;
  const int xcd = bid & 7, sq = bid >> 3;
  const int z = sq >> 5;
  const int rem = sq & 31;
  const size_t tm = (size_t)(xcd * 4 + (rem >> 3)) * 128;
  const size_t tn = (size_t)(rem & 7) * 128;
  A += (size_t)z * K;
  B += (size_t)z * K;
  __shared__ alignas(16) bf16 As[128 * 64];
  __shared__ alignas(16) bf16 Bs[128 * 64];
  const int tid = threadIdx.x;
  const int lane = tid & 63, wave = tid >> 6;
  const int lo = lane & 15, hi = lane >> 4;
  const int wm = wave >> 1, wn = wave & 1;
  f32x4 acc[4][4] = {};
  for (int k0 = 0; k0 < K; k0 += 64) {
    __syncthreads();
#pragma unroll
    for (int i4 = 0; i4 < 4; i4++) {
      int p = tid + 256 * i4;
      int row = p >> 3, c = p & 7;
      int cs = c ^ (row & 7);
      async_cp16((char*)As + (size_t)p * 16, A + (tm + row) * (size_t)ldk + k0 + cs * 8);
      async_cp16((char*)Bs + (size_t)p * 16, B + (tn + row) * (size_t)ldk + k0 + cs * 8);
    }
    __syncthreads();
#pragma unroll
    for (int kh = 0; kh < 2; kh++) {
      bf16x8 fa[4], fb[4];
#pragma unroll
      for (int i = 0; i < 4; i++) {
        int ra = wm * 64 + i * 16 + lo;
        fa[i] = *(const bf16x8*)((const char*)As + ra * 128 + (((kh * 4 + hi) ^ (ra & 7)) << 4));
        int rb = wn * 64 + i * 16 + lo;
        fb[i] = *(const bf16x8*)((const char*)Bs + rb * 128 + (((kh * 4 + hi) ^ (rb & 7)) << 4));
      }
      __builtin_amdgcn_s_setprio(1);
#pragma unroll
      for (int i = 0; i < 4; i++)
#pragma unroll
        for (int j = 0; j < 4; j++) acc[i][j] = mfma16(fa[i], fb[j], acc[i][j]);
      __builtin_amdgcn_s_setprio(0);
    }
  }
#pragma unroll
  for (int i = 0; i < 4; i++)
#pragma unroll
    for (int j = 0; j < 4; j++)
#pragma unroll
      for (int r = 0; r < 4; r++) {
        size_t m = tm + wm * 64 + i * 16 + hi * 4 + r;
        size_t n = tn + wn * 64 + j * 16 + lo;
        float v = acc[i][j][r];
        if constexpr (EPI == 0) {
          size_t idx = (((m >> 10) * 16 + (n >> 6)) * 64 + (n & 63)) * 1024 + (m & 1023);
          outB[idx] = (bf16)v;
        } else if constexpr (EPI == 1) {
          size_t idx = m * (size_t)N + n;
          outF[idx] = v + resF[idx];
        } else {
          atomicAdd(&outF[m * (size_t)N + n], v);
        }
      }
}

// ---------------- fused FFN-up (unchanged from R6): 256Mx128N, BK=64, 8 waves ----------------
extern "C" __global__ __launch_bounds__(512, 2) void gemm_up_kernel(
    const bf16* __restrict__ A, const bf16* __restrict__ B1,
    const bf16* __restrict__ B3, bf16* __restrict__ G) {
  __shared__ alignas(16) bf16 LA[2][2][256][32];
  __shared__ alignas(16) bf16 LB1[2][2][128][32];
  __shared__ alignas(16) bf16 LB3[2][2][128][32];
  const int tid = threadIdx.x;
  const int lane = tid & 63, wave = tid >> 6;
  const int lo = lane & 15, hi = lane >> 4;
  const int wm = wave >> 1, wn = wave & 1;
  const int bid = blockIdx.x;
  const int xcd = bid & 7, sq = bid >> 3;
  const size_t tn = (size_t)(xcd * 4 + (sq & 3)) * 128;
  const size_t tm = (size_t)(sq >> 2) * 256;

  f32x4 acc1[4][4] = {}, acc3[4][4] = {};

  int offA[4], offB[4];
#pragma unroll
  for (int i = 0; i < 4; i++) {
    int ra = wm * 64 + i * 16 + lo;
    offA[i] = ra * 64 + ((hi ^ swz4(ra)) << 4);
    int rb = wn * 64 + i * 16 + lo;
    offB[i] = rb * 64 + ((hi ^ swz4(rb)) << 4);
  }

  const int r0 = tid >> 2, c0 = tid & 3;
  const bf16* pA0 = A + (tm + r0) * (size_t)1024 + ((c0 ^ swz4(r0)) << 3);
  const bf16* pB1 = B1 + (tn + r0) * (size_t)1024 + ((c0 ^ swz4(r0)) << 3);
  const bf16* pB3 = B3 + (tn + r0) * (size_t)1024 + ((c0 ^ swz4(r0)) << 3);

  auto stA = [&](char* plane) {
    async_cp16(plane + tid * 16, pA0);
    async_cp16(plane + (512 + tid) * 16, pA0 + 128 * 1024);
    pA0 += 32;
  };
  auto stB = [&](char* plane1, char* plane3) {
    async_cp16(plane1 + tid * 16, pB1);
    pB1 += 32;
    async_cp16(plane3 + tid * 16, pB3);
    pB3 += 32;
  };

  stA((char*)&LA[0][0][0][0]); stB((char*)&LB1[0][0][0][0], (char*)&LB3[0][0][0][0]);
  stA((char*)&LA[0][1][0][0]); stB((char*)&LB1[0][1][0][0], (char*)&LB3[0][1][0][0]);
  stA((char*)&LA[1][0][0][0]); stB((char*)&LB1[1][0][0][0], (char*)&LB3[1][0][0][0]);
  asm volatile("s_waitcnt vmcnt(4)");
  __builtin_amdgcn_s_barrier();

#define UP_RD(ARR, P, KH, OFF) \
  (*(const bf16x8*)((const char*)&ARR[P][KH][0][0] + (OFF)))

#define UP_MFMA(ACC)                                        \
  __builtin_amdgcn_s_setprio(1);                            \
  _Pragma("unroll") for (int i = 0; i < 4; i++)             \
    _Pragma("unroll") for (int j = 0; j < 4; j++)           \
      ACC[i][j] = mfma16(fa[i], fb[j], ACC[i][j]);          \
  __builtin_amdgcn_s_setprio(0);

#define UP_TILE(T, P)                                                          \
  {                                                                            \
    bf16x8 fa[4], fb[4];                                                       \
    _Pragma("unroll") for (int i = 0; i < 4; i++) {                            \
      fa[i] = UP_RD(LA, P, 0, offA[i]);                                        \
      fb[i] = UP_RD(LB1, P, 0, offB[i]);                                       \
    }                                                                          \
    if ((T) + 1 < 16) stA((char*)&LA[(P) ^ 1][1][0][0]);                       \
    UP_MFMA(acc1)                                                              \
    __builtin_amdgcn_s_barrier();                                              \
    _Pragma("unroll") for (int j = 0; j < 4; j++)                              \
      fb[j] = UP_RD(LB3, P, 0, offB[j]);                                       \
    if ((T) + 1 < 16)                                                          \
      stB((char*)&LB1[(P) ^ 1][1][0][0], (char*)&LB3[(P) ^ 1][1][0][0]);       \
    UP_MFMA(acc3)                                                              \
    __builtin_amdgcn_s_barrier();                                              \
    _Pragma("unroll") for (int i = 0; i < 4; i++) {                            \
      fa[i] = UP_RD(LA, P, 1, offA[i]);                                        \
      fb[i] = UP_RD(LB1, P, 1, offB[i]);                                       \
    }                                                                          \
    if ((T) + 2 < 16) stA((char*)&LA[P][0][0][0]);                             \
    UP_MFMA(acc1)                                                              \
    __builtin_amdgcn_s_barrier();                                              \
    _Pragma("unroll") for (int j = 0; j < 4; j++)                              \
      fb[j] = UP_RD(LB3, P, 1, offB[j]);                                       \
    if ((T) + 2 < 16)                                                          \
      stB((char*)&LB1[P][0][0][0], (char*)&LB3[P][0][0][0]);                   \
    UP_MFMA(acc3)                                                              \
    if ((T) + 2 < 16) {                                                        \
      asm volatile("s_waitcnt vmcnt(4)");                                      \
    } else if ((T) + 1 < 16) {                                                 \
      asm volatile("s_waitcnt vmcnt(0)");                                      \
    }                                                                          \
    __builtin_amdgcn_s_barrier();                                              \
  }

  for (int tt = 0; tt < 16; tt += 2) {
    UP_TILE(tt, 0)
    UP_TILE(tt + 1, 1)
  }

#pragma unroll
  for (int i = 0; i < 4; i++)
#pragma unroll
    for (int j = 0; j < 4; j++)
#pragma unroll
      for (int r = 0; r < 4; r++) {
        size_t m = tm + wm * 64 + i * 16 + hi * 4 + r;
        size_t n = tn + wn * 64 + j * 16 + lo;
        float v1 = acc1[i][j][r], v3 = acc3[i][j][r];
        G[m * 4096 + n] = (bf16)(v1 / (1.0f + __expf(-v1)) * v3);
      }
}

// ---------------- split-precision q/k projection GEMM with fused RoPE, BK=64 ----------------
extern "C" __global__ __launch_bounds__(256, 2) void gemm_qk_kernel(
    const bf16* __restrict__ Ah, const bf16* __restrict__ Al,
    const bf16* __restrict__ BhQ, const bf16* __restrict__ BlQ,
    const bf16* __restrict__ BhK, const bf16* __restrict__ BlK,
    const float2* __restrict__ rope,
    bf16* __restrict__ OhQ, bf16* __restrict__ OlQ,
    bf16* __restrict__ OhK, bf16* __restrict__ OlK) {
  const int bid = blockIdx.x;
  const int xcd = bid & 7, sq = bid >> 3;
  const int zqk = sq >> 5;
  const int rem = sq & 31;
  const size_t tm = (size_t)(xcd * 4 + (rem >> 3)) * 128;
  const size_t tn = (size_t)(rem & 7) * 128;
  const bf16* Bh = zqk ? BhK : BhQ;
  const bf16* Bl = zqk ? BlK : BlQ;
  bf16* Oh = zqk ? OhK : OhQ;
  bf16* Ol = zqk ? OlK : OlQ;
  __shared__ alignas(16) bf16 Ahs[128 * 64], Als[128 * 64];
  __shared__ alignas(16) bf16 Bhs[128 * 64], Bls[128 * 64];
  const int tid = threadIdx.x;
  const int lane = tid & 63, wave = tid >> 6;
  const int lo = lane & 15, hi = lane >> 4;
  const int wm = wave >> 1, wn = wave & 1;
  const int K = 1024;
  f32x4 acc[4][4] = {};
  for (int k0 = 0; k0 < K; k0 += 64) {
    __syncthreads();
#pragma unroll
    for (int i4 = 0; i4 < 4; i4++) {
      int p = tid + 256 * i4;
      int row = p >> 3, c = p & 7;
      int cs = c ^ (row & 7);
      size_t ga = (tm + row) * (size_t)K + k0 + cs * 8;
      size_t gb = (tn + row) * (size_t)K + k0 + cs * 8;
      async_cp16((char*)Ahs + (size_t)p * 16, Ah + ga);
      async_cp16((char*)Als + (size_t)p * 16, Al + ga);
      async_cp16((char*)Bhs + (size_t)p * 16, Bh + gb);
      async_cp16((char*)Bls + (size_t)p * 16, Bl + gb);
    }
    __syncthreads();
#pragma unroll
    for (int kh = 0; kh < 2; kh++) {
      int offa[4], offb[4];
#pragma unroll
      for (int i = 0; i < 4; i++) {
        int ra = wm * 64 + i * 16 + lo;
        offa[i] = ra * 128 + (((kh * 4 + hi) ^ (ra & 7)) << 4);
        int rb = wn * 64 + i * 16 + lo;
        offb[i] = rb * 128 + (((kh * 4 + hi) ^ (rb & 7)) << 4);
      }
      bf16x8 fah[4], fbh[4], fx[4];
#pragma unroll
      for (int i = 0; i < 4; i++) {
        fah[i] = *(const bf16x8*)((const char*)Ahs + offa[i]);
        fbh[i] = *(const bf16x8*)((const char*)Bhs + offb[i]);
      }
      __builtin_amdgcn_s_setprio(1);
#pragma unroll
      for (int i = 0; i < 4; i++)
#pragma unroll
        for (int j = 0; j < 4; j++) acc[i][j] = mfma16(fah[i], fbh[j], acc[i][j]);
      __builtin_amdgcn_s_setprio(0);
#pragma unroll
      for (int j = 0; j < 4; j++) fx[j] = *(const bf16x8*)((const char*)Bls + offb[j]);
      __builtin_amdgcn_s_setprio(1);
#pragma unroll
      for (int i = 0; i < 4; i++)
#pragma unroll
        for (int j = 0; j < 4; j++) acc[i][j] = mfma16(fah[i], fx[j], acc[i][j]);
      __builtin_amdgcn_s_setprio(0);
#pragma unroll
      for (int i = 0; i < 4; i++) fx[i] = *(const bf16x8*)((const char*)Als + offa[i]);
      __builtin_amdgcn_s_setprio(1);
#pragma unroll
      for (int i = 0; i < 4; i++)
#pragma unroll
        for (int j = 0; j < 4; j++) acc[i][j] = mfma16(fx[i], fbh[j], acc[i][j]);
      __builtin_amdgcn_s_setprio(0);
    }
  }
#pragma unroll
  for (int i = 0; i < 4; i++)
#pragma unroll
    for (int j = 0; j < 4; j++)
#pragma unroll
      for (int r = 0; r < 4; r++) {
        float v = acc[i][j][r];
        float vp = __shfl_xor(v, 1, 64);
        size_t m = tm + wm * 64 + i * 16 + hi * 4 + r;
        size_t n = tn + wn * 64 + j * 16 + lo;
        int s = (int)(m & 1023);
        int pi = (int)((n & 63) >> 1);
        float2 cs = rope[s * 32 + pi];
        float res = (n & 1) ? (vp * cs.y + v * cs.x) : (v * cs.x - vp * cs.y);
        size_t idx = (((m >> 10) * 16 + (n >> 6)) * 1024 + (m & 1023)) * 64 + (n & 63);
        bf16 hb = (bf16)res;
        Oh[idx] = hb;
        Ol[idx] = (bf16)(res - (float)hb);
      }
}

// ---------------- flash attention (unchanged) ----------------
extern "C" __global__ __launch_bounds__(256, 4) void flash_kernel(
    const bf16* __restrict__ qhi, const bf16* __restrict__ qlo,
    const bf16* __restrict__ khi, const bf16* __restrict__ klo,
    const bf16* __restrict__ vT, bf16* __restrict__ ctx) {
  const int bid = blockIdx.x;
  const int qb = bid >> 6;
  const int bh = bid & 63;
  const int tid = threadIdx.x;
  const int wave = tid >> 6, lane = tid & 63;
  const int lo = lane & 15, hi = lane >> 4;

  __shared__ alignas(16) bf16 Ksh[2][64][32];
  __shared__ alignas(16) bf16 Ksl[2][64][32];
  __shared__ alignas(16) bf16 Vs[2][64][32];
  __shared__ alignas(16) bf16 P[4][16][72];

  size_t qoff = ((size_t)bh * 1024 + qb * 64 + wave * 16 + lo) * 64;
  bf16x8 qh[2], ql[2];
#pragma unroll
  for (int ks = 0; ks < 2; ks++) {
    qh[ks] = *(const bf16x8*)(qhi + qoff + ks * 32 + hi * 8);
    ql[ks] = *(const bf16x8*)(qlo + qoff + ks * 32 + hi * 8);
  }

  const int srow = tid >> 2;
  const int scl = (tid & 3) ^ swz4(srow);
  const size_t kgb = (size_t)bh * 1024 * 64;
  const size_t vgb = ((size_t)bh * 64 + srow) * 1024;

  float mrun[4] = {-1e30f, -1e30f, -1e30f, -1e30f};
  float lrun[4] = {0.f, 0.f, 0.f, 0.f};
  f32x4 o[4] = {};
  const float scale = 0.125f;

  for (int kt = 0; kt <= qb; kt++) {
    __syncthreads();
#pragma unroll
    for (int i = 0; i < 2; i++) {
      int p = tid + 256 * i;
      size_t gk = kgb + (size_t)(kt * 64 + srow) * 64 + i * 32 + scl * 8;
      async_cp16((char*)Ksh + (size_t)p * 16, khi + gk);
      async_cp16((char*)Ksl + (size_t)p * 16, klo + gk);
      async_cp16((char*)Vs + (size_t)p * 16, vT + vgb + kt * 64 + i * 32 + scl * 8);
    }
    __syncthreads();

    f32x4 sv[4];
    __builtin_amdgcn_s_setprio(1);
#pragma unroll
    for (int nb = 0; nb < 4; nb++) {
      f32x4 a = {0.f, 0.f, 0.f, 0.f};
#pragma unroll
      for (int ks = 0; ks < 2; ks++) {
        int row = nb * 16 + lo;
        int off16 = (ks * 64 + row) * 4 + (hi ^ swz4(row));
        bf16x8 kh = *(const bf16x8*)((const char*)Ksh + off16 * 16);
        bf16x8 kl = *(const bf16x8*)((const char*)Ksl + off16 * 16);
        a = mfma16(qh[ks], kh, a);
        a = mfma16(qh[ks], kl, a);
        a = mfma16(ql[ks], kh, a);
      }
      sv[nb] = a;
    }
    __builtin_amdgcn_s_setprio(0);

    const bool mt = (kt == qb);
#pragma unroll
    for (int nb = 0; nb < 4; nb++)
#pragma unroll
      for (int r = 0; r < 4; r++) {
        float s = sv[nb][r] * scale;
        if (mt) {
          int kp = nb * 16 + lo;
          int qr = wave * 16 + hi * 4 + r;
          if (kp > qr) s = -1e30f;
        }
        sv[nb][r] = s;
      }
    float mnew[4], rs[4];
#pragma unroll
    for (int r = 0; r < 4; r++) {
      float mx = fmaxf(fmaxf(sv[0][r], sv[1][r]), fmaxf(sv[2][r], sv[3][r]));
#pragma unroll
      for (int d = 1; d < 16; d <<= 1) mx = fmaxf(mx, __shfl_xor(mx, d, 64));
      mnew[r] = fmaxf(mrun[r], mx);
      float sc = __expf(mrun[r] - mnew[r]);
      lrun[r] *= sc;
#pragma unroll
      for (int db = 0; db < 4; db++) o[db][r] *= sc;
      mrun[r] = mnew[r];
      rs[r] = 0.f;
    }
#pragma unroll
    for (int nb = 0; nb < 4; nb++)
#pragma unroll
      for (int r = 0; r < 4; r++) {
        float p = __expf(sv[nb][r] - mnew[r]);
        bf16 pb = (bf16)p;
        rs[r] += (float)pb;
        P[wave][hi * 4 + r][nb * 16 + lo] = pb;
      }
#pragma unroll
    for (int r = 0; r < 4; r++) {
      float t = rs[r];
#pragma unroll
      for (int d = 1; d < 16; d <<= 1) t += __shfl_xor(t, d, 64);
      lrun[r] += t;
    }
    bf16x8 pa[2];
#pragma unroll
    for (int ks = 0; ks < 2; ks++) pa[ks] = *(const bf16x8*)&P[wave][lo][ks * 32 + hi * 8];
    __builtin_amdgcn_s_setprio(1);
#pragma unroll
    for (int db = 0; db < 4; db++)
#pragma unroll
      for (int ks = 0; ks < 2; ks++) {
        int row = db * 16 + lo;
        int off16 = (ks * 64 + row) * 4 + (hi ^ swz4(row));
        bf16x8 vf = *(const bf16x8*)((const char*)Vs + off16 * 16);
        o[db] = mfma16(pa[ks], vf, o[db]);
      }
    __builtin_amdgcn_s_setprio(0);
  }
  int b = bh >> 4, h = bh & 15;
#pragma unroll
  for (int db = 0; db < 4; db++)
#pragma unroll
    for (int r = 0; r < 4; r++) {
      float val = o[db][r] / lrun[r];
      size_t row = (size_t)b * 1024 + qb * 64 + wave * 16 + hi * 4 + r;
      ctx[row * 1024 + h * 64 + db * 16 + lo] = (bf16)val;
    }
}

// ---------------- host launcher ----------------

extern "C" void kernel_launch(void* const* d_in, const int* in_sizes, int n_in,
                              void* d_out, int out_size, void* d_ws, size_t ws_size,
                              hipStream_t stream) {
  (void)in_sizes; (void)n_in; (void)out_size; (void)ws_size;
  const float* x  = (const float*)d_in[0];
  const float* wq = (const float*)d_in[1];
  const float* wk = (const float*)d_in[2];
  const float* wv = (const float*)d_in[3];
  const float* wo = (const float*)d_in[4];
  const float* w1 = (const float*)d_in[5];
  const float* w2 = (const float*)d_in[6];
  const float* w3 = (const float*)d_in[7];
  const float* g1 = (const float*)d_in[8];
  const float* g2 = (const float*)d_in[9];
  float* out = (float*)d_out;

  char* ws = (char*)d_ws;
  size_t off = 0;
  auto alloc = [&](size_t bytes) {
    char* p = ws + off;
    off += (bytes + 255) & ~(size_t)255;
    return p;
  };
  const size_t MB2 = 1024u * 1024u * 2u;
  const size_t MB8 = 4096u * 1024u * 2u;
  void* WQH = alloc(MB2);  void* WQL = alloc(MB2);
  void* WKH = alloc(MB2);  void* WKL = alloc(MB2);
  void* WVH = alloc(MB2);  void* WOH = alloc(MB2);
  void* W1H = alloc(MB8);  void* W3H = alloc(MB8);  void* W2H = alloc(MB8);
  void* ROPE = alloc(32768u * 8u);
  void* Y1H = alloc(MB8);  void* Y1L = alloc(MB8);
  void* QH = alloc(MB8);   void* QL = alloc(MB8);
  void* KH = alloc(MB8);   void* KL = alloc(MB8);
  void* VT = alloc(MB8);
  void* CTX = alloc(MB8);
  void* Y2H = alloc(MB8);
  void* GLU = QH;

  prep_kernel<<<dim3(4096, 8), dim3(256), 0, stream>>>(
      wq, wk, wv, wo, w1, w3, w2,
      (unsigned short*)WQH, (unsigned short*)WQL, (unsigned short*)WKH,
      (unsigned short*)WKL, (unsigned short*)WVH, (unsigned short*)WOH,
      (unsigned short*)W1H, (unsigned short*)W3H, (unsigned short*)W2H,
      (float2*)ROPE);

  rmsnorm_kernel<<<dim3(4096), dim3(256), 0, stream>>>(
      x, g1, (unsigned short*)Y1H, (unsigned short*)Y1L);

  gemm_qk_kernel<<<dim3(512), dim3(256), 0, stream>>>(
      (const bf16*)Y1H, (const bf16*)Y1L,
      (const bf16*)WQH, (const bf16*)WQL, (const bf16*)WKH, (const bf16*)WKL,
      (const float2*)ROPE,
      (bf16*)QH, (bf16*)QL, (bf16*)KH, (bf16*)KL);

  gemm_nt<0><<<dim3(256), dim3(256), 0, stream>>>(
      (const bf16*)Y1H, (const bf16*)WVH, 1024, 1024, 1024,
      nullptr, (bf16*)VT, nullptr);

  flash_kernel<<<dim3(1024), dim3(256), 0, stream>>>(
      (const bf16*)QH, (const bf16*)QL, (const bf16*)KH, (const bf16*)KL,
      (const bf16*)VT, (bf16*)CTX);

  gemm_nt<1><<<dim3(256), dim3(256), 0, stream>>>(
      (const bf16*)CTX, (const bf16*)WOH, 1024, 1024, 1024,
      out, nullptr, x);

  rmsnorm_kernel<<<dim3(4096), dim3(256), 0, stream>>>(
      out, g2, (unsigned short*)Y2H, nullptr);

  gemm_up_kernel<<<dim3(512), dim3(512), 0, stream>>>(
      (const bf16*)Y2H, (const bf16*)W1H, (const bf16*)W3H, (bf16*)GLU);

  gemm_nt<5><<<dim3(1024), dim3(256), 0, stream>>>(
      (const bf16*)GLU, (const bf16*)W2H, 1024, 1024, 4096,
      out, nullptr, nullptr);
}

// Round 8
// 305.401 us; speedup vs baseline: 1.2609x; 1.0153x over previous
//
#include <hip/hip_runtime.h>

typedef __bf16 bf16;
typedef __attribute__((ext_vector_type(8))) __bf16 bf16x8;
typedef __attribute__((ext_vector_type(4))) float f32x4;

// swizzle for [R][32]-bf16 (64B-row) tiles (flash kernel)
static __device__ __forceinline__ int swz4(int r) { return (r >> 1) & 3; }

static __device__ __forceinline__ void async_cp16(void* lds, const void* g) {
  __builtin_amdgcn_global_load_lds((__attribute__((address_space(1))) void*)g,
                                   (__attribute__((address_space(3))) void*)lds,
                                   16, 0, 0);
}

static __device__ __forceinline__ f32x4 mfma16(bf16x8 a, bf16x8 b, f32x4 c) {
  return __builtin_amdgcn_mfma_f32_16x16x32_bf16(a, b, c, 0, 0, 0);
}

static __device__ __forceinline__ unsigned short bfbits(float f) {
  bf16 b = (bf16)f;
  return __builtin_bit_cast(unsigned short, b);
}

// ---------------- fused prep: 7 weight conversions + rope table, one launch ----------------
extern "C" __global__ void prep_kernel(
    const float* __restrict__ wq, const float* __restrict__ wk,
    const float* __restrict__ wv, const float* __restrict__ wo,
    const float* __restrict__ w1, const float* __restrict__ w3,
    const float* __restrict__ w2,
    unsigned short* __restrict__ WQH, unsigned short* __restrict__ WQL,
    unsigned short* __restrict__ WKH, unsigned short* __restrict__ WKL,
    unsigned short* __restrict__ WVH, unsigned short* __restrict__ WOH,
    unsigned short* __restrict__ W1H, unsigned short* __restrict__ W3H,
    unsigned short* __restrict__ W2H, float2* __restrict__ rope) {
  const int seg = blockIdx.y;
  const int i = blockIdx.x * 256 + threadIdx.x;
  if (seg == 7) {
    if (i >= 32768) return;
    int s = i >> 5, fi = i & 31;
    float inv_freq = powf(10000.0f, -(2.0f * (float)fi) / 64.0f);
    float ang = (float)s * inv_freq;
    float2 cs;
    cs.x = cosf(ang);
    cs.y = sinf(ang);
    rope[i] = cs;
    return;
  }
  const float* src;
  unsigned short* hi_;
  unsigned short* lo_ = nullptr;
  int n4;
  switch (seg) {
    case 0: src = wq; hi_ = WQH; lo_ = WQL; n4 = 262144; break;
    case 1: src = wk; hi_ = WKH; lo_ = WKL; n4 = 262144; break;
    case 2: src = wv; hi_ = WVH; n4 = 262144; break;
    case 3: src = wo; hi_ = WOH; n4 = 262144; break;
    case 4: src = w1; hi_ = W1H; n4 = 1048576; break;
    case 5: src = w3; hi_ = W3H; n4 = 1048576; break;
    default: src = w2; hi_ = W2H; n4 = 1048576; break;
  }
  if (i >= n4) return;
  float4 v = ((const float4*)src)[i];
  bf16 b0 = (bf16)v.x, b1 = (bf16)v.y, b2 = (bf16)v.z, b3 = (bf16)v.w;
  ushort4 oh;
  oh.x = __builtin_bit_cast(unsigned short, b0);
  oh.y = __builtin_bit_cast(unsigned short, b1);
  oh.z = __builtin_bit_cast(unsigned short, b2);
  oh.w = __builtin_bit_cast(unsigned short, b3);
  ((ushort4*)hi_)[i] = oh;
  if (lo_) {
    ushort4 ol;
    ol.x = bfbits(v.x - (float)b0);
    ol.y = bfbits(v.y - (float)b1);
    ol.z = bfbits(v.z - (float)b2);
    ol.w = bfbits(v.w - (float)b3);
    ((ushort4*)lo_)[i] = ol;
  }
}

extern "C" __global__ __launch_bounds__(256) void rmsnorm_kernel(
    const float* __restrict__ x, const float* __restrict__ g,
    unsigned short* __restrict__ yhi, unsigned short* __restrict__ ylo) {
  int row = blockIdx.x;
  int t = threadIdx.x;
  const float4 xv = *(const float4*)(x + (size_t)row * 1024 + t * 4);
  float ss = xv.x * xv.x + xv.y * xv.y + xv.z * xv.z + xv.w * xv.w;
#pragma unroll
  for (int d = 1; d < 64; d <<= 1) ss += __shfl_xor(ss, d, 64);
  __shared__ float red[4];
  if ((t & 63) == 0) red[t >> 6] = ss;
  __syncthreads();
  float tot = red[0] + red[1] + red[2] + red[3];
  float inv = 1.0f / sqrtf(tot * (1.0f / 1024.0f) + 1e-5f);
  const float4 gv = *(const float4*)(g + t * 4);
  float y0 = xv.x * gv.x * inv, y1 = xv.y * gv.y * inv;
  float y2 = xv.z * gv.z * inv, y3 = xv.w * gv.w * inv;
  bf16 b0 = (bf16)y0, b1 = (bf16)y1, b2 = (bf16)y2, b3 = (bf16)y3;
  ushort4 oh;
  oh.x = __builtin_bit_cast(unsigned short, b0);
  oh.y = __builtin_bit_cast(unsigned short, b1);
  oh.z = __builtin_bit_cast(unsigned short, b2);
  oh.w = __builtin_bit_cast(unsigned short, b3);
  ((ushort4*)yhi)[(size_t)row * 256 + t] = oh;
  if (ylo) {
    ushort4 ol;
    ol.x = bfbits(y0 - (float)b0);
    ol.y = bfbits(y1 - (float)b1);
    ol.z = bfbits(y2 - (float)b2);
    ol.w = bfbits(y3 - (float)b3);
    ((ushort4*)ylo)[(size_t)row * 256 + t] = ol;
  }
}

// ---------------- GEMM: C[M,N] = A[M,K(ldk)] * B[N,K(ldk)]^T, 128x128 tile, BK=64 ----------------
// [128][64] LDS tiles, 128B rows, swizzle c ^= r&7. Flat grid, XCD-chunked M-slab.
// z = sq>>5 = K-slice for split-K. EPI 0: vT store; EPI 1: +resF -> f32; EPI 5: atomicAdd f32
template <int EPI>
__global__ __launch_bounds__(256, 2) void gemm_nt(
    const bf16* __restrict__ A, const bf16* __restrict__ B, int N, int K, int ldk,
    float* __restrict__ outF, bf16* __restrict__ outB,
    const float* __restrict__ resF) {
  const int bid = blockIdx.x;
  const int xcd = bid & 7, sq = bid >> 3;
  const int z = sq >> 5;
  const int rem = sq & 31;
  const size_t tm = (size_t)(xcd * 4 + (rem >> 3)) * 128;
  const size_t tn = (size_t)(rem & 7) * 128;
  A += (size_t)z * K;
  B += (size_t)z * K;
  __shared__ alignas(16) bf16 As[128 * 64];
  __shared__ alignas(16) bf16 Bs[128 * 64];
  const int tid = threadIdx.x;
  const int lane = tid & 63, wave = tid >> 6;
  const int lo = lane & 15, hi = lane >> 4;
  const int wm = wave >> 1, wn = wave & 1;
  f32x4 acc[4][4] = {};
  for (int k0 = 0; k0 < K; k0 += 64) {
    __syncthreads();
#pragma unroll
    for (int i4 = 0; i4 < 4; i4++) {
      int p = tid + 256 * i4;
      int row = p >> 3, c = p & 7;
      int cs = c ^ (row & 7);
      async_cp16((char*)As + (size_t)p * 16, A + (tm + row) * (size_t)ldk + k0 + cs * 8);
      async_cp16((char*)Bs + (size_t)p * 16, B + (tn + row) * (size_t)ldk + k0 + cs * 8);
    }
    __syncthreads();
#pragma unroll
    for (int kh = 0; kh < 2; kh++) {
      bf16x8 fa[4], fb[4];
#pragma unroll
      for (int i = 0; i < 4; i++) {
        int ra = wm * 64 + i * 16 + lo;
        fa[i] = *(const bf16x8*)((const char*)As + ra * 128 + (((kh * 4 + hi) ^ (ra & 7)) << 4));
        int rb = wn * 64 + i * 16 + lo;
        fb[i] = *(const bf16x8*)((const char*)Bs + rb * 128 + (((kh * 4 + hi) ^ (rb & 7)) << 4));
      }
      __builtin_amdgcn_s_setprio(1);
#pragma unroll
      for (int i = 0; i < 4; i++)
#pragma unroll
        for (int j = 0; j < 4; j++) acc[i][j] = mfma16(fa[i], fb[j], acc[i][j]);
      __builtin_amdgcn_s_setprio(0);
    }
  }
#pragma unroll
  for (int i = 0; i < 4; i++)
#pragma unroll
    for (int j = 0; j < 4; j++)
#pragma unroll
      for (int r = 0; r < 4; r++) {
        size_t m = tm + wm * 64 + i * 16 + hi * 4 + r;
        size_t n = tn + wn * 64 + j * 16 + lo;
        float v = acc[i][j][r];
        if constexpr (EPI == 0) {
          size_t idx = (((m >> 10) * 16 + (n >> 6)) * 64 + (n & 63)) * 1024 + (m & 1023);
          outB[idx] = (bf16)v;
        } else if constexpr (EPI == 1) {
          size_t idx = m * (size_t)N + n;
          outF[idx] = v + resF[idx];
        } else {
          atomicAdd(&outF[m * (size_t)N + n], v);
        }
      }
}

// ---------------- fused FFN-up v2: G = silu(A*B1^T) * (A*B3^T) ----------------
// Same structure as gemm_nt BK=64 (proven): 128x128 tile, 4 waves, 48KB LDS,
// 2 blocks/CU, single-buffer 2-barrier loop, dual acc, fused silu epilogue.
// Grid 1024 flat: xcd = bid&7 owns M-slab of 4 y-tiles; sq>>2 = n-tile 0..31.
extern "C" __global__ __launch_bounds__(256, 2) void gemm_up_kernel(
    const bf16* __restrict__ A, const bf16* __restrict__ B1,
    const bf16* __restrict__ B3, bf16* __restrict__ G) {
  const int bid = blockIdx.x;
  const int xcd = bid & 7, sq = bid >> 3;  // sq 0..127
  const size_t tm = (size_t)(xcd * 4 + (sq & 3)) * 128;
  const size_t tn = (size_t)(sq >> 2) * 128;
  __shared__ alignas(16) bf16 As[128 * 64];
  __shared__ alignas(16) bf16 B1s[128 * 64];
  __shared__ alignas(16) bf16 B3s[128 * 64];
  const int tid = threadIdx.x;
  const int lane = tid & 63, wave = tid >> 6;
  const int lo = lane & 15, hi = lane >> 4;
  const int wm = wave >> 1, wn = wave & 1;
  f32x4 acc1[4][4] = {}, acc3[4][4] = {};
  for (int k0 = 0; k0 < 1024; k0 += 64) {
    __syncthreads();
#pragma unroll
    for (int i4 = 0; i4 < 4; i4++) {
      int p = tid + 256 * i4;
      int row = p >> 3, c = p & 7;
      int cs = c ^ (row & 7);
      async_cp16((char*)As + (size_t)p * 16, A + (tm + row) * (size_t)1024 + k0 + cs * 8);
      async_cp16((char*)B1s + (size_t)p * 16, B1 + (tn + row) * (size_t)1024 + k0 + cs * 8);
      async_cp16((char*)B3s + (size_t)p * 16, B3 + (tn + row) * (size_t)1024 + k0 + cs * 8);
    }
    __syncthreads();
#pragma unroll
    for (int kh = 0; kh < 2; kh++) {
      bf16x8 fa[4], fb[4];
#pragma unroll
      for (int i = 0; i < 4; i++) {
        int ra = wm * 64 + i * 16 + lo;
        fa[i] = *(const bf16x8*)((const char*)As + ra * 128 + (((kh * 4 + hi) ^ (ra & 7)) << 4));
        int rb = wn * 64 + i * 16 + lo;
        fb[i] = *(const bf16x8*)((const char*)B1s + rb * 128 + (((kh * 4 + hi) ^ (rb & 7)) << 4));
      }
      __builtin_amdgcn_s_setprio(1);
#pragma unroll
      for (int i = 0; i < 4; i++)
#pragma unroll
        for (int j = 0; j < 4; j++) acc1[i][j] = mfma16(fa[i], fb[j], acc1[i][j]);
      __builtin_amdgcn_s_setprio(0);
#pragma unroll
      for (int j = 0; j < 4; j++) {
        int rb = wn * 64 + j * 16 + lo;
        fb[j] = *(const bf16x8*)((const char*)B3s + rb * 128 + (((kh * 4 + hi) ^ (rb & 7)) << 4));
      }
      __builtin_amdgcn_s_setprio(1);
#pragma unroll
      for (int i = 0; i < 4; i++)
#pragma unroll
        for (int j = 0; j < 4; j++) acc3[i][j] = mfma16(fa[i], fb[j], acc3[i][j]);
      __builtin_amdgcn_s_setprio(0);
    }
  }
#pragma unroll
  for (int i = 0; i < 4; i++)
#pragma unroll
    for (int j = 0; j < 4; j++)
#pragma unroll
      for (int r = 0; r < 4; r++) {
        size_t m = tm + wm * 64 + i * 16 + hi * 4 + r;
        size_t n = tn + wn * 64 + j * 16 + lo;
        float v1 = acc1[i][j][r], v3 = acc3[i][j][r];
        G[m * 4096 + n] = (bf16)(v1 / (1.0f + __expf(-v1)) * v3);
      }
}

// ---------------- split-precision q/k projection GEMM with fused RoPE, BK=64 ----------------
extern "C" __global__ __launch_bounds__(256, 2) void gemm_qk_kernel(
    const bf16* __restrict__ Ah, const bf16* __restrict__ Al,
    const bf16* __restrict__ BhQ, const bf16* __restrict__ BlQ,
    const bf16* __restrict__ BhK, const bf16* __restrict__ BlK,
    const float2* __restrict__ rope,
    bf16* __restrict__ OhQ, bf16* __restrict__ OlQ,
    bf16* __restrict__ OhK, bf16* __restrict__ OlK) {
  const int bid = blockIdx.x;
  const int xcd = bid & 7, sq = bid >> 3;
  const int zqk = sq >> 5;
  const int rem = sq & 31;
  const size_t tm = (size_t)(xcd * 4 + (rem >> 3)) * 128;
  const size_t tn = (size_t)(rem & 7) * 128;
  const bf16* Bh = zqk ? BhK : BhQ;
  const bf16* Bl = zqk ? BlK : BlQ;
  bf16* Oh = zqk ? OhK : OhQ;
  bf16* Ol = zqk ? OlK : OlQ;
  __shared__ alignas(16) bf16 Ahs[128 * 64], Als[128 * 64];
  __shared__ alignas(16) bf16 Bhs[128 * 64], Bls[128 * 64];
  const int tid = threadIdx.x;
  const int lane = tid & 63, wave = tid >> 6;
  const int lo = lane & 15, hi = lane >> 4;
  const int wm = wave >> 1, wn = wave & 1;
  const int K = 1024;
  f32x4 acc[4][4] = {};
  for (int k0 = 0; k0 < K; k0 += 64) {
    __syncthreads();
#pragma unroll
    for (int i4 = 0; i4 < 4; i4++) {
      int p = tid + 256 * i4;
      int row = p >> 3, c = p & 7;
      int cs = c ^ (row & 7);
      size_t ga = (tm + row) * (size_t)K + k0 + cs * 8;
      size_t gb = (tn + row) * (size_t)K + k0 + cs * 8;
      async_cp16((char*)Ahs + (size_t)p * 16, Ah + ga);
      async_cp16((char*)Als + (size_t)p * 16, Al + ga);
      async_cp16((char*)Bhs + (size_t)p * 16, Bh + gb);
      async_cp16((char*)Bls + (size_t)p * 16, Bl + gb);
    }
    __syncthreads();
#pragma unroll
    for (int kh = 0; kh < 2; kh++) {
      int offa[4], offb[4];
#pragma unroll
      for (int i = 0; i < 4; i++) {
        int ra = wm * 64 + i * 16 + lo;
        offa[i] = ra * 128 + (((kh * 4 + hi) ^ (ra & 7)) << 4);
        int rb = wn * 64 + i * 16 + lo;
        offb[i] = rb * 128 + (((kh * 4 + hi) ^ (rb & 7)) << 4);
      }
      bf16x8 fah[4], fbh[4], fx[4];
#pragma unroll
      for (int i = 0; i < 4; i++) {
        fah[i] = *(const bf16x8*)((const char*)Ahs + offa[i]);
        fbh[i] = *(const bf16x8*)((const char*)Bhs + offb[i]);
      }
      __builtin_amdgcn_s_setprio(1);
#pragma unroll
      for (int i = 0; i < 4; i++)
#pragma unroll
        for (int j = 0; j < 4; j++) acc[i][j] = mfma16(fah[i], fbh[j], acc[i][j]);
      __builtin_amdgcn_s_setprio(0);
#pragma unroll
      for (int j = 0; j < 4; j++) fx[j] = *(const bf16x8*)((const char*)Bls + offb[j]);
      __builtin_amdgcn_s_setprio(1);
#pragma unroll
      for (int i = 0; i < 4; i++)
#pragma unroll
        for (int j = 0; j < 4; j++) acc[i][j] = mfma16(fah[i], fx[j], acc[i][j]);
      __builtin_amdgcn_s_setprio(0);
#pragma unroll
      for (int i = 0; i < 4; i++) fx[i] = *(const bf16x8*)((const char*)Als + offa[i]);
      __builtin_amdgcn_s_setprio(1);
#pragma unroll
      for (int i = 0; i < 4; i++)
#pragma unroll
        for (int j = 0; j < 4; j++) acc[i][j] = mfma16(fx[i], fbh[j], acc[i][j]);
      __builtin_amdgcn_s_setprio(0);
    }
  }
#pragma unroll
  for (int i = 0; i < 4; i++)
#pragma unroll
    for (int j = 0; j < 4; j++)
#pragma unroll
      for (int r = 0; r < 4; r++) {
        float v = acc[i][j][r];
        float vp = __shfl_xor(v, 1, 64);
        size_t m = tm + wm * 64 + i * 16 + hi * 4 + r;
        size_t n = tn + wn * 64 + j * 16 + lo;
        int s = (int)(m & 1023);
        int pi = (int)((n & 63) >> 1);
        float2 cs = rope[s * 32 + pi];
        float res = (n & 1) ? (vp * cs.y + v * cs.x) : (v * cs.x - vp * cs.y);
        size_t idx = (((m >> 10) * 16 + (n >> 6)) * 1024 + (m & 1023)) * 64 + (n & 63);
        bf16 hb = (bf16)res;
        Oh[idx] = hb;
        Ol[idx] = (bf16)(res - (float)hb);
      }
}

// ---------------- flash attention (unchanged) ----------------
extern "C" __global__ __launch_bounds__(256, 4) void flash_kernel(
    const bf16* __restrict__ qhi, const bf16* __restrict__ qlo,
    const bf16* __restrict__ khi, const bf16* __restrict__ klo,
    const bf16* __restrict__ vT, bf16* __restrict__ ctx) {
  const int bid = blockIdx.x;
  const int qb = bid >> 6;
  const int bh = bid & 63;
  const int tid = threadIdx.x;
  const int wave = tid >> 6, lane = tid & 63;
  const int lo = lane & 15, hi = lane >> 4;

  __shared__ alignas(16) bf16 Ksh[2][64][32];
  __shared__ alignas(16) bf16 Ksl[2][64][32];
  __shared__ alignas(16) bf16 Vs[2][64][32];
  __shared__ alignas(16) bf16 P[4][16][72];

  size_t qoff = ((size_t)bh * 1024 + qb * 64 + wave * 16 + lo) * 64;
  bf16x8 qh[2], ql[2];
#pragma unroll
  for (int ks = 0; ks < 2; ks++) {
    qh[ks] = *(const bf16x8*)(qhi + qoff + ks * 32 + hi * 8);
    ql[ks] = *(const bf16x8*)(qlo + qoff + ks * 32 + hi * 8);
  }

  const int srow = tid >> 2;
  const int scl = (tid & 3) ^ swz4(srow);
  const size_t kgb = (size_t)bh * 1024 * 64;
  const size_t vgb = ((size_t)bh * 64 + srow) * 1024;

  float mrun[4] = {-1e30f, -1e30f, -1e30f, -1e30f};
  float lrun[4] = {0.f, 0.f, 0.f, 0.f};
  f32x4 o[4] = {};
  const float scale = 0.125f;

  for (int kt = 0; kt <= qb; kt++) {
    __syncthreads();
#pragma unroll
    for (int i = 0; i < 2; i++) {
      int p = tid + 256 * i;
      size_t gk = kgb + (size_t)(kt * 64 + srow) * 64 + i * 32 + scl * 8;
      async_cp16((char*)Ksh + (size_t)p * 16, khi + gk);
      async_cp16((char*)Ksl + (size_t)p * 16, klo + gk);
      async_cp16((char*)Vs + (size_t)p * 16, vT + vgb + kt * 64 + i * 32 + scl * 8);
    }
    __syncthreads();

    f32x4 sv[4];
    __builtin_amdgcn_s_setprio(1);
#pragma unroll
    for (int nb = 0; nb < 4; nb++) {
      f32x4 a = {0.f, 0.f, 0.f, 0.f};
#pragma unroll
      for (int ks = 0; ks < 2; ks++) {
        int row = nb * 16 + lo;
        int off16 = (ks * 64 + row) * 4 + (hi ^ swz4(row));
        bf16x8 kh = *(const bf16x8*)((const char*)Ksh + off16 * 16);
        bf16x8 kl = *(const bf16x8*)((const char*)Ksl + off16 * 16);
        a = mfma16(qh[ks], kh, a);
        a = mfma16(qh[ks], kl, a);
        a = mfma16(ql[ks], kh, a);
      }
      sv[nb] = a;
    }
    __builtin_amdgcn_s_setprio(0);

    const bool mt = (kt == qb);
#pragma unroll
    for (int nb = 0; nb < 4; nb++)
#pragma unroll
      for (int r = 0; r < 4; r++) {
        float s = sv[nb][r] * scale;
        if (mt) {
          int kp = nb * 16 + lo;
          int qr = wave * 16 + hi * 4 + r;
          if (kp > qr) s = -1e30f;
        }
        sv[nb][r] = s;
      }
    float mnew[4], rs[4];
#pragma unroll
    for (int r = 0; r < 4; r++) {
      float mx = fmaxf(fmaxf(sv[0][r], sv[1][r]), fmaxf(sv[2][r], sv[3][r]));
#pragma unroll
      for (int d = 1; d < 16; d <<= 1) mx = fmaxf(mx, __shfl_xor(mx, d, 64));
      mnew[r] = fmaxf(mrun[r], mx);
      float sc = __expf(mrun[r] - mnew[r]);
      lrun[r] *= sc;
#pragma unroll
      for (int db = 0; db < 4; db++) o[db][r] *= sc;
      mrun[r] = mnew[r];
      rs[r] = 0.f;
    }
#pragma unroll
    for (int nb = 0; nb < 4; nb++)
#pragma unroll
      for (int r = 0; r < 4; r++) {
        float p = __expf(sv[nb][r] - mnew[r]);
        bf16 pb = (bf16)p;
        rs[r] += (float)pb;
        P[wave][hi * 4 + r][nb * 16 + lo] = pb;
      }
#pragma unroll
    for (int r = 0; r < 4; r++) {
      float t = rs[r];
#pragma unroll
      for (int d = 1; d < 16; d <<= 1) t += __shfl_xor(t, d, 64);
      lrun[r] += t;
    }
    bf16x8 pa[2];
#pragma unroll
    for (int ks = 0; ks < 2; ks++) pa[ks] = *(const bf16x8*)&P[wave][lo][ks * 32 + hi * 8];
    __builtin_amdgcn_s_setprio(1);
#pragma unroll
    for (int db = 0; db < 4; db++)
#pragma unroll
      for (int ks = 0; ks < 2; ks++) {
        int row = db * 16 + lo;
        int off16 = (ks * 64 + row) * 4 + (hi ^ swz4(row));
        bf16x8 vf = *(const bf16x8*)((const char*)Vs + off16 * 16);
        o[db] = mfma16(pa[ks], vf, o[db]);
      }
    __builtin_amdgcn_s_setprio(0);
  }
  int b = bh >> 4, h = bh & 15;
#pragma unroll
  for (int db = 0; db < 4; db++)
#pragma unroll
    for (int r = 0; r < 4; r++) {
      float val = o[db][r] / lrun[r];
      size_t row = (size_t)b * 1024 + qb * 64 + wave * 16 + hi * 4 + r;
      ctx[row * 1024 + h * 64 + db * 16 + lo] = (bf16)val;
    }
}

// ---------------- host launcher ----------------

extern "C" void kernel_launch(void* const* d_in, const int* in_sizes, int n_in,
                              void* d_out, int out_size, void* d_ws, size_t ws_size,
                              hipStream_t stream) {
  (void)in_sizes; (void)n_in; (void)out_size; (void)ws_size;
  const float* x  = (const float*)d_in[0];
  const float* wq = (const float*)d_in[1];
  const float* wk = (const float*)d_in[2];
  const float* wv = (const float*)d_in[3];
  const float* wo = (const float*)d_in[4];
  const float* w1 = (const float*)d_in[5];
  const float* w2 = (const float*)d_in[6];
  const float* w3 = (const float*)d_in[7];
  const float* g1 = (const float*)d_in[8];
  const float* g2 = (const float*)d_in[9];
  float* out = (float*)d_out;

  char* ws = (char*)d_ws;
  size_t off = 0;
  auto alloc = [&](size_t bytes) {
    char* p = ws + off;
    off += (bytes + 255) & ~(size_t)255;
    return p;
  };
  const size_t MB2 = 1024u * 1024u * 2u;
  const size_t MB8 = 4096u * 1024u * 2u;
  void* WQH = alloc(MB2);  void* WQL = alloc(MB2);
  void* WKH = alloc(MB2);  void* WKL = alloc(MB2);
  void* WVH = alloc(MB2);  void* WOH = alloc(MB2);
  void* W1H = alloc(MB8);  void* W3H = alloc(MB8);  void* W2H = alloc(MB8);
  void* ROPE = alloc(32768u * 8u);
  void* Y1H = alloc(MB8);  void* Y1L = alloc(MB8);
  void* QH = alloc(MB8);   void* QL = alloc(MB8);
  void* KH = alloc(MB8);   void* KL = alloc(MB8);
  void* VT = alloc(MB8);
  void* CTX = alloc(MB8);
  void* Y2H = alloc(MB8);
  void* GLU = QH;

  prep_kernel<<<dim3(4096, 8), dim3(256), 0, stream>>>(
      wq, wk, wv, wo, w1, w3, w2,
      (unsigned short*)WQH, (unsigned short*)WQL, (unsigned short*)WKH,
      (unsigned short*)WKL, (unsigned short*)WVH, (unsigned short*)WOH,
      (unsigned short*)W1H, (unsigned short*)W3H, (unsigned short*)W2H,
      (float2*)ROPE);

  rmsnorm_kernel<<<dim3(4096), dim3(256), 0, stream>>>(
      x, g1, (unsigned short*)Y1H, (unsigned short*)Y1L);

  gemm_qk_kernel<<<dim3(512), dim3(256), 0, stream>>>(
      (const bf16*)Y1H, (const bf16*)Y1L,
      (const bf16*)WQH, (const bf16*)WQL, (const bf16*)WKH, (const bf16*)WKL,
      (const float2*)ROPE,
      (bf16*)QH, (bf16*)QL, (bf16*)KH, (bf16*)KL);

  gemm_nt<0><<<dim3(256), dim3(256), 0, stream>>>(
      (const bf16*)Y1H, (const bf16*)WVH, 1024, 1024, 1024,
      nullptr, (bf16*)VT, nullptr);

  flash_kernel<<<dim3(1024), dim3(256), 0, stream>>>(
      (const bf16*)QH, (const bf16*)QL, (const bf16*)KH, (const bf16*)KL,
      (const bf16*)VT, (bf16*)CTX);

  gemm_nt<1><<<dim3(256), dim3(256), 0, stream>>>(
      (const bf16*)CTX, (const bf16*)WOH, 1024, 1024, 1024,
      out, nullptr, x);

  rmsnorm_kernel<<<dim3(4096), dim3(256), 0, stream>>>(
      out, g2, (unsigned short*)Y2H, nullptr);

  // fused SwiGLU up-projection: 1024 blocks, 128x128 tiles, 2 blocks/CU
  gemm_up_kernel<<<dim3(1024), dim3(256), 0, stream>>>(
      (const bf16*)Y2H, (const bf16*)W1H, (const bf16*)W3H, (bf16*)GLU);

  gemm_nt<5><<<dim3(1024), dim3(256), 0, stream>>>(
      (const bf16*)GLU, (const bf16*)W2H, 1024, 1024, 4096,
      out, nullptr, nullptr);
}

// Round 10
// 290.609 us; speedup vs baseline: 1.3251x; 1.0509x over previous
//
#include <hip/hip_runtime.h>

typedef __bf16 bf16;
typedef __attribute__((ext_vector_type(8))) __bf16 bf16x8;
typedef __attribute__((ext_vector_type(4))) float f32x4;

// swizzle for [R][32]-bf16 (64B-row) tiles (flash kernel)
static __device__ __forceinline__ int swz4(int r) { return (r >> 1) & 3; }

static __device__ __forceinline__ void async_cp16(void* lds, const void* g) {
  __builtin_amdgcn_global_load_lds((__attribute__((address_space(1))) void*)g,
                                   (__attribute__((address_space(3))) void*)lds,
                                   16, 0, 0);
}

static __device__ __forceinline__ f32x4 mfma16(bf16x8 a, bf16x8 b, f32x4 c) {
  return __builtin_amdgcn_mfma_f32_16x16x32_bf16(a, b, c, 0, 0, 0);
}

static __device__ __forceinline__ unsigned short bfbits(float f) {
  bf16 b = (bf16)f;
  return __builtin_bit_cast(unsigned short, b);
}

// ---------------- fused prep: 7 weight conversions + rope table, one launch ----------------
// NOTE: wq/wk get hi+lo split — the score path REQUIRES it (R9 post-mortem: the
// FFN amplifies residual-stream errors ~20x; score-error budget is ~0.05 sigma).
extern "C" __global__ void prep_kernel(
    const float* __restrict__ wq, const float* __restrict__ wk,
    const float* __restrict__ wv, const float* __restrict__ wo,
    const float* __restrict__ w1, const float* __restrict__ w3,
    const float* __restrict__ w2,
    unsigned short* __restrict__ WQH, unsigned short* __restrict__ WQL,
    unsigned short* __restrict__ WKH, unsigned short* __restrict__ WKL,
    unsigned short* __restrict__ WVH, unsigned short* __restrict__ WOH,
    unsigned short* __restrict__ W1H, unsigned short* __restrict__ W3H,
    unsigned short* __restrict__ W2H, float2* __restrict__ rope) {
  const int seg = blockIdx.y;
  const int i = blockIdx.x * 256 + threadIdx.x;
  if (seg == 7) {
    if (i >= 32768) return;
    int s = i >> 5, fi = i & 31;
    float inv_freq = powf(10000.0f, -(2.0f * (float)fi) / 64.0f);
    float ang = (float)s * inv_freq;
    float2 cs;
    cs.x = cosf(ang);
    cs.y = sinf(ang);
    rope[i] = cs;
    return;
  }
  const float* src;
  unsigned short* hi_;
  unsigned short* lo_ = nullptr;
  int n4;
  switch (seg) {
    case 0: src = wq; hi_ = WQH; lo_ = WQL; n4 = 262144; break;
    case 1: src = wk; hi_ = WKH; lo_ = WKL; n4 = 262144; break;
    case 2: src = wv; hi_ = WVH; n4 = 262144; break;
    case 3: src = wo; hi_ = WOH; n4 = 262144; break;
    case 4: src = w1; hi_ = W1H; n4 = 1048576; break;
    case 5: src = w3; hi_ = W3H; n4 = 1048576; break;
    default: src = w2; hi_ = W2H; n4 = 1048576; break;
  }
  if (i >= n4) return;
  float4 v = ((const float4*)src)[i];
  bf16 b0 = (bf16)v.x, b1 = (bf16)v.y, b2 = (bf16)v.z, b3 = (bf16)v.w;
  ushort4 oh;
  oh.x = __builtin_bit_cast(unsigned short, b0);
  oh.y = __builtin_bit_cast(unsigned short, b1);
  oh.z = __builtin_bit_cast(unsigned short, b2);
  oh.w = __builtin_bit_cast(unsigned short, b3);
  ((ushort4*)hi_)[i] = oh;
  if (lo_) {
    ushort4 ol;
    ol.x = bfbits(v.x - (float)b0);
    ol.y = bfbits(v.y - (float)b1);
    ol.z = bfbits(v.z - (float)b2);
    ol.w = bfbits(v.w - (float)b3);
    ((ushort4*)lo_)[i] = ol;
  }
}

extern "C" __global__ __launch_bounds__(256) void rmsnorm_kernel(
    const float* __restrict__ x, const float* __restrict__ g,
    unsigned short* __restrict__ yhi, unsigned short* __restrict__ ylo) {
  int row = blockIdx.x;
  int t = threadIdx.x;
  const float4 xv = *(const float4*)(x + (size_t)row * 1024 + t * 4);
  float ss = xv.x * xv.x + xv.y * xv.y + xv.z * xv.z + xv.w * xv.w;
#pragma unroll
  for (int d = 1; d < 64; d <<= 1) ss += __shfl_xor(ss, d, 64);
  __shared__ float red[4];
  if ((t & 63) == 0) red[t >> 6] = ss;
  __syncthreads();
  float tot = red[0] + red[1] + red[2] + red[3];
  float inv = 1.0f / sqrtf(tot * (1.0f / 1024.0f) + 1e-5f);
  const float4 gv = *(const float4*)(g + t * 4);
  float y0 = xv.x * gv.x * inv, y1 = xv.y * gv.y * inv;
  float y2 = xv.z * gv.z * inv, y3 = xv.w * gv.w * inv;
  bf16 b0 = (bf16)y0, b1 = (bf16)y1, b2 = (bf16)y2, b3 = (bf16)y3;
  ushort4 oh;
  oh.x = __builtin_bit_cast(unsigned short, b0);
  oh.y = __builtin_bit_cast(unsigned short, b1);
  oh.z = __builtin_bit_cast(unsigned short, b2);
  oh.w = __builtin_bit_cast(unsigned short, b3);
  ((ushort4*)yhi)[(size_t)row * 256 + t] = oh;
  if (ylo) {
    ushort4 ol;
    ol.x = bfbits(y0 - (float)b0);
    ol.y = bfbits(y1 - (float)b1);
    ol.z = bfbits(y2 - (float)b2);
    ol.w = bfbits(y3 - (float)b3);
    ((ushort4*)ylo)[(size_t)row * 256 + t] = ol;
  }
}

// ---------------- GEMM: C[M,N] = A[M,K(ldk)] * B[N,K(ldk)]^T, 128x128 tile, BK=64 ----------------
// [128][64] LDS tiles, 128B rows, swizzle c ^= r&7. Flat grid, XCD-chunked M-slab.
// z = sq>>5 = K-slice for split-K. EPI 0: vT store; EPI 1: +resF -> f32; EPI 5: atomicAdd f32
template <int EPI>
__global__ __launch_bounds__(256, 2) void gemm_nt(
    const bf16* __restrict__ A, const bf16* __restrict__ B, int N, int K, int ldk,
    float* __restrict__ outF, bf16* __restrict__ outB,
    const float* __restrict__ resF) {
  const int bid = blockIdx.x;
  const int xcd = bid & 7, sq = bid >> 3;
  const int z = sq >> 5;
  const int rem = sq & 31;
  const size_t tm = (size_t)(xcd * 4 + (rem >> 3)) * 128;
  const size_t tn = (size_t)(rem & 7) * 128;
  A += (size_t)z * K;
  B += (size_t)z * K;
  __shared__ alignas(16) bf16 As[128 * 64];
  __shared__ alignas(16) bf16 Bs[128 * 64];
  const int tid = threadIdx.x;
  const int lane = tid & 63, wave = tid >> 6;
  const int lo = lane & 15, hi = lane >> 4;
  const int wm = wave >> 1, wn = wave & 1;
  f32x4 acc[4][4] = {};
  for (int k0 = 0; k0 < K; k0 += 64) {
    __syncthreads();
#pragma unroll
    for (int i4 = 0; i4 < 4; i4++) {
      int p = tid + 256 * i4;
      int row = p >> 3, c = p & 7;
      int cs = c ^ (row & 7);
      async_cp16((char*)As + (size_t)p * 16, A + (tm + row) * (size_t)ldk + k0 + cs * 8);
      async_cp16((char*)Bs + (size_t)p * 16, B + (tn + row) * (size_t)ldk + k0 + cs * 8);
    }
    __syncthreads();
#pragma unroll
    for (int kh = 0; kh < 2; kh++) {
      bf16x8 fa[4], fb[4];
#pragma unroll
      for (int i = 0; i < 4; i++) {
        int ra = wm * 64 + i * 16 + lo;
        fa[i] = *(const bf16x8*)((const char*)As + ra * 128 + (((kh * 4 + hi) ^ (ra & 7)) << 4));
        int rb = wn * 64 + i * 16 + lo;
        fb[i] = *(const bf16x8*)((const char*)Bs + rb * 128 + (((kh * 4 + hi) ^ (rb & 7)) << 4));
      }
      __builtin_amdgcn_s_setprio(1);
#pragma unroll
      for (int i = 0; i < 4; i++)
#pragma unroll
        for (int j = 0; j < 4; j++) acc[i][j] = mfma16(fa[i], fb[j], acc[i][j]);
      __builtin_amdgcn_s_setprio(0);
    }
  }
#pragma unroll
  for (int i = 0; i < 4; i++)
#pragma unroll
    for (int j = 0; j < 4; j++)
#pragma unroll
      for (int r = 0; r < 4; r++) {
        size_t m = tm + wm * 64 + i * 16 + hi * 4 + r;
        size_t n = tn + wn * 64 + j * 16 + lo;
        float v = acc[i][j][r];
        if constexpr (EPI == 0) {
          size_t idx = (((m >> 10) * 16 + (n >> 6)) * 64 + (n & 63)) * 1024 + (m & 1023);
          outB[idx] = (bf16)v;
        } else if constexpr (EPI == 1) {
          size_t idx = m * (size_t)N + n;
          outF[idx] = v + resF[idx];
        } else {
          atomicAdd(&outF[m * (size_t)N + n], v);
        }
      }
}

// ---------------- fused FFN-up: G = silu(A*B1^T) * (A*B3^T), 128x128, BK=64 ----------------
extern "C" __global__ __launch_bounds__(256, 2) void gemm_up_kernel(
    const bf16* __restrict__ A, const bf16* __restrict__ B1,
    const bf16* __restrict__ B3, bf16* __restrict__ G) {
  const int bid = blockIdx.x;
  const int xcd = bid & 7, sq = bid >> 3;
  const size_t tm = (size_t)(xcd * 4 + (sq & 3)) * 128;
  const size_t tn = (size_t)(sq >> 2) * 128;
  __shared__ alignas(16) bf16 As[128 * 64];
  __shared__ alignas(16) bf16 B1s[128 * 64];
  __shared__ alignas(16) bf16 B3s[128 * 64];
  const int tid = threadIdx.x;
  const int lane = tid & 63, wave = tid >> 6;
  const int lo = lane & 15, hi = lane >> 4;
  const int wm = wave >> 1, wn = wave & 1;
  f32x4 acc1[4][4] = {}, acc3[4][4] = {};
  for (int k0 = 0; k0 < 1024; k0 += 64) {
    __syncthreads();
#pragma unroll
    for (int i4 = 0; i4 < 4; i4++) {
      int p = tid + 256 * i4;
      int row = p >> 3, c = p & 7;
      int cs = c ^ (row & 7);
      async_cp16((char*)As + (size_t)p * 16, A + (tm + row) * (size_t)1024 + k0 + cs * 8);
      async_cp16((char*)B1s + (size_t)p * 16, B1 + (tn + row) * (size_t)1024 + k0 + cs * 8);
      async_cp16((char*)B3s + (size_t)p * 16, B3 + (tn + row) * (size_t)1024 + k0 + cs * 8);
    }
    __syncthreads();
#pragma unroll
    for (int kh = 0; kh < 2; kh++) {
      bf16x8 fa[4], fb[4];
#pragma unroll
      for (int i = 0; i < 4; i++) {
        int ra = wm * 64 + i * 16 + lo;
        fa[i] = *(const bf16x8*)((const char*)As + ra * 128 + (((kh * 4 + hi) ^ (ra & 7)) << 4));
        int rb = wn * 64 + i * 16 + lo;
        fb[i] = *(const bf16x8*)((const char*)B1s + rb * 128 + (((kh * 4 + hi) ^ (rb & 7)) << 4));
      }
      __builtin_amdgcn_s_setprio(1);
#pragma unroll
      for (int i = 0; i < 4; i++)
#pragma unroll
        for (int j = 0; j < 4; j++) acc1[i][j] = mfma16(fa[i], fb[j], acc1[i][j]);
      __builtin_amdgcn_s_setprio(0);
#pragma unroll
      for (int j = 0; j < 4; j++) {
        int rb = wn * 64 + j * 16 + lo;
        fb[j] = *(const bf16x8*)((const char*)B3s + rb * 128 + (((kh * 4 + hi) ^ (rb & 7)) << 4));
      }
      __builtin_amdgcn_s_setprio(1);
#pragma unroll
      for (int i = 0; i < 4; i++)
#pragma unroll
        for (int j = 0; j < 4; j++) acc3[i][j] = mfma16(fa[i], fb[j], acc3[i][j]);
      __builtin_amdgcn_s_setprio(0);
    }
  }
#pragma unroll
  for (int i = 0; i < 4; i++)
#pragma unroll
    for (int j = 0; j < 4; j++)
#pragma unroll
      for (int r = 0; r < 4; r++) {
        size_t m = tm + wm * 64 + i * 16 + hi * 4 + r;
        size_t n = tn + wn * 64 + j * 16 + lo;
        float v1 = acc1[i][j][r], v3 = acc3[i][j][r];
        G[m * 4096 + n] = (bf16)(v1 / (1.0f + __expf(-v1)) * v3);
      }
}

// ---------------- split-precision q/k projection GEMM with fused RoPE, BK=64 ----------------
extern "C" __global__ __launch_bounds__(256, 2) void gemm_qk_kernel(
    const bf16* __restrict__ Ah, const bf16* __restrict__ Al,
    const bf16* __restrict__ BhQ, const bf16* __restrict__ BlQ,
    const bf16* __restrict__ BhK, const bf16* __restrict__ BlK,
    const float2* __restrict__ rope,
    bf16* __restrict__ OhQ, bf16* __restrict__ OlQ,
    bf16* __restrict__ OhK, bf16* __restrict__ OlK) {
  const int bid = blockIdx.x;
  const int xcd = bid & 7, sq = bid >> 3;
  const int zqk = sq >> 5;
  const int rem = sq & 31;
  const size_t tm = (size_t)(xcd * 4 + (rem >> 3)) * 128;
  const size_t tn = (size_t)(rem & 7) * 128;
  const bf16* Bh = zqk ? BhK : BhQ;
  const bf16* Bl = zqk ? BlK : BlQ;
  bf16* Oh = zqk ? OhK : OhQ;
  bf16* Ol = zqk ? OlK : OlQ;
  __shared__ alignas(16) bf16 Ahs[128 * 64], Als[128 * 64];
  __shared__ alignas(16) bf16 Bhs[128 * 64], Bls[128 * 64];
  const int tid = threadIdx.x;
  const int lane = tid & 63, wave = tid >> 6;
  const int lo = lane & 15, hi = lane >> 4;
  const int wm = wave >> 1, wn = wave & 1;
  const int K = 1024;
  f32x4 acc[4][4] = {};
  for (int k0 = 0; k0 < K; k0 += 64) {
    __syncthreads();
#pragma unroll
    for (int i4 = 0; i4 < 4; i4++) {
      int p = tid + 256 * i4;
      int row = p >> 3, c = p & 7;
      int cs = c ^ (row & 7);
      size_t ga = (tm + row) * (size_t)K + k0 + cs * 8;
      size_t gb = (tn + row) * (size_t)K + k0 + cs * 8;
      async_cp16((char*)Ahs + (size_t)p * 16, Ah + ga);
      async_cp16((char*)Als + (size_t)p * 16, Al + ga);
      async_cp16((char*)Bhs + (size_t)p * 16, Bh + gb);
      async_cp16((char*)Bls + (size_t)p * 16, Bl + gb);
    }
    __syncthreads();
#pragma unroll
    for (int kh = 0; kh < 2; kh++) {
      int offa[4], offb[4];
#pragma unroll
      for (int i = 0; i < 4; i++) {
        int ra = wm * 64 + i * 16 + lo;
        offa[i] = ra * 128 + (((kh * 4 + hi) ^ (ra & 7)) << 4);
        int rb = wn * 64 + i * 16 + lo;
        offb[i] = rb * 128 + (((kh * 4 + hi) ^ (rb & 7)) << 4);
      }
      bf16x8 fah[4], fbh[4], fx[4];
#pragma unroll
      for (int i = 0; i < 4; i++) {
        fah[i] = *(const bf16x8*)((const char*)Ahs + offa[i]);
        fbh[i] = *(const bf16x8*)((const char*)Bhs + offb[i]);
      }
      __builtin_amdgcn_s_setprio(1);
#pragma unroll
      for (int i = 0; i < 4; i++)
#pragma unroll
        for (int j = 0; j < 4; j++) acc[i][j] = mfma16(fah[i], fbh[j], acc[i][j]);
      __builtin_amdgcn_s_setprio(0);
#pragma unroll
      for (int j = 0; j < 4; j++) fx[j] = *(const bf16x8*)((const char*)Bls + offb[j]);
      __builtin_amdgcn_s_setprio(1);
#pragma unroll
      for (int i = 0; i < 4; i++)
#pragma unroll
        for (int j = 0; j < 4; j++) acc[i][j] = mfma16(fah[i], fx[j], acc[i][j]);
      __builtin_amdgcn_s_setprio(0);
#pragma unroll
      for (int i = 0; i < 4; i++) fx[i] = *(const bf16x8*)((const char*)Als + offa[i]);
      __builtin_amdgcn_s_setprio(1);
#pragma unroll
      for (int i = 0; i < 4; i++)
#pragma unroll
        for (int j = 0; j < 4; j++) acc[i][j] = mfma16(fx[i], fbh[j], acc[i][j]);
      __builtin_amdgcn_s_setprio(0);
    }
  }
#pragma unroll
  for (int i = 0; i < 4; i++)
#pragma unroll
    for (int j = 0; j < 4; j++)
#pragma unroll
      for (int r = 0; r < 4; r++) {
        float v = acc[i][j][r];
        float vp = __shfl_xor(v, 1, 64);
        size_t m = tm + wm * 64 + i * 16 + hi * 4 + r;
        size_t n = tn + wn * 64 + j * 16 + lo;
        int s = (int)(m & 1023);
        int pi = (int)((n & 63) >> 1);
        float2 cs = rope[s * 32 + pi];
        float res = (n & 1) ? (vp * cs.y + v * cs.x) : (v * cs.x - vp * cs.y);
        size_t idx = (((m >> 10) * 16 + (n >> 6)) * 1024 + (m & 1023)) * 64 + (n & 63);
        bf16 hb = (bf16)res;
        Oh[idx] = hb;
        Ol[idx] = (bf16)(res - (float)hb);
      }
}

// ---------------- flash attention (causal), split-precision scores, LDS-staged K/V ----------------
extern "C" __global__ __launch_bounds__(256, 4) void flash_kernel(
    const bf16* __restrict__ qhi, const bf16* __restrict__ qlo,
    const bf16* __restrict__ khi, const bf16* __restrict__ klo,
    const bf16* __restrict__ vT, bf16* __restrict__ ctx) {
  const int bid = blockIdx.x;
  const int qb = bid >> 6;
  const int bh = bid & 63;
  const int tid = threadIdx.x;
  const int wave = tid >> 6, lane = tid & 63;
  const int lo = lane & 15, hi = lane >> 4;

  __shared__ alignas(16) bf16 Ksh[2][64][32];
  __shared__ alignas(16) bf16 Ksl[2][64][32];
  __shared__ alignas(16) bf16 Vs[2][64][32];
  __shared__ alignas(16) bf16 P[4][16][72];

  size_t qoff = ((size_t)bh * 1024 + qb * 64 + wave * 16 + lo) * 64;
  bf16x8 qh[2], ql[2];
#pragma unroll
  for (int ks = 0; ks < 2; ks++) {
    qh[ks] = *(const bf16x8*)(qhi + qoff + ks * 32 + hi * 8);
    ql[ks] = *(const bf16x8*)(qlo + qoff + ks * 32 + hi * 8);
  }

  const int srow = tid >> 2;
  const int scl = (tid & 3) ^ swz4(srow);
  const size_t kgb = (size_t)bh * 1024 * 64;
  const size_t vgb = ((size_t)bh * 64 + srow) * 1024;

  float mrun[4] = {-1e30f, -1e30f, -1e30f, -1e30f};
  float lrun[4] = {0.f, 0.f, 0.f, 0.f};
  f32x4 o[4] = {};
  const float scale = 0.125f;

  for (int kt = 0; kt <= qb; kt++) {
    __syncthreads();
#pragma unroll
    for (int i = 0; i < 2; i++) {
      int p = tid + 256 * i;
      size_t gk = kgb + (size_t)(kt * 64 + srow) * 64 + i * 32 + scl * 8;
      async_cp16((char*)Ksh + (size_t)p * 16, khi + gk);
      async_cp16((char*)Ksl + (size_t)p * 16, klo + gk);
      async_cp16((char*)Vs + (size_t)p * 16, vT + vgb + kt * 64 + i * 32 + scl * 8);
    }
    __syncthreads();

    f32x4 sv[4];
    __builtin_amdgcn_s_setprio(1);
#pragma unroll
    for (int nb = 0; nb < 4; nb++) {
      f32x4 a = {0.f, 0.f, 0.f, 0.f};
#pragma unroll
      for (int ks = 0; ks < 2; ks++) {
        int row = nb * 16 + lo;
        int off16 = (ks * 64 + row) * 4 + (hi ^ swz4(row));
        bf16x8 kh = *(const bf16x8*)((const char*)Ksh + off16 * 16);
        bf16x8 kl = *(const bf16x8*)((const char*)Ksl + off16 * 16);
        a = mfma16(qh[ks], kh, a);
        a = mfma16(qh[ks], kl, a);
        a = mfma16(ql[ks], kh, a);
      }
      sv[nb] = a;
    }
    __builtin_amdgcn_s_setprio(0);

    const bool mt = (kt == qb);
#pragma unroll
    for (int nb = 0; nb < 4; nb++)
#pragma unroll
      for (int r = 0; r < 4; r++) {
        float s = sv[nb][r] * scale;
        if (mt) {
          int kp = nb * 16 + lo;
          int qr = wave * 16 + hi * 4 + r;
          if (kp > qr) s = -1e30f;
        }
        sv[nb][r] = s;
      }
    float mnew[4], rs[4];
#pragma unroll
    for (int r = 0; r < 4; r++) {
      float mx = fmaxf(fmaxf(sv[0][r], sv[1][r]), fmaxf(sv[2][r], sv[3][r]));
#pragma unroll
      for (int d = 1; d < 16; d <<= 1) mx = fmaxf(mx, __shfl_xor(mx, d, 64));
      mnew[r] = fmaxf(mrun[r], mx);
      float sc = __expf(mrun[r] - mnew[r]);
      lrun[r] *= sc;
#pragma unroll
      for (int db = 0; db < 4; db++) o[db][r] *= sc;
      mrun[r] = mnew[r];
      rs[r] = 0.f;
    }
#pragma unroll
    for (int nb = 0; nb < 4; nb++)
#pragma unroll
      for (int r = 0; r < 4; r++) {
        float p = __expf(sv[nb][r] - mnew[r]);
        bf16 pb = (bf16)p;
        rs[r] += (float)pb;
        P[wave][hi * 4 + r][nb * 16 + lo] = pb;
      }
#pragma unroll
    for (int r = 0; r < 4; r++) {
      float t = rs[r];
#pragma unroll
      for (int d = 1; d < 16; d <<= 1) t += __shfl_xor(t, d, 64);
      lrun[r] += t;
    }
    bf16x8 pa[2];
#pragma unroll
    for (int ks = 0; ks < 2; ks++) pa[ks] = *(const bf16x8*)&P[wave][lo][ks * 32 + hi * 8];
    __builtin_amdgcn_s_setprio(1);
#pragma unroll
    for (int db = 0; db < 4; db++)
#pragma unroll
      for (int ks = 0; ks < 2; ks++) {
        int row = db * 16 + lo;
        int off16 = (ks * 64 + row) * 4 + (hi ^ swz4(row));
        bf16x8 vf = *(const bf16x8*)((const char*)Vs + off16 * 16);
        o[db] = mfma16(pa[ks], vf, o[db]);
      }
    __builtin_amdgcn_s_setprio(0);
  }
  int b = bh >> 4, h = bh & 15;
#pragma unroll
  for (int db = 0; db < 4; db++)
#pragma unroll
    for (int r = 0; r < 4; r++) {
      float val = o[db][r] / lrun[r];
      size_t row = (size_t)b * 1024 + qb * 64 + wave * 16 + hi * 4 + r;
      ctx[row * 1024 + h * 64 + db * 16 + lo] = (bf16)val;
    }
}

// ---------------- host launcher ----------------

extern "C" void kernel_launch(void* const* d_in, const int* in_sizes, int n_in,
                              void* d_out, int out_size, void* d_ws, size_t ws_size,
                              hipStream_t stream) {
  (void)in_sizes; (void)n_in; (void)out_size; (void)ws_size;
  const float* x  = (const float*)d_in[0];
  const float* wq = (const float*)d_in[1];
  const float* wk = (const float*)d_in[2];
  const float* wv = (const float*)d_in[3];
  const float* wo = (const float*)d_in[4];
  const float* w1 = (const float*)d_in[5];
  const float* w2 = (const float*)d_in[6];
  const float* w3 = (const float*)d_in[7];
  const float* g1 = (const float*)d_in[8];
  const float* g2 = (const float*)d_in[9];
  float* out = (float*)d_out;

  char* ws = (char*)d_ws;
  size_t off = 0;
  auto alloc = [&](size_t bytes) {
    char* p = ws + off;
    off += (bytes + 255) & ~(size_t)255;
    return p;
  };
  const size_t MB2 = 1024u * 1024u * 2u;
  const size_t MB8 = 4096u * 1024u * 2u;
  void* WQH = alloc(MB2);  void* WQL = alloc(MB2);
  void* WKH = alloc(MB2);  void* WKL = alloc(MB2);
  void* WVH = alloc(MB2);  void* WOH = alloc(MB2);
  void* W1H = alloc(MB8);  void* W3H = alloc(MB8);  void* W2H = alloc(MB8);
  void* ROPE = alloc(32768u * 8u);
  void* Y1H = alloc(MB8);  void* Y1L = alloc(MB8);
  void* QH = alloc(MB8);   void* QL = alloc(MB8);
  void* KH = alloc(MB8);   void* KL = alloc(MB8);
  void* VT = alloc(MB8);
  void* CTX = alloc(MB8);
  void* Y2H = alloc(MB8);
  void* GLU = QH;  // 32MB alias over QH,QL,KH,KL (dead after flash)

  prep_kernel<<<dim3(4096, 8), dim3(256), 0, stream>>>(
      wq, wk, wv, wo, w1, w3, w2,
      (unsigned short*)WQH, (unsigned short*)WQL, (unsigned short*)WKH,
      (unsigned short*)WKL, (unsigned short*)WVH, (unsigned short*)WOH,
      (unsigned short*)W1H, (unsigned short*)W3H, (unsigned short*)W2H,
      (float2*)ROPE);

  rmsnorm_kernel<<<dim3(4096), dim3(256), 0, stream>>>(
      x, g1, (unsigned short*)Y1H, (unsigned short*)Y1L);

  gemm_qk_kernel<<<dim3(512), dim3(256), 0, stream>>>(
      (const bf16*)Y1H, (const bf16*)Y1L,
      (const bf16*)WQH, (const bf16*)WQL, (const bf16*)WKH, (const bf16*)WKL,
      (const float2*)ROPE,
      (bf16*)QH, (bf16*)QL, (bf16*)KH, (bf16*)KL);

  gemm_nt<0><<<dim3(256), dim3(256), 0, stream>>>(
      (const bf16*)Y1H, (const bf16*)WVH, 1024, 1024, 1024,
      nullptr, (bf16*)VT, nullptr);

  flash_kernel<<<dim3(1024), dim3(256), 0, stream>>>(
      (const bf16*)QH, (const bf16*)QL, (const bf16*)KH, (const bf16*)KL,
      (const bf16*)VT, (bf16*)CTX);

  gemm_nt<1><<<dim3(256), dim3(256), 0, stream>>>(
      (const bf16*)CTX, (const bf16*)WOH, 1024, 1024, 1024,
      out, nullptr, x);

  rmsnorm_kernel<<<dim3(4096), dim3(256), 0, stream>>>(
      out, g2, (unsigned short*)Y2H, nullptr);

  gemm_up_kernel<<<dim3(1024), dim3(256), 0, stream>>>(
      (const bf16*)Y2H, (const bf16*)W1H, (const bf16*)W3H, (bf16*)GLU);

  // down-projection: split-K=2 (512 blocks, K=2048), atomic f32 accumulate
  gemm_nt<5><<<dim3(512), dim3(256), 0, stream>>>(
      (const bf16*)GLU, (const bf16*)W2H, 1024, 2048, 4096,
      out, nullptr, nullptr);
}